// Round 6
// baseline (169.515 us; speedup 1.0000x reference)
//
#include <hip/hip_runtime.h>
#include <math.h>

// LinearCatVAE loss on MI355X.
// Psi = Helmert basis => Psi products are diag + prefix scans.
// R4: barrier-free fused mega (bf16 MFMA z,t + fp32 scan/LSE + Woodbury quad).
// R5: occupancy fix: LDS 60KB->26KB (G/Minv read from global in epilogue),
// __launch_bounds__(256,4) -> 4 blocks/CU (~50% occ, was 2 blocks/20%);
// log(x+1) via bf16 LDS LUT (kills 16 v_log/chunk); guards only on chunk 31;
// wdT+gram fused, gram_reduce folded into neumann (6 launches total).

#define LOG2PI_F 1.8378770664093453f

typedef short  v8s    __attribute__((ext_vector_type(8)));
typedef float  f32x4v __attribute__((ext_vector_type(4)));
typedef __bf16 bf8v   __attribute__((ext_vector_type(8)));

// ---- workspace offsets (floats) ----
#define OFF_A     0          // 2048
#define OFF_C     2048       // 2048
#define OFF_WEFFB 4096       // 64*2048 bf16 = 65536 floats
#define OFF_WDTB  69632      // 65536 floats
#define OFF_G     135168     // 4096
#define OFF_MINV  139264     // 4096
#define OFF_MISC  143360     // 64
#define OFF_GPART 143424     // 131072
#define OFF_MULT  274496     // 8192
#define OFF_LP    282688     // 8192

__device__ inline float red16(float v){
#pragma unroll
  for (int m = 1; m < 16; m <<= 1) v += __shfl_xor(v, m, 16);
  return v;
}

// ---------------- P0: Helmert coefficients ----------------
__global__ __launch_bounds__(256) void coef_kernel(const float* __restrict__ Psi,
                                                   float* __restrict__ a_ws,
                                                   float* __restrict__ c_ws){
  int e = blockIdx.x * 256 + threadIdx.x;
  if (e >= 2048) return;
  float a = 0.f, c = 0.f;
  if (e < 1999){
    a = Psi[(size_t)e * 2000 + e];
    c = -Psi[(size_t)e * 2000 + e + 1];
  }
  a_ws[e] = a;
  c_ws[e] = c;
}

// ---------------- P1: weffb[k][j] = bf16((W_enc @ Psi)[k][j]) ----------------
__global__ __launch_bounds__(256) void wenceff_kernel(const float* __restrict__ Wenc,
    const float* __restrict__ a_ws, const float* __restrict__ c_ws,
    __bf16* __restrict__ weffb){
  __shared__ float scan[256];
  int k = blockIdx.x, tid = threadIdx.x;
  const float* wrow = Wenc + (size_t)k * 1999;
  int base = tid * 8;
  float w[8], sloc[8];
  float run = 0.f;
#pragma unroll
  for (int u = 0; u < 8; ++u){
    int e = base + u;
    float wv = (e < 1999) ? wrow[e] : 0.f;
    w[u] = wv;
    sloc[u] = run;
    run += c_ws[e] * wv;
  }
  scan[tid] = run;
  __syncthreads();
  for (int off = 1; off < 256; off <<= 1){
    float y = (tid >= off) ? scan[tid - off] : 0.f;
    __syncthreads();
    scan[tid] += y;
    __syncthreads();
  }
  float excl = scan[tid] - run;
#pragma unroll
  for (int u = 0; u < 8; ++u){
    int e = base + u;
    float val = (e < 2000) ? (a_ws[e] * w[u] - (excl + sloc[u])) : 0.f;
    weffb[(size_t)k * 2048 + e] = (__bf16)val;
  }
}

// ------- P1b+P2a fused: wdtb[k][j] = bf16(Wdec[j][k]) AND gram partials -------
__global__ __launch_bounds__(256) void wdtgram_kernel(const float* __restrict__ Wdec,
                                                      __bf16* __restrict__ wdtb,
                                                      float* __restrict__ gparts){
  __shared__ __align__(16) float Ws[64][64];
  int tid = threadIdx.x;
  int j0 = blockIdx.x * 64;
#pragma unroll
  for (int i = 0; i < 16; ++i){
    int e = tid + i * 256;
    int j = e >> 6, k = e & 63;
    Ws[j][k] = (j0 + j < 1999) ? Wdec[(size_t)(j0 + j) * 64 + k] : 0.f;
  }
  __syncthreads();
  // transpose-write bf16
#pragma unroll
  for (int i = 0; i < 16; ++i){
    int e = tid + i * 256; int k = e >> 6, j = e & 63;
    wdtb[(size_t)k * 2048 + j0 + j] = (__bf16)Ws[j][k];
  }
  // gram partial
  int p = tid & 63;
  int qb = (tid >> 6) * 16;
  float acc[16] = {};
  for (int jj = 0; jj < 64; ++jj){
    float wp = Ws[jj][p];
    const float4 q0 = *(const float4*)&Ws[jj][qb];
    const float4 q1 = *(const float4*)&Ws[jj][qb + 4];
    const float4 q2 = *(const float4*)&Ws[jj][qb + 8];
    const float4 q3 = *(const float4*)&Ws[jj][qb + 12];
    acc[0]  = fmaf(wp, q0.x, acc[0]);  acc[1]  = fmaf(wp, q0.y, acc[1]);
    acc[2]  = fmaf(wp, q0.z, acc[2]);  acc[3]  = fmaf(wp, q0.w, acc[3]);
    acc[4]  = fmaf(wp, q1.x, acc[4]);  acc[5]  = fmaf(wp, q1.y, acc[5]);
    acc[6]  = fmaf(wp, q1.z, acc[6]);  acc[7]  = fmaf(wp, q1.w, acc[7]);
    acc[8]  = fmaf(wp, q2.x, acc[8]);  acc[9]  = fmaf(wp, q2.y, acc[9]);
    acc[10] = fmaf(wp, q2.z, acc[10]); acc[11] = fmaf(wp, q2.w, acc[11]);
    acc[12] = fmaf(wp, q3.x, acc[12]); acc[13] = fmaf(wp, q3.y, acc[13]);
    acc[14] = fmaf(wp, q3.z, acc[14]); acc[15] = fmaf(wp, q3.w, acc[15]);
  }
  float* gp = gparts + (size_t)blockIdx.x * 4096 + (size_t)p * 64 + qb;
#pragma unroll
  for (int u = 0; u < 4; ++u){
    float4 o; o.x = acc[4*u]; o.y = acc[4*u+1]; o.z = acc[4*u+2]; o.w = acc[4*u+3];
    *(float4*)&gp[4*u] = o;
  }
}

// ---- P3: gram reduce + Minv + logdet (Neumann truncated at A^2) ----
__global__ __launch_bounds__(256) void neumann_kernel(const float* __restrict__ gparts,
    const float* __restrict__ vlv, const float* __restrict__ lss,
    float* __restrict__ Gws, float* __restrict__ Minv, float* __restrict__ misc){
  __shared__ float As[64][65];
  __shared__ float A2s[64][65];
  __shared__ double dred[4][3];
  int tid = threadIdx.x;
  float var = expf(lss[0]);
  for (int e = tid; e < 4096; e += 256){
    int i = e >> 6;
    float s = 0.f;
#pragma unroll
    for (int p = 0; p < 32; ++p) s += gparts[(size_t)p * 4096 + e];
    Gws[e] = s;
    As[i][e & 63] = expf(vlv[i]) * s / var;
  }
  __syncthreads();
  for (int e = tid; e < 4096; e += 256){
    int i = e >> 6, j = e & 63;
    float s = 0.f;
    for (int q = 0; q < 64; ++q) s = fmaf(As[i][q], As[q][j], s);
    A2s[i][j] = s;
  }
  __syncthreads();
  double t1 = 0, t2 = 0, t3 = 0;
  for (int e = tid; e < 4096; e += 256){
    int i = e >> 6, j = e & 63;
    if (i == j){ t1 += (double)As[i][i]; t2 += (double)A2s[i][i]; }
    t3 += (double)A2s[i][j] * (double)As[j][i];
  }
#pragma unroll
  for (int m = 1; m < 64; m <<= 1){
    t1 += __shfl_xor(t1, m, 64); t2 += __shfl_xor(t2, m, 64); t3 += __shfl_xor(t3, m, 64);
  }
  int wid = tid >> 6;
  if ((tid & 63) == 0){ dred[wid][0] = t1; dred[wid][1] = t2; dred[wid][2] = t3; }
  __syncthreads();
  for (int e = tid; e < 4096; e += 256){
    int i = e >> 6, j = e & 63;
    float v = ((i == j) ? 1.f : 0.f) - As[i][j] + A2s[i][j];
    Minv[e] = v * expf(vlv[j]);
  }
  if (tid == 0){
    double tr1 = 0, tr2 = 0, tr3 = 0;
    for (int w2 = 0; w2 < 4; ++w2){
      tr1 += dred[w2][0]; tr2 += dred[w2][1]; tr3 += dred[w2][2];
    }
    misc[0] = (float)(1999.0 * (double)lss[0] + tr1 - tr2 / 2.0 + tr3 / 3.0);
  }
}

// ---------------- MEGA: barrier-free fused pass over x,eta ----------------
// 512 blocks x 256 threads; 16 rows/block; 32 chunks of 64 cols.
struct ChunkBuf {
  float sx4[4];   // scan x
  float se4[4];   // scan eta
  float ax[16];   // MFMA A-frag x (2 k-halves)
  float ae[16];   // MFMA A-frag eta
  v8s bf0, bf1;   // B-frag Weff (bf16)
  v8s bd0, bd1;   // B-frag WdT (bf16)
};

__global__ __launch_bounds__(256, 4) void mega_kernel(
    const float* __restrict__ x, const float* __restrict__ eta,
    const short* __restrict__ wfB, const short* __restrict__ wdB,
    const float* __restrict__ a_ws, const float* __restrict__ c_ws,
    const float* __restrict__ Gws, const float* __restrict__ Minv,
    const float* __restrict__ misc, const float* __restrict__ lss,
    float* __restrict__ mult_out, float* __restrict__ lp_out)
{
  __shared__ unsigned short lutlog[128];           // bf16 bits of log(i+1)
  __shared__ float lutlg[128];
  __shared__ __align__(16) float a_lds[2048];
  __shared__ __align__(16) float c_lds[2048];
  __shared__ __align__(16) float z_l[16][68];
  __shared__ __align__(16) float t_l[16][68];

  const int tid = threadIdx.x;
  const int b0 = blockIdx.x * 16;
  if (tid < 128){
    union { __bf16 b; unsigned short u; } cv;
    cv.b = (__bf16)logf((float)(tid + 1));
    lutlog[tid] = cv.u;
    lutlg[tid] = lgammaf((float)(tid + 1));
  }
  for (int i = tid; i < 2048; i += 256){ a_lds[i] = a_ws[i]; c_lds[i] = c_ws[i]; }

  // roles
  const int lrow = tid >> 4;                 // 0..15 scan row
  const int sl   = tid & 15;                 // scan lane
  const int lq4  = sl * 4;                   // 4 cols/lane
  const int wid  = tid >> 6, lan = tid & 63;
  const int arow = lan & 15;                 // MFMA A row
  const int bcol = wid * 16 + (lan & 15);    // MFMA B col (output col)
  const int kgrp = (lan >> 4) * 8;           // k-offset within 32-half

  __syncthreads();  // luts ready

  f32x4v accz = {0.f, 0.f, 0.f, 0.f}, acct = {0.f, 0.f, 0.f, 0.f};
  float carry = 0.f, mOn = -3.0e38f, sOn = 0.f;
  float xdot = 0.f, sx = 0.f, sgl = 0.f, e2 = 0.f;

  const float* xs_base = x   + (size_t)(b0 + lrow) * 2000 + lq4;
  const float* es_base = eta + (size_t)(b0 + lrow) * 1999 + lq4;
  const float* xa_base = x   + (size_t)(b0 + arow) * 2000 + kgrp;
  const float* ea_base = eta + (size_t)(b0 + arow) * 1999 + kgrp;
  const short* wf_base = wfB + (size_t)bcol * 2048 + kgrp;
  const short* wd_base = wdB + (size_t)bcol * 2048 + kgrp;

  auto loadChunk = [&](ChunkBuf& B, int ch, bool guard){
    const int j0 = ch * 64;
    const float* xp = xs_base + j0;
    const float* ep = es_base + j0;
    if (!guard){
      f32x4v v = *(const f32x4v*)xp;
      B.sx4[0] = v[0]; B.sx4[1] = v[1]; B.sx4[2] = v[2]; B.sx4[3] = v[3];
#pragma unroll
      for (int u = 0; u < 4; ++u) B.se4[u] = ep[u];
    } else {
#pragma unroll
      for (int u = 0; u < 4; ++u){
        int c = j0 + lq4 + u;
        B.sx4[u] = (c < 2000) ? xp[u] : 0.f;
        B.se4[u] = (c < 1999) ? ep[u] : 0.f;
      }
    }
    const float* axp = xa_base + j0;
    const float* aep = ea_base + j0;
    if (!guard){
      f32x4v a0 = *(const f32x4v*)axp;
      f32x4v a1 = *(const f32x4v*)(axp + 4);
      f32x4v a2 = *(const f32x4v*)(axp + 32);
      f32x4v a3 = *(const f32x4v*)(axp + 36);
#pragma unroll
      for (int u = 0; u < 4; ++u){
        B.ax[u] = a0[u]; B.ax[4+u] = a1[u]; B.ax[8+u] = a2[u]; B.ax[12+u] = a3[u];
      }
#pragma unroll
      for (int u = 0; u < 8; ++u){ B.ae[u] = aep[u]; B.ae[8+u] = aep[32 + u]; }
    } else {
#pragma unroll
      for (int u = 0; u < 8; ++u){
        int c0 = j0 + kgrp + u, c1 = c0 + 32;
        B.ax[u]   = (c0 < 2000) ? axp[u]      : 0.f;
        B.ax[8+u] = (c1 < 2000) ? axp[32 + u] : 0.f;
        B.ae[u]   = (c0 < 1999) ? aep[u]      : 0.f;
        B.ae[8+u] = (c1 < 1999) ? aep[32 + u] : 0.f;
      }
    }
    B.bf0 = *(const v8s*)(wf_base + j0);
    B.bf1 = *(const v8s*)(wf_base + j0 + 32);
    B.bd0 = *(const v8s*)(wd_base + j0);
    B.bd1 = *(const v8s*)(wd_base + j0 + 32);
  };

  auto computeChunk = [&](ChunkBuf& B, int ch, bool guard){
    const int j0 = ch * 64;
    // MFMA path: x via bf16 log-LUT, eta via cvt
    union U16 { v8s s; unsigned short u[8]; } ax0, ax1;
    union BU  { bf8v b; v8s s; } ae0, ae1;
#pragma unroll
    for (int u = 0; u < 8; ++u){
      ax0.u[u] = lutlog[(int)B.ax[u]];
      ax1.u[u] = lutlog[(int)B.ax[8+u]];
      ae0.b[u] = (__bf16)B.ae[u];
      ae1.b[u] = (__bf16)B.ae[8+u];
    }
    accz = __builtin_amdgcn_mfma_f32_16x16x32_bf16(ax0.s, B.bf0, accz, 0, 0, 0);
    accz = __builtin_amdgcn_mfma_f32_16x16x32_bf16(ax1.s, B.bf1, accz, 0, 0, 0);
    acct = __builtin_amdgcn_mfma_f32_16x16x32_bf16(ae0.s, B.bd0, acct, 0, 0, 0);
    acct = __builtin_amdgcn_mfma_f32_16x16x32_bf16(ae1.s, B.bd1, acct, 0, 0, 0);
    // scan path
    f32x4v cz = *(const f32x4v*)&c_lds[j0 + lq4];
    f32x4v az = *(const f32x4v*)&a_lds[j0 + lq4];
    float s0 = cz[0] * B.se4[0], s1 = cz[1] * B.se4[1];
    float s2 = cz[2] * B.se4[2], s3 = cz[3] * B.se4[3];
    float run = s0 + s1 + s2 + s3;
    float p1 = s0, p2 = s0 + s1, p3 = s0 + s1 + s2;
    float tot = run;
#pragma unroll
    for (int d = 1; d < 16; d <<= 1){
      float o = __shfl_up(tot, d, 16);
      if (sl >= d) tot += o;
    }
    float excl = tot - run;
    float base = carry + excl;
    carry += __shfl(tot, 15, 16);
    float lg0 = az[0] * B.se4[0] - base;
    float lg1 = az[1] * B.se4[1] - (base + p1);
    float lg2 = az[2] * B.se4[2] - (base + p2);
    float lg3 = az[3] * B.se4[3] - (base + p3);
    if (!guard){
      float cm = fmaxf(fmaxf(lg0, lg1), fmaxf(lg2, lg3));
      if (cm > mOn){ sOn *= __expf(mOn - cm); mOn = cm; }
      sOn += __expf(lg0 - mOn) + __expf(lg1 - mOn) + __expf(lg2 - mOn) + __expf(lg3 - mOn);
      xdot = fmaf(B.sx4[0], lg0, xdot);
      xdot = fmaf(B.sx4[1], lg1, xdot);
      xdot = fmaf(B.sx4[2], lg2, xdot);
      xdot = fmaf(B.sx4[3], lg3, xdot);
    } else {
      int nvalid = 2000 - (j0 + lq4);
      float cm = -3.0e38f;
      if (0 < nvalid) cm = fmaxf(cm, lg0);
      if (1 < nvalid) cm = fmaxf(cm, lg1);
      if (2 < nvalid) cm = fmaxf(cm, lg2);
      if (3 < nvalid) cm = fmaxf(cm, lg3);
      if (cm > mOn){ sOn *= __expf(mOn - cm); mOn = cm; }
      if (0 < nvalid){ sOn += __expf(lg0 - mOn); xdot = fmaf(B.sx4[0], lg0, xdot); }
      if (1 < nvalid){ sOn += __expf(lg1 - mOn); xdot = fmaf(B.sx4[1], lg1, xdot); }
      if (2 < nvalid){ sOn += __expf(lg2 - mOn); xdot = fmaf(B.sx4[2], lg2, xdot); }
      if (3 < nvalid){ sOn += __expf(lg3 - mOn); xdot = fmaf(B.sx4[3], lg3, xdot); }
    }
#pragma unroll
    for (int u = 0; u < 4; ++u){
      sx += B.sx4[u];
      sgl += lutlg[(int)B.sx4[u]];
      e2 = fmaf(B.se4[u], B.se4[u], e2);
    }
  };

  ChunkBuf bufA, bufB;
  loadChunk(bufA, 0, false);
#pragma unroll 1
  for (int ch = 0; ch < 30; ch += 2){
    loadChunk(bufB, ch + 1, false);
    computeChunk(bufA, ch, false);
    loadChunk(bufA, ch + 2, false);
    computeChunk(bufB, ch + 1, false);
  }
  loadChunk(bufB, 31, true);
  computeChunk(bufA, 30, false);
  computeChunk(bufB, 31, true);

  // ---- epilogue ----
  {
    int r0 = (lan >> 4) * 4;
#pragma unroll
    for (int r = 0; r < 4; ++r){
      z_l[r0 + r][bcol] = accz[r];
      t_l[r0 + r][bcol] = acct[r];
    }
  }
  __syncthreads();

  float z4[4], t4[4];
  {
    f32x4v zv = *(const f32x4v*)&z_l[lrow][lq4];
    f32x4v tv = *(const f32x4v*)&t_l[lrow][lq4];
#pragma unroll
    for (int u = 0; u < 4; ++u){ z4[u] = zv[u]; t4[u] = tv[u]; }
  }
  float zz = 0.f, tz = 0.f;
#pragma unroll
  for (int u = 0; u < 4; ++u){ zz = fmaf(z4[u], z4[u], zz); tz = fmaf(t4[u], z4[u], tz); }
  float gz[4] = {0.f, 0.f, 0.f, 0.f};
#pragma unroll 8
  for (int q = 0; q < 64; ++q){
    float zq = z_l[lrow][q];
    f32x4v g = *(const f32x4v*)&Gws[q * 64 + lq4];   // G symmetric; L2-hot
#pragma unroll
    for (int u = 0; u < 4; ++u) gz[u] = fmaf(g[u], zq, gz[u]);
  }
  float zGz = 0.f;
#pragma unroll
  for (int u = 0; u < 4; ++u) zGz = fmaf(z4[u], gz[u], zGz);
  float tk[4];
#pragma unroll
  for (int u = 0; u < 4; ++u){ tk[u] = t4[u] - gz[u]; t_l[lrow][lq4 + u] = tk[u]; }
  float sol[4] = {0.f, 0.f, 0.f, 0.f};
#pragma unroll 8
  for (int q = 0; q < 64; ++q){
    float tq = t_l[lrow][q];
    f32x4v g = *(const f32x4v*)&Minv[q * 64 + lq4];  // Minv symmetric; L2-hot
#pragma unroll
    for (int u = 0; u < 4; ++u) sol[u] = fmaf(g[u], tq, sol[u]);
  }
  float ts = 0.f;
#pragma unroll
  for (int u = 0; u < 4; ++u) ts = fmaf(tk[u], sol[u], ts);

  zz = red16(zz); tz = red16(tz); zGz = red16(zGz); ts = red16(ts);
  xdot = red16(xdot); sx = red16(sx); sgl = red16(sgl); e2 = red16(e2);
#pragma unroll
  for (int d = 1; d < 16; d <<= 1){
    float om = __shfl_xor(mOn, d, 16);
    float os = __shfl_xor(sOn, d, 16);
    float nm = fmaxf(mOn, om);
    sOn = sOn * __expf(mOn - nm) + os * __expf(om - nm);
    mOn = nm;
  }
  if (sl == 0){
    int b = b0 + lrow;
    float lse = mOn + logf(sOn);
    mult_out[b] = lgammaf(sx + 1.f) - sgl + xdot - sx * lse;
    float var = expf(lss[0]);
    float logdet = misc[0];
    float diff2 = e2 - 2.f * tz + zGz;
    float quad = diff2 / var - ts / (var * var);
    lp_out[b] = -0.5f * (1999.f * LOG2PI_F + logdet + quad) - 0.5f * zz;
  }
}

// ---------------- Z: final mean + constants ----------------
__global__ __launch_bounds__(256) void reduce_kernel(const float* __restrict__ mult,
    const float* __restrict__ lp, float* __restrict__ out){
  __shared__ double red[4];
  int tid = threadIdx.x;
  double acc = 0.0;
  for (int b = tid; b < 8192; b += 256)
    acc += (double)mult[b] + (double)lp[b];
#pragma unroll
  for (int m = 1; m < 64; m <<= 1) acc += __shfl_xor(acc, m, 64);
  if ((tid & 63) == 0) red[tid >> 6] = acc;
  __syncthreads();
  if (tid == 0){
    double tot = red[0] + red[1] + red[2] + red[3];
    double mean = tot / 8192.0;
    double loss = -(mean - 0.5 * 64.0 * 1.8378770664093453);
    out[0] = (float)loss;
  }
}

extern "C" void kernel_launch(void* const* d_in, const int* in_sizes, int n_in,
                              void* d_out, int out_size, void* d_ws, size_t ws_size,
                              hipStream_t stream){
  const float* x    = (const float*)d_in[0];
  const float* Psi  = (const float*)d_in[1];
  const float* Wenc = (const float*)d_in[2];
  const float* Wdec = (const float*)d_in[3];
  const float* vlv  = (const float*)d_in[4];
  const float* lss  = (const float*)d_in[5];
  const float* eta  = (const float*)d_in[6];
  float* ws = (float*)d_ws;
  float*  a_ws  = ws + OFF_A;
  float*  c_ws  = ws + OFF_C;
  __bf16* weffb = (__bf16*)(ws + OFF_WEFFB);
  __bf16* wdtb  = (__bf16*)(ws + OFF_WDTB);
  float*  Gws   = ws + OFF_G;
  float*  Minv  = ws + OFF_MINV;
  float*  misc  = ws + OFF_MISC;
  float*  gpart = ws + OFF_GPART;
  float*  multw = ws + OFF_MULT;
  float*  lpw   = ws + OFF_LP;

  coef_kernel<<<8, 256, 0, stream>>>(Psi, a_ws, c_ws);
  wenceff_kernel<<<64, 256, 0, stream>>>(Wenc, a_ws, c_ws, weffb);
  wdtgram_kernel<<<32, 256, 0, stream>>>(Wdec, wdtb, gpart);
  neumann_kernel<<<1, 256, 0, stream>>>(gpart, vlv, lss, Gws, Minv, misc);
  mega_kernel<<<512, 256, 0, stream>>>(x, eta, (const short*)weffb, (const short*)wdtb,
                                       a_ws, c_ws, Gws, Minv, misc, lss, multw, lpw);
  reduce_kernel<<<1, 256, 0, stream>>>(multw, lpw, (float*)d_out);
}

// Round 7
// 134.058 us; speedup vs baseline: 1.2645x; 1.2645x over previous
//
#include <hip/hip_runtime.h>
#include <math.h>

// LinearCatVAE loss on MI355X.
// Psi = Helmert basis => Psi products are diag + prefix scans.
// R4: barrier-free fused mega (bf16 MFMA z,t + fp32 scan/LSE + Woodbury quad).
// R5 (regressed): launch_bounds(256,4)+26KB LDS made the allocator target the
// 6-block/64-VGPR tier -> ChunkBuf spilled to scratch (WRITE_SIZE 28MB).
// R6: occupancy steered via LDS size instead: pad LDS to ~36KB so the
// LDS-derived cap is exactly 4 blocks/CU -> VGPR budget 128 >= natural 112,
// no spills, 16 waves/CU. Plain __launch_bounds__(256) (R4-verified alloc).

#define LOG2PI_F 1.8378770664093453f

typedef short  v8s    __attribute__((ext_vector_type(8)));
typedef float  f32x4v __attribute__((ext_vector_type(4)));
typedef __bf16 bf8v   __attribute__((ext_vector_type(8)));

// ---- workspace offsets (floats) ----
#define OFF_A     0          // 2048
#define OFF_C     2048       // 2048
#define OFF_WEFFB 4096       // 64*2048 bf16 = 65536 floats
#define OFF_WDTB  69632      // 65536 floats
#define OFF_G     135168     // 4096
#define OFF_MINV  139264     // 4096
#define OFF_MISC  143360     // 64
#define OFF_GPART 143424     // 131072
#define OFF_MULT  274496     // 8192
#define OFF_LP    282688     // 8192

__device__ inline float red16(float v){
#pragma unroll
  for (int m = 1; m < 16; m <<= 1) v += __shfl_xor(v, m, 16);
  return v;
}

// ---------------- P0: Helmert coefficients ----------------
__global__ __launch_bounds__(256) void coef_kernel(const float* __restrict__ Psi,
                                                   float* __restrict__ a_ws,
                                                   float* __restrict__ c_ws){
  int e = blockIdx.x * 256 + threadIdx.x;
  if (e >= 2048) return;
  float a = 0.f, c = 0.f;
  if (e < 1999){
    a = Psi[(size_t)e * 2000 + e];
    c = -Psi[(size_t)e * 2000 + e + 1];
  }
  a_ws[e] = a;
  c_ws[e] = c;
}

// ---------------- P1: weffb[k][j] = bf16((W_enc @ Psi)[k][j]) ----------------
__global__ __launch_bounds__(256) void wenceff_kernel(const float* __restrict__ Wenc,
    const float* __restrict__ a_ws, const float* __restrict__ c_ws,
    __bf16* __restrict__ weffb){
  __shared__ float scan[256];
  int k = blockIdx.x, tid = threadIdx.x;
  const float* wrow = Wenc + (size_t)k * 1999;
  int base = tid * 8;
  float w[8], sloc[8];
  float run = 0.f;
#pragma unroll
  for (int u = 0; u < 8; ++u){
    int e = base + u;
    float wv = (e < 1999) ? wrow[e] : 0.f;
    w[u] = wv;
    sloc[u] = run;
    run += c_ws[e] * wv;
  }
  scan[tid] = run;
  __syncthreads();
  for (int off = 1; off < 256; off <<= 1){
    float y = (tid >= off) ? scan[tid - off] : 0.f;
    __syncthreads();
    scan[tid] += y;
    __syncthreads();
  }
  float excl = scan[tid] - run;
#pragma unroll
  for (int u = 0; u < 8; ++u){
    int e = base + u;
    float val = (e < 2000) ? (a_ws[e] * w[u] - (excl + sloc[u])) : 0.f;
    weffb[(size_t)k * 2048 + e] = (__bf16)val;
  }
}

// ------- P1b+P2a fused: wdtb[k][j] = bf16(Wdec[j][k]) AND gram partials -------
__global__ __launch_bounds__(256) void wdtgram_kernel(const float* __restrict__ Wdec,
                                                      __bf16* __restrict__ wdtb,
                                                      float* __restrict__ gparts){
  __shared__ __align__(16) float Ws[64][64];
  int tid = threadIdx.x;
  int j0 = blockIdx.x * 64;
#pragma unroll
  for (int i = 0; i < 16; ++i){
    int e = tid + i * 256;
    int j = e >> 6, k = e & 63;
    Ws[j][k] = (j0 + j < 1999) ? Wdec[(size_t)(j0 + j) * 64 + k] : 0.f;
  }
  __syncthreads();
  // transpose-write bf16
#pragma unroll
  for (int i = 0; i < 16; ++i){
    int e = tid + i * 256; int k = e >> 6, j = e & 63;
    wdtb[(size_t)k * 2048 + j0 + j] = (__bf16)Ws[j][k];
  }
  // gram partial
  int p = tid & 63;
  int qb = (tid >> 6) * 16;
  float acc[16] = {};
  for (int jj = 0; jj < 64; ++jj){
    float wp = Ws[jj][p];
    const float4 q0 = *(const float4*)&Ws[jj][qb];
    const float4 q1 = *(const float4*)&Ws[jj][qb + 4];
    const float4 q2 = *(const float4*)&Ws[jj][qb + 8];
    const float4 q3 = *(const float4*)&Ws[jj][qb + 12];
    acc[0]  = fmaf(wp, q0.x, acc[0]);  acc[1]  = fmaf(wp, q0.y, acc[1]);
    acc[2]  = fmaf(wp, q0.z, acc[2]);  acc[3]  = fmaf(wp, q0.w, acc[3]);
    acc[4]  = fmaf(wp, q1.x, acc[4]);  acc[5]  = fmaf(wp, q1.y, acc[5]);
    acc[6]  = fmaf(wp, q1.z, acc[6]);  acc[7]  = fmaf(wp, q1.w, acc[7]);
    acc[8]  = fmaf(wp, q2.x, acc[8]);  acc[9]  = fmaf(wp, q2.y, acc[9]);
    acc[10] = fmaf(wp, q2.z, acc[10]); acc[11] = fmaf(wp, q2.w, acc[11]);
    acc[12] = fmaf(wp, q3.x, acc[12]); acc[13] = fmaf(wp, q3.y, acc[13]);
    acc[14] = fmaf(wp, q3.z, acc[14]); acc[15] = fmaf(wp, q3.w, acc[15]);
  }
  float* gp = gparts + (size_t)blockIdx.x * 4096 + (size_t)p * 64 + qb;
#pragma unroll
  for (int u = 0; u < 4; ++u){
    float4 o; o.x = acc[4*u]; o.y = acc[4*u+1]; o.z = acc[4*u+2]; o.w = acc[4*u+3];
    *(float4*)&gp[4*u] = o;
  }
}

// ---- P3: gram reduce + Minv + logdet (Neumann truncated at A^2) ----
__global__ __launch_bounds__(256) void neumann_kernel(const float* __restrict__ gparts,
    const float* __restrict__ vlv, const float* __restrict__ lss,
    float* __restrict__ Gws, float* __restrict__ Minv, float* __restrict__ misc){
  __shared__ float As[64][65];
  __shared__ float A2s[64][65];
  __shared__ double dred[4][3];
  int tid = threadIdx.x;
  float var = expf(lss[0]);
  for (int e = tid; e < 4096; e += 256){
    int i = e >> 6;
    float s = 0.f;
#pragma unroll
    for (int p = 0; p < 32; ++p) s += gparts[(size_t)p * 4096 + e];
    Gws[e] = s;
    As[i][e & 63] = expf(vlv[i]) * s / var;
  }
  __syncthreads();
  for (int e = tid; e < 4096; e += 256){
    int i = e >> 6, j = e & 63;
    float s = 0.f;
    for (int q = 0; q < 64; ++q) s = fmaf(As[i][q], As[q][j], s);
    A2s[i][j] = s;
  }
  __syncthreads();
  double t1 = 0, t2 = 0, t3 = 0;
  for (int e = tid; e < 4096; e += 256){
    int i = e >> 6, j = e & 63;
    if (i == j){ t1 += (double)As[i][i]; t2 += (double)A2s[i][i]; }
    t3 += (double)A2s[i][j] * (double)As[j][i];
  }
#pragma unroll
  for (int m = 1; m < 64; m <<= 1){
    t1 += __shfl_xor(t1, m, 64); t2 += __shfl_xor(t2, m, 64); t3 += __shfl_xor(t3, m, 64);
  }
  int wid = tid >> 6;
  if ((tid & 63) == 0){ dred[wid][0] = t1; dred[wid][1] = t2; dred[wid][2] = t3; }
  __syncthreads();
  for (int e = tid; e < 4096; e += 256){
    int i = e >> 6, j = e & 63;
    float v = ((i == j) ? 1.f : 0.f) - As[i][j] + A2s[i][j];
    Minv[e] = v * expf(vlv[j]);
  }
  if (tid == 0){
    double tr1 = 0, tr2 = 0, tr3 = 0;
    for (int w2 = 0; w2 < 4; ++w2){
      tr1 += dred[w2][0]; tr2 += dred[w2][1]; tr3 += dred[w2][2];
    }
    misc[0] = (float)(1999.0 * (double)lss[0] + tr1 - tr2 / 2.0 + tr3 / 3.0);
  }
}

// ---------------- MEGA: barrier-free fused pass over x,eta ----------------
// 512 blocks x 256 threads; 16 rows/block; 32 chunks of 64 cols.
// LDS deliberately padded to ~36KB => LDS-derived cap = 4 blocks/CU =>
// compiler VGPR budget 128 (natural need ~112, no spill), 16 waves/CU.
struct ChunkBuf {
  float sx4[4];   // scan x
  float se4[4];   // scan eta
  float ax[16];   // MFMA A-frag x (2 k-halves)
  float ae[16];   // MFMA A-frag eta
  v8s bf0, bf1;   // B-frag Weff (bf16)
  v8s bd0, bd1;   // B-frag WdT (bf16)
};

#define ACPAD 3328   // 2048 used; rest pads LDS to steer occupancy tier

__global__ __launch_bounds__(256) void mega_kernel(
    const float* __restrict__ x, const float* __restrict__ eta,
    const short* __restrict__ wfB, const short* __restrict__ wdB,
    const float* __restrict__ a_ws, const float* __restrict__ c_ws,
    const float* __restrict__ Gws, const float* __restrict__ Minv,
    const float* __restrict__ misc, const float* __restrict__ lss,
    float* __restrict__ mult_out, float* __restrict__ lp_out)
{
  __shared__ unsigned short lutlog[128];           // bf16 bits of log(i+1)
  __shared__ float lutlg[128];
  __shared__ __align__(16) float a_lds[ACPAD];
  __shared__ __align__(16) float c_lds[ACPAD];
  __shared__ __align__(16) float z_l[16][68];
  __shared__ __align__(16) float t_l[16][68];

  const int tid = threadIdx.x;
  const int b0 = blockIdx.x * 16;
  if (tid < 128){
    union { __bf16 b; unsigned short u; } cv;
    cv.b = (__bf16)logf((float)(tid + 1));
    lutlog[tid] = cv.u;
    lutlg[tid] = lgammaf((float)(tid + 1));
  }
  for (int i = tid; i < 2048; i += 256){ a_lds[i] = a_ws[i]; c_lds[i] = c_ws[i]; }

  // roles
  const int lrow = tid >> 4;                 // 0..15 scan row
  const int sl   = tid & 15;                 // scan lane
  const int lq4  = sl * 4;                   // 4 cols/lane
  const int wid  = tid >> 6, lan = tid & 63;
  const int arow = lan & 15;                 // MFMA A row
  const int bcol = wid * 16 + (lan & 15);    // MFMA B col (output col)
  const int kgrp = (lan >> 4) * 8;           // k-offset within 32-half

  __syncthreads();  // luts ready

  f32x4v accz = {0.f, 0.f, 0.f, 0.f}, acct = {0.f, 0.f, 0.f, 0.f};
  float carry = 0.f, mOn = -3.0e38f, sOn = 0.f;
  float xdot = 0.f, sx = 0.f, sgl = 0.f, e2 = 0.f;

  const float* xs_base = x   + (size_t)(b0 + lrow) * 2000 + lq4;
  const float* es_base = eta + (size_t)(b0 + lrow) * 1999 + lq4;
  const float* xa_base = x   + (size_t)(b0 + arow) * 2000 + kgrp;
  const float* ea_base = eta + (size_t)(b0 + arow) * 1999 + kgrp;
  const short* wf_base = wfB + (size_t)bcol * 2048 + kgrp;
  const short* wd_base = wdB + (size_t)bcol * 2048 + kgrp;

  auto loadChunk = [&](ChunkBuf& B, int ch, bool guard){
    const int j0 = ch * 64;
    const float* xp = xs_base + j0;
    const float* ep = es_base + j0;
    if (!guard){
      f32x4v v = *(const f32x4v*)xp;
      B.sx4[0] = v[0]; B.sx4[1] = v[1]; B.sx4[2] = v[2]; B.sx4[3] = v[3];
#pragma unroll
      for (int u = 0; u < 4; ++u) B.se4[u] = ep[u];
    } else {
#pragma unroll
      for (int u = 0; u < 4; ++u){
        int c = j0 + lq4 + u;
        B.sx4[u] = (c < 2000) ? xp[u] : 0.f;
        B.se4[u] = (c < 1999) ? ep[u] : 0.f;
      }
    }
    const float* axp = xa_base + j0;
    const float* aep = ea_base + j0;
    if (!guard){
      f32x4v a0 = *(const f32x4v*)axp;
      f32x4v a1 = *(const f32x4v*)(axp + 4);
      f32x4v a2 = *(const f32x4v*)(axp + 32);
      f32x4v a3 = *(const f32x4v*)(axp + 36);
#pragma unroll
      for (int u = 0; u < 4; ++u){
        B.ax[u] = a0[u]; B.ax[4+u] = a1[u]; B.ax[8+u] = a2[u]; B.ax[12+u] = a3[u];
      }
#pragma unroll
      for (int u = 0; u < 8; ++u){ B.ae[u] = aep[u]; B.ae[8+u] = aep[32 + u]; }
    } else {
#pragma unroll
      for (int u = 0; u < 8; ++u){
        int c0 = j0 + kgrp + u, c1 = c0 + 32;
        B.ax[u]   = (c0 < 2000) ? axp[u]      : 0.f;
        B.ax[8+u] = (c1 < 2000) ? axp[32 + u] : 0.f;
        B.ae[u]   = (c0 < 1999) ? aep[u]      : 0.f;
        B.ae[8+u] = (c1 < 1999) ? aep[32 + u] : 0.f;
      }
    }
    B.bf0 = *(const v8s*)(wf_base + j0);
    B.bf1 = *(const v8s*)(wf_base + j0 + 32);
    B.bd0 = *(const v8s*)(wd_base + j0);
    B.bd1 = *(const v8s*)(wd_base + j0 + 32);
  };

  auto computeChunk = [&](ChunkBuf& B, int ch, bool guard){
    const int j0 = ch * 64;
    // MFMA path: x via bf16 log-LUT, eta via cvt
    union U16 { v8s s; unsigned short u[8]; } ax0, ax1;
    union BU  { bf8v b; v8s s; } ae0, ae1;
#pragma unroll
    for (int u = 0; u < 8; ++u){
      ax0.u[u] = lutlog[(int)B.ax[u]];
      ax1.u[u] = lutlog[(int)B.ax[8+u]];
      ae0.b[u] = (__bf16)B.ae[u];
      ae1.b[u] = (__bf16)B.ae[8+u];
    }
    accz = __builtin_amdgcn_mfma_f32_16x16x32_bf16(ax0.s, B.bf0, accz, 0, 0, 0);
    accz = __builtin_amdgcn_mfma_f32_16x16x32_bf16(ax1.s, B.bf1, accz, 0, 0, 0);
    acct = __builtin_amdgcn_mfma_f32_16x16x32_bf16(ae0.s, B.bd0, acct, 0, 0, 0);
    acct = __builtin_amdgcn_mfma_f32_16x16x32_bf16(ae1.s, B.bd1, acct, 0, 0, 0);
    // scan path
    f32x4v cz = *(const f32x4v*)&c_lds[j0 + lq4];
    f32x4v az = *(const f32x4v*)&a_lds[j0 + lq4];
    float s0 = cz[0] * B.se4[0], s1 = cz[1] * B.se4[1];
    float s2 = cz[2] * B.se4[2], s3 = cz[3] * B.se4[3];
    float run = s0 + s1 + s2 + s3;
    float p1 = s0, p2 = s0 + s1, p3 = s0 + s1 + s2;
    float tot = run;
#pragma unroll
    for (int d = 1; d < 16; d <<= 1){
      float o = __shfl_up(tot, d, 16);
      if (sl >= d) tot += o;
    }
    float excl = tot - run;
    float base = carry + excl;
    carry += __shfl(tot, 15, 16);
    float lg0 = az[0] * B.se4[0] - base;
    float lg1 = az[1] * B.se4[1] - (base + p1);
    float lg2 = az[2] * B.se4[2] - (base + p2);
    float lg3 = az[3] * B.se4[3] - (base + p3);
    if (!guard){
      float cm = fmaxf(fmaxf(lg0, lg1), fmaxf(lg2, lg3));
      if (cm > mOn){ sOn *= __expf(mOn - cm); mOn = cm; }
      sOn += __expf(lg0 - mOn) + __expf(lg1 - mOn) + __expf(lg2 - mOn) + __expf(lg3 - mOn);
      xdot = fmaf(B.sx4[0], lg0, xdot);
      xdot = fmaf(B.sx4[1], lg1, xdot);
      xdot = fmaf(B.sx4[2], lg2, xdot);
      xdot = fmaf(B.sx4[3], lg3, xdot);
    } else {
      int nvalid = 2000 - (j0 + lq4);
      float cm = -3.0e38f;
      if (0 < nvalid) cm = fmaxf(cm, lg0);
      if (1 < nvalid) cm = fmaxf(cm, lg1);
      if (2 < nvalid) cm = fmaxf(cm, lg2);
      if (3 < nvalid) cm = fmaxf(cm, lg3);
      if (cm > mOn){ sOn *= __expf(mOn - cm); mOn = cm; }
      if (0 < nvalid){ sOn += __expf(lg0 - mOn); xdot = fmaf(B.sx4[0], lg0, xdot); }
      if (1 < nvalid){ sOn += __expf(lg1 - mOn); xdot = fmaf(B.sx4[1], lg1, xdot); }
      if (2 < nvalid){ sOn += __expf(lg2 - mOn); xdot = fmaf(B.sx4[2], lg2, xdot); }
      if (3 < nvalid){ sOn += __expf(lg3 - mOn); xdot = fmaf(B.sx4[3], lg3, xdot); }
    }
#pragma unroll
    for (int u = 0; u < 4; ++u){
      sx += B.sx4[u];
      sgl += lutlg[(int)B.sx4[u]];
      e2 = fmaf(B.se4[u], B.se4[u], e2);
    }
  };

  ChunkBuf bufA, bufB;
  loadChunk(bufA, 0, false);
#pragma unroll 1
  for (int ch = 0; ch < 30; ch += 2){
    loadChunk(bufB, ch + 1, false);
    computeChunk(bufA, ch, false);
    loadChunk(bufA, ch + 2, false);
    computeChunk(bufB, ch + 1, false);
  }
  loadChunk(bufB, 31, true);
  computeChunk(bufA, 30, false);
  computeChunk(bufB, 31, true);

  // ---- epilogue ----
  {
    int r0 = (lan >> 4) * 4;
#pragma unroll
    for (int r = 0; r < 4; ++r){
      z_l[r0 + r][bcol] = accz[r];
      t_l[r0 + r][bcol] = acct[r];
    }
  }
  __syncthreads();

  float z4[4], t4[4];
  {
    f32x4v zv = *(const f32x4v*)&z_l[lrow][lq4];
    f32x4v tv = *(const f32x4v*)&t_l[lrow][lq4];
#pragma unroll
    for (int u = 0; u < 4; ++u){ z4[u] = zv[u]; t4[u] = tv[u]; }
  }
  float zz = 0.f, tz = 0.f;
#pragma unroll
  for (int u = 0; u < 4; ++u){ zz = fmaf(z4[u], z4[u], zz); tz = fmaf(t4[u], z4[u], tz); }
  float gz[4] = {0.f, 0.f, 0.f, 0.f};
#pragma unroll 8
  for (int q = 0; q < 64; ++q){
    float zq = z_l[lrow][q];
    f32x4v g = *(const f32x4v*)&Gws[q * 64 + lq4];   // G symmetric; L2-hot
#pragma unroll
    for (int u = 0; u < 4; ++u) gz[u] = fmaf(g[u], zq, gz[u]);
  }
  float zGz = 0.f;
#pragma unroll
  for (int u = 0; u < 4; ++u) zGz = fmaf(z4[u], gz[u], zGz);
  float tk[4];
#pragma unroll
  for (int u = 0; u < 4; ++u){ tk[u] = t4[u] - gz[u]; t_l[lrow][lq4 + u] = tk[u]; }
  float sol[4] = {0.f, 0.f, 0.f, 0.f};
#pragma unroll 8
  for (int q = 0; q < 64; ++q){
    float tq = t_l[lrow][q];
    f32x4v g = *(const f32x4v*)&Minv[q * 64 + lq4];  // Minv symmetric; L2-hot
#pragma unroll
    for (int u = 0; u < 4; ++u) sol[u] = fmaf(g[u], tq, sol[u]);
  }
  float ts = 0.f;
#pragma unroll
  for (int u = 0; u < 4; ++u) ts = fmaf(tk[u], sol[u], ts);

  zz = red16(zz); tz = red16(tz); zGz = red16(zGz); ts = red16(ts);
  xdot = red16(xdot); sx = red16(sx); sgl = red16(sgl); e2 = red16(e2);
#pragma unroll
  for (int d = 1; d < 16; d <<= 1){
    float om = __shfl_xor(mOn, d, 16);
    float os = __shfl_xor(sOn, d, 16);
    float nm = fmaxf(mOn, om);
    sOn = sOn * __expf(mOn - nm) + os * __expf(om - nm);
    mOn = nm;
  }
  if (sl == 0){
    int b = b0 + lrow;
    float lse = mOn + logf(sOn);
    mult_out[b] = lgammaf(sx + 1.f) - sgl + xdot - sx * lse;
    float var = expf(lss[0]);
    float logdet = misc[0];
    float diff2 = e2 - 2.f * tz + zGz;
    float quad = diff2 / var - ts / (var * var);
    lp_out[b] = -0.5f * (1999.f * LOG2PI_F + logdet + quad) - 0.5f * zz;
  }
}

// ---------------- Z: final mean + constants ----------------
__global__ __launch_bounds__(256) void reduce_kernel(const float* __restrict__ mult,
    const float* __restrict__ lp, float* __restrict__ out){
  __shared__ double red[4];
  int tid = threadIdx.x;
  double acc = 0.0;
  for (int b = tid; b < 8192; b += 256)
    acc += (double)mult[b] + (double)lp[b];
#pragma unroll
  for (int m = 1; m < 64; m <<= 1) acc += __shfl_xor(acc, m, 64);
  if ((tid & 63) == 0) red[tid >> 6] = acc;
  __syncthreads();
  if (tid == 0){
    double tot = red[0] + red[1] + red[2] + red[3];
    double mean = tot / 8192.0;
    double loss = -(mean - 0.5 * 64.0 * 1.8378770664093453);
    out[0] = (float)loss;
  }
}

extern "C" void kernel_launch(void* const* d_in, const int* in_sizes, int n_in,
                              void* d_out, int out_size, void* d_ws, size_t ws_size,
                              hipStream_t stream){
  const float* x    = (const float*)d_in[0];
  const float* Psi  = (const float*)d_in[1];
  const float* Wenc = (const float*)d_in[2];
  const float* Wdec = (const float*)d_in[3];
  const float* vlv  = (const float*)d_in[4];
  const float* lss  = (const float*)d_in[5];
  const float* eta  = (const float*)d_in[6];
  float* ws = (float*)d_ws;
  float*  a_ws  = ws + OFF_A;
  float*  c_ws  = ws + OFF_C;
  __bf16* weffb = (__bf16*)(ws + OFF_WEFFB);
  __bf16* wdtb  = (__bf16*)(ws + OFF_WDTB);
  float*  Gws   = ws + OFF_G;
  float*  Minv  = ws + OFF_MINV;
  float*  misc  = ws + OFF_MISC;
  float*  gpart = ws + OFF_GPART;
  float*  multw = ws + OFF_MULT;
  float*  lpw   = ws + OFF_LP;

  coef_kernel<<<8, 256, 0, stream>>>(Psi, a_ws, c_ws);
  wenceff_kernel<<<64, 256, 0, stream>>>(Wenc, a_ws, c_ws, weffb);
  wdtgram_kernel<<<32, 256, 0, stream>>>(Wdec, wdtb, gpart);
  neumann_kernel<<<1, 256, 0, stream>>>(gpart, vlv, lss, Gws, Minv, misc);
  mega_kernel<<<512, 256, 0, stream>>>(x, eta, (const short*)weffb, (const short*)wdtb,
                                       a_ws, c_ws, Gws, Minv, misc, lss, multw, lpw);
  reduce_kernel<<<1, 256, 0, stream>>>(multw, lpw, (float*)d_out);
}

// Round 8
// 129.689 us; speedup vs baseline: 1.3071x; 1.0337x over previous
//
#include <hip/hip_runtime.h>
#include <math.h>

// LinearCatVAE loss on MI355X.
// Psi = Helmert basis => Psi products are diag + prefix scans.
// R4: barrier-free fused mega (bf16 MFMA z,t + fp32 scan/LSE + Woodbury quad).
// R6: no-spill config (VGPR 108), but occupancy grid-capped: 512 blocks x 4
// waves = 8 waves/CU only.
// R7: 512-thread blocks, chunk-split halves: waves 0-3 do chunks 0-15,
// waves 4-7 do chunks 16-31 (same 16 rows). Sequential Helmert prefix fixed
// up exactly in the epilogue (carry1 shift: m1-=c, xdot1-=c*sx1, s1 invar).
// 2 blocks/CU x 8 waves = 16 waves/CU (~50% occ, 2x R6). Prep fused to one
// kernel (4 launches total).

#define LOG2PI_F 1.8378770664093453f

typedef short  v8s    __attribute__((ext_vector_type(8)));
typedef float  f32x4v __attribute__((ext_vector_type(4)));
typedef __bf16 bf8v   __attribute__((ext_vector_type(8)));

// ---- workspace offsets (floats) ----
#define OFF_A     0          // 2048
#define OFF_C     2048       // 2048
#define OFF_WEFFB 4096       // 64*2048 bf16 = 65536 floats
#define OFF_WDTB  69632      // 65536 floats
#define OFF_G     135168     // 4096
#define OFF_MINV  139264     // 4096
#define OFF_MISC  143360     // 64
#define OFF_GPART 143424     // 131072
#define OFF_MULT  274496     // 8192
#define OFF_LP    282688     // 8192

__device__ inline float red16(float v){
#pragma unroll
  for (int m = 1; m < 16; m <<= 1) v += __shfl_xor(v, m, 16);
  return v;
}

// ------- PREP (fused): blocks 0-7 coef, 8-71 wenceff, 72-103 wdtgram -------
__global__ __launch_bounds__(256) void prep_kernel(const float* __restrict__ Psi,
    const float* __restrict__ Wenc, const float* __restrict__ Wdec,
    float* __restrict__ a_ws, float* __restrict__ c_ws,
    __bf16* __restrict__ weffb, __bf16* __restrict__ wdtb,
    float* __restrict__ gparts){
  __shared__ __align__(16) float shm[4160];
  const int tid = threadIdx.x;
  const int blk = blockIdx.x;
  if (blk < 8){
    int e = blk * 256 + tid;
    float a = 0.f, c = 0.f;
    if (e < 1999){
      a = Psi[(size_t)e * 2001];
      c = -Psi[(size_t)e * 2001 + 1];
    }
    a_ws[e] = a;
    c_ws[e] = c;
    return;
  }
  if (blk < 72){
    // wenceff: weffb[k][j] = bf16((Wenc @ Psi)[k][j]) via exclusive scan
    float* scan = shm;
    int k = blk - 8;
    const float* wrow = Wenc + (size_t)k * 1999;
    int base = tid * 8;
    float w[8], sloc[8], av[8];
    float run = 0.f;
#pragma unroll
    for (int u = 0; u < 8; ++u){
      int e = base + u;
      bool v = (e < 1999);
      float wv = v ? wrow[e] : 0.f;
      av[u] = v ? Psi[(size_t)e * 2001] : 0.f;
      float cv = v ? -Psi[(size_t)e * 2001 + 1] : 0.f;
      w[u] = wv;
      sloc[u] = run;
      run += cv * wv;
    }
    scan[tid] = run;
    __syncthreads();
    for (int off = 1; off < 256; off <<= 1){
      float y = (tid >= off) ? scan[tid - off] : 0.f;
      __syncthreads();
      scan[tid] += y;
      __syncthreads();
    }
    float excl = scan[tid] - run;
#pragma unroll
    for (int u = 0; u < 8; ++u){
      int e = base + u;
      float val = (e < 2000) ? (av[u] * w[u] - (excl + sloc[u])) : 0.f;
      weffb[(size_t)k * 2048 + e] = (__bf16)val;
    }
    return;
  }
  // wdtgram: wdtb[k][j] = bf16(Wdec[j][k]) AND gram partials
  auto Ws = (float(*)[64])shm;
  int j0 = (blk - 72) * 64;
#pragma unroll
  for (int i = 0; i < 16; ++i){
    int e = tid + i * 256;
    int j = e >> 6, kk = e & 63;
    Ws[j][kk] = (j0 + j < 1999) ? Wdec[(size_t)(j0 + j) * 64 + kk] : 0.f;
  }
  __syncthreads();
#pragma unroll
  for (int i = 0; i < 16; ++i){
    int e = tid + i * 256; int kk = e >> 6, j = e & 63;
    wdtb[(size_t)kk * 2048 + j0 + j] = (__bf16)Ws[j][kk];
  }
  int p = tid & 63;
  int qb = (tid >> 6) * 16;
  float acc[16] = {};
  for (int jj = 0; jj < 64; ++jj){
    float wp = Ws[jj][p];
    const float4 q0 = *(const float4*)&Ws[jj][qb];
    const float4 q1 = *(const float4*)&Ws[jj][qb + 4];
    const float4 q2 = *(const float4*)&Ws[jj][qb + 8];
    const float4 q3 = *(const float4*)&Ws[jj][qb + 12];
    acc[0]  = fmaf(wp, q0.x, acc[0]);  acc[1]  = fmaf(wp, q0.y, acc[1]);
    acc[2]  = fmaf(wp, q0.z, acc[2]);  acc[3]  = fmaf(wp, q0.w, acc[3]);
    acc[4]  = fmaf(wp, q1.x, acc[4]);  acc[5]  = fmaf(wp, q1.y, acc[5]);
    acc[6]  = fmaf(wp, q1.z, acc[6]);  acc[7]  = fmaf(wp, q1.w, acc[7]);
    acc[8]  = fmaf(wp, q2.x, acc[8]);  acc[9]  = fmaf(wp, q2.y, acc[9]);
    acc[10] = fmaf(wp, q2.z, acc[10]); acc[11] = fmaf(wp, q2.w, acc[11]);
    acc[12] = fmaf(wp, q3.x, acc[12]); acc[13] = fmaf(wp, q3.y, acc[13]);
    acc[14] = fmaf(wp, q3.z, acc[14]); acc[15] = fmaf(wp, q3.w, acc[15]);
  }
  float* gp = gparts + (size_t)(blk - 72) * 4096 + (size_t)p * 64 + qb;
#pragma unroll
  for (int u = 0; u < 4; ++u){
    float4 o; o.x = acc[4*u]; o.y = acc[4*u+1]; o.z = acc[4*u+2]; o.w = acc[4*u+3];
    *(float4*)&gp[4*u] = o;
  }
}

// ---- P3: gram reduce + Minv + logdet (Neumann truncated at A^2) ----
__global__ __launch_bounds__(256) void neumann_kernel(const float* __restrict__ gparts,
    const float* __restrict__ vlv, const float* __restrict__ lss,
    float* __restrict__ Gws, float* __restrict__ Minv, float* __restrict__ misc){
  __shared__ float As[64][65];
  __shared__ float A2s[64][65];
  __shared__ double dred[4][3];
  int tid = threadIdx.x;
  float var = expf(lss[0]);
  for (int e = tid; e < 4096; e += 256){
    int i = e >> 6;
    float s = 0.f;
#pragma unroll
    for (int p = 0; p < 32; ++p) s += gparts[(size_t)p * 4096 + e];
    Gws[e] = s;
    As[i][e & 63] = expf(vlv[i]) * s / var;
  }
  __syncthreads();
  for (int e = tid; e < 4096; e += 256){
    int i = e >> 6, j = e & 63;
    float s = 0.f;
    for (int q = 0; q < 64; ++q) s = fmaf(As[i][q], As[q][j], s);
    A2s[i][j] = s;
  }
  __syncthreads();
  double t1 = 0, t2 = 0, t3 = 0;
  for (int e = tid; e < 4096; e += 256){
    int i = e >> 6, j = e & 63;
    if (i == j){ t1 += (double)As[i][i]; t2 += (double)A2s[i][i]; }
    t3 += (double)A2s[i][j] * (double)As[j][i];
  }
#pragma unroll
  for (int m = 1; m < 64; m <<= 1){
    t1 += __shfl_xor(t1, m, 64); t2 += __shfl_xor(t2, m, 64); t3 += __shfl_xor(t3, m, 64);
  }
  int wid = tid >> 6;
  if ((tid & 63) == 0){ dred[wid][0] = t1; dred[wid][1] = t2; dred[wid][2] = t3; }
  __syncthreads();
  for (int e = tid; e < 4096; e += 256){
    int i = e >> 6, j = e & 63;
    float v = ((i == j) ? 1.f : 0.f) - As[i][j] + A2s[i][j];
    Minv[e] = v * expf(vlv[j]);
  }
  if (tid == 0){
    double tr1 = 0, tr2 = 0, tr3 = 0;
    for (int w2 = 0; w2 < 4; ++w2){
      tr1 += dred[w2][0]; tr2 += dred[w2][1]; tr3 += dred[w2][2];
    }
    misc[0] = (float)(1999.0 * (double)lss[0] + tr1 - tr2 / 2.0 + tr3 / 3.0);
  }
}

// ---------------- MEGA: chunk-split fused pass over x,eta ----------------
// 512 blocks x 512 threads; 16 rows/block; waves 0-3: chunks 0-15,
// waves 4-7: chunks 16-31. Helmert carry fixed up in epilogue.
struct ChunkBuf {
  float sx4[4];   // scan x
  float se4[4];   // scan eta
  float ax[16];   // MFMA A-frag x (2 k-halves)
  float ae[16];   // MFMA A-frag eta
  v8s bf0, bf1;   // B-frag Weff (bf16)
  v8s bd0, bd1;   // B-frag WdT (bf16)
};

__global__ __launch_bounds__(512) void mega_kernel(
    const float* __restrict__ x, const float* __restrict__ eta,
    const short* __restrict__ wfB, const short* __restrict__ wdB,
    const float* __restrict__ a_ws, const float* __restrict__ c_ws,
    const float* __restrict__ Gws, const float* __restrict__ Minv,
    const float* __restrict__ misc, const float* __restrict__ lss,
    float* __restrict__ mult_out, float* __restrict__ lp_out)
{
  __shared__ unsigned short lutlog[128];           // bf16 bits of log(i+1)
  __shared__ float lutlg[128];
  __shared__ __align__(16) float a_lds[2048];
  __shared__ __align__(16) float c_lds[2048];
  __shared__ __align__(16) float z_l[2][16][68];
  __shared__ __align__(16) float t_l[2][16][68];
  __shared__ float sc_carry[2][16], sc_m[2][16], sc_s[2][16], sc_xd[2][16],
                   sc_sx[2][16], sc_sgl[2][16], sc_e2[2][16];

  const int tid = threadIdx.x;
  const int b0 = blockIdx.x * 16;
  const int half = tid >> 8;                 // 0: chunks 0-15, 1: chunks 16-31
  if (tid < 128){
    union { __bf16 b; unsigned short u; } cv;
    cv.b = (__bf16)logf((float)(tid + 1));
    lutlog[tid] = cv.u;
    lutlg[tid] = lgammaf((float)(tid + 1));
  }
  for (int i = tid; i < 2048; i += 512){ a_lds[i] = a_ws[i]; c_lds[i] = c_ws[i]; }

  // roles
  const int lrow = (tid >> 4) & 15;          // scan row 0..15
  const int sl   = tid & 15;                 // scan lane
  const int lq4  = sl * 4;                   // 4 cols/lane
  const int wid  = tid >> 6, lan = tid & 63;
  const int arow = lan & 15;                 // MFMA A row
  const int bcol = (wid & 3) * 16 + (lan & 15);  // MFMA B col (output col)
  const int kgrp = (lan >> 4) * 8;           // k-offset within 32-half

  __syncthreads();  // luts ready

  f32x4v accz = {0.f, 0.f, 0.f, 0.f}, acct = {0.f, 0.f, 0.f, 0.f};
  float carry = 0.f, mOn = -3.0e38f, sOn = 0.f;
  float xdot = 0.f, sx = 0.f, sgl = 0.f, e2 = 0.f;

  const float* xs_base = x   + (size_t)(b0 + lrow) * 2000 + lq4;
  const float* es_base = eta + (size_t)(b0 + lrow) * 1999 + lq4;
  const float* xa_base = x   + (size_t)(b0 + arow) * 2000 + kgrp;
  const float* ea_base = eta + (size_t)(b0 + arow) * 1999 + kgrp;
  const short* wf_base = wfB + (size_t)bcol * 2048 + kgrp;
  const short* wd_base = wdB + (size_t)bcol * 2048 + kgrp;

  auto loadChunk = [&](ChunkBuf& B, int ch, bool guard){
    const int j0 = ch * 64;
    const float* xp = xs_base + j0;
    const float* ep = es_base + j0;
    if (!guard){
      f32x4v v = *(const f32x4v*)xp;
      B.sx4[0] = v[0]; B.sx4[1] = v[1]; B.sx4[2] = v[2]; B.sx4[3] = v[3];
#pragma unroll
      for (int u = 0; u < 4; ++u) B.se4[u] = ep[u];
    } else {
#pragma unroll
      for (int u = 0; u < 4; ++u){
        int c = j0 + lq4 + u;
        B.sx4[u] = (c < 2000) ? xp[u] : 0.f;
        B.se4[u] = (c < 1999) ? ep[u] : 0.f;
      }
    }
    const float* axp = xa_base + j0;
    const float* aep = ea_base + j0;
    if (!guard){
      f32x4v a0 = *(const f32x4v*)axp;
      f32x4v a1 = *(const f32x4v*)(axp + 4);
      f32x4v a2 = *(const f32x4v*)(axp + 32);
      f32x4v a3 = *(const f32x4v*)(axp + 36);
#pragma unroll
      for (int u = 0; u < 4; ++u){
        B.ax[u] = a0[u]; B.ax[4+u] = a1[u]; B.ax[8+u] = a2[u]; B.ax[12+u] = a3[u];
      }
#pragma unroll
      for (int u = 0; u < 8; ++u){ B.ae[u] = aep[u]; B.ae[8+u] = aep[32 + u]; }
    } else {
#pragma unroll
      for (int u = 0; u < 8; ++u){
        int c0 = j0 + kgrp + u, c1 = c0 + 32;
        B.ax[u]   = (c0 < 2000) ? axp[u]      : 0.f;
        B.ax[8+u] = (c1 < 2000) ? axp[32 + u] : 0.f;
        B.ae[u]   = (c0 < 1999) ? aep[u]      : 0.f;
        B.ae[8+u] = (c1 < 1999) ? aep[32 + u] : 0.f;
      }
    }
    B.bf0 = *(const v8s*)(wf_base + j0);
    B.bf1 = *(const v8s*)(wf_base + j0 + 32);
    B.bd0 = *(const v8s*)(wd_base + j0);
    B.bd1 = *(const v8s*)(wd_base + j0 + 32);
  };

  auto computeChunk = [&](ChunkBuf& B, int ch, bool guard){
    const int j0 = ch * 64;
    union U16 { v8s s; unsigned short u[8]; } ax0, ax1;
    union BU  { bf8v b; v8s s; } ae0, ae1;
#pragma unroll
    for (int u = 0; u < 8; ++u){
      ax0.u[u] = lutlog[(int)B.ax[u]];
      ax1.u[u] = lutlog[(int)B.ax[8+u]];
      ae0.b[u] = (__bf16)B.ae[u];
      ae1.b[u] = (__bf16)B.ae[8+u];
    }
    accz = __builtin_amdgcn_mfma_f32_16x16x32_bf16(ax0.s, B.bf0, accz, 0, 0, 0);
    accz = __builtin_amdgcn_mfma_f32_16x16x32_bf16(ax1.s, B.bf1, accz, 0, 0, 0);
    acct = __builtin_amdgcn_mfma_f32_16x16x32_bf16(ae0.s, B.bd0, acct, 0, 0, 0);
    acct = __builtin_amdgcn_mfma_f32_16x16x32_bf16(ae1.s, B.bd1, acct, 0, 0, 0);
    // scan path (local prefix within this half; carry1 fixup in epilogue)
    f32x4v cz = *(const f32x4v*)&c_lds[j0 + lq4];
    f32x4v az = *(const f32x4v*)&a_lds[j0 + lq4];
    float s0 = cz[0] * B.se4[0], s1 = cz[1] * B.se4[1];
    float s2 = cz[2] * B.se4[2], s3 = cz[3] * B.se4[3];
    float run = s0 + s1 + s2 + s3;
    float p1 = s0, p2 = s0 + s1, p3 = s0 + s1 + s2;
    float tot = run;
#pragma unroll
    for (int d = 1; d < 16; d <<= 1){
      float o = __shfl_up(tot, d, 16);
      if (sl >= d) tot += o;
    }
    float excl = tot - run;
    float base = carry + excl;
    carry += __shfl(tot, 15, 16);
    float lg0 = az[0] * B.se4[0] - base;
    float lg1 = az[1] * B.se4[1] - (base + p1);
    float lg2 = az[2] * B.se4[2] - (base + p2);
    float lg3 = az[3] * B.se4[3] - (base + p3);
    if (!guard){
      float cm = fmaxf(fmaxf(lg0, lg1), fmaxf(lg2, lg3));
      if (cm > mOn){ sOn *= __expf(mOn - cm); mOn = cm; }
      sOn += __expf(lg0 - mOn) + __expf(lg1 - mOn) + __expf(lg2 - mOn) + __expf(lg3 - mOn);
      xdot = fmaf(B.sx4[0], lg0, xdot);
      xdot = fmaf(B.sx4[1], lg1, xdot);
      xdot = fmaf(B.sx4[2], lg2, xdot);
      xdot = fmaf(B.sx4[3], lg3, xdot);
    } else {
      int nvalid = 2000 - (j0 + lq4);
      float cm = -3.0e38f;
      if (0 < nvalid) cm = fmaxf(cm, lg0);
      if (1 < nvalid) cm = fmaxf(cm, lg1);
      if (2 < nvalid) cm = fmaxf(cm, lg2);
      if (3 < nvalid) cm = fmaxf(cm, lg3);
      if (cm > mOn){ sOn *= __expf(mOn - cm); mOn = cm; }
      if (0 < nvalid){ sOn += __expf(lg0 - mOn); xdot = fmaf(B.sx4[0], lg0, xdot); }
      if (1 < nvalid){ sOn += __expf(lg1 - mOn); xdot = fmaf(B.sx4[1], lg1, xdot); }
      if (2 < nvalid){ sOn += __expf(lg2 - mOn); xdot = fmaf(B.sx4[2], lg2, xdot); }
      if (3 < nvalid){ sOn += __expf(lg3 - mOn); xdot = fmaf(B.sx4[3], lg3, xdot); }
    }
#pragma unroll
    for (int u = 0; u < 4; ++u){
      sx += B.sx4[u];
      sgl += lutlg[(int)B.sx4[u]];
      e2 = fmaf(B.se4[u], B.se4[u], e2);
    }
  };

  const int ch0 = half * 16;
  const bool lastGuard = (half == 1);
  ChunkBuf bufA, bufB;
  loadChunk(bufA, ch0, false);
#pragma unroll 1
  for (int i = 0; i < 14; i += 2){
    loadChunk(bufB, ch0 + i + 1, false);
    computeChunk(bufA, ch0 + i, false);
    loadChunk(bufA, ch0 + i + 2, false);
    computeChunk(bufB, ch0 + i + 1, false);
  }
  loadChunk(bufB, ch0 + 15, lastGuard);
  computeChunk(bufA, ch0 + 14, false);
  computeChunk(bufB, ch0 + 15, lastGuard);

  // ---- per-half reductions ----
  xdot = red16(xdot); sx = red16(sx); sgl = red16(sgl); e2 = red16(e2);
#pragma unroll
  for (int d = 1; d < 16; d <<= 1){
    float om = __shfl_xor(mOn, d, 16);
    float os = __shfl_xor(sOn, d, 16);
    float nm = fmaxf(mOn, om);
    sOn = sOn * __expf(mOn - nm) + os * __expf(om - nm);
    mOn = nm;
  }
  // ---- write frags + per-half scalars ----
  {
    int r0 = (lan >> 4) * 4;
#pragma unroll
    for (int r = 0; r < 4; ++r){
      z_l[half][r0 + r][bcol] = accz[r];
      t_l[half][r0 + r][bcol] = acct[r];
    }
  }
  if (sl == 0){
    sc_carry[half][lrow] = carry;
    sc_m[half][lrow] = mOn;  sc_s[half][lrow] = sOn;
    sc_xd[half][lrow] = xdot; sc_sx[half][lrow] = sx;
    sc_sgl[half][lrow] = sgl; sc_e2[half][lrow] = e2;
  }
  __syncthreads();

  // ---- epilogue: combine halves, per-row quad (waves 0-3 only) ----
  if (tid < 256){
    float z4[4], t4[4];
#pragma unroll
    for (int u = 0; u < 4; ++u){
      z4[u] = z_l[0][lrow][lq4 + u] + z_l[1][lrow][lq4 + u];
      t4[u] = t_l[0][lrow][lq4 + u] + t_l[1][lrow][lq4 + u];
      z_l[0][lrow][lq4 + u] = z4[u];   // combined, same-wave lockstep use
    }
    float zz = 0.f, tz = 0.f;
#pragma unroll
    for (int u = 0; u < 4; ++u){ zz = fmaf(z4[u], z4[u], zz); tz = fmaf(t4[u], z4[u], tz); }
    float gz[4] = {0.f, 0.f, 0.f, 0.f};
#pragma unroll 8
    for (int q = 0; q < 64; ++q){
      float zq = z_l[0][lrow][q];
      f32x4v g = *(const f32x4v*)&Gws[q * 64 + lq4];   // G symmetric; L2-hot
#pragma unroll
      for (int u = 0; u < 4; ++u) gz[u] = fmaf(g[u], zq, gz[u]);
    }
    float zGz = 0.f;
#pragma unroll
    for (int u = 0; u < 4; ++u) zGz = fmaf(z4[u], gz[u], zGz);
    float tk[4];
#pragma unroll
    for (int u = 0; u < 4; ++u){ tk[u] = t4[u] - gz[u]; t_l[0][lrow][lq4 + u] = tk[u]; }
    float sol[4] = {0.f, 0.f, 0.f, 0.f};
#pragma unroll 8
    for (int q = 0; q < 64; ++q){
      float tq = t_l[0][lrow][q];
      f32x4v g = *(const f32x4v*)&Minv[q * 64 + lq4];  // Minv symmetric; L2-hot
#pragma unroll
      for (int u = 0; u < 4; ++u) sol[u] = fmaf(g[u], tq, sol[u]);
    }
    float ts = 0.f;
#pragma unroll
    for (int u = 0; u < 4; ++u) ts = fmaf(tk[u], sol[u], ts);

    zz = red16(zz); tz = red16(tz); zGz = red16(zGz); ts = red16(ts);
    if (sl == 0){
      // merge the two halves' scan scalars with carry1 fixup
      float carry1 = sc_carry[0][lrow];
      float m0 = sc_m[0][lrow],            s0v = sc_s[0][lrow];
      float m1 = sc_m[1][lrow] - carry1,   s1v = sc_s[1][lrow];
      float M = fmaxf(m0, m1);
      float S = s0v * __expf(m0 - M) + s1v * __expf(m1 - M);
      float lse = M + logf(S);
      float xdT = sc_xd[0][lrow] + sc_xd[1][lrow] - carry1 * sc_sx[1][lrow];
      float sxT = sc_sx[0][lrow] + sc_sx[1][lrow];
      float sglT = sc_sgl[0][lrow] + sc_sgl[1][lrow];
      float e2T = sc_e2[0][lrow] + sc_e2[1][lrow];
      int b = b0 + lrow;
      mult_out[b] = lgammaf(sxT + 1.f) - sglT + xdT - sxT * lse;
      float var = expf(lss[0]);
      float logdet = misc[0];
      float diff2 = e2T - 2.f * tz + zGz;
      float quad = diff2 / var - ts / (var * var);
      lp_out[b] = -0.5f * (1999.f * LOG2PI_F + logdet + quad) - 0.5f * zz;
    }
  }
}

// ---------------- Z: final mean + constants ----------------
__global__ __launch_bounds__(256) void reduce_kernel(const float* __restrict__ mult,
    const float* __restrict__ lp, float* __restrict__ out){
  __shared__ double red[4];
  int tid = threadIdx.x;
  double acc = 0.0;
  for (int b = tid; b < 8192; b += 256)
    acc += (double)mult[b] + (double)lp[b];
#pragma unroll
  for (int m = 1; m < 64; m <<= 1) acc += __shfl_xor(acc, m, 64);
  if ((tid & 63) == 0) red[tid >> 6] = acc;
  __syncthreads();
  if (tid == 0){
    double tot = red[0] + red[1] + red[2] + red[3];
    double mean = tot / 8192.0;
    double loss = -(mean - 0.5 * 64.0 * 1.8378770664093453);
    out[0] = (float)loss;
  }
}

extern "C" void kernel_launch(void* const* d_in, const int* in_sizes, int n_in,
                              void* d_out, int out_size, void* d_ws, size_t ws_size,
                              hipStream_t stream){
  const float* x    = (const float*)d_in[0];
  const float* Psi  = (const float*)d_in[1];
  const float* Wenc = (const float*)d_in[2];
  const float* Wdec = (const float*)d_in[3];
  const float* vlv  = (const float*)d_in[4];
  const float* lss  = (const float*)d_in[5];
  const float* eta  = (const float*)d_in[6];
  float* ws = (float*)d_ws;
  float*  a_ws  = ws + OFF_A;
  float*  c_ws  = ws + OFF_C;
  __bf16* weffb = (__bf16*)(ws + OFF_WEFFB);
  __bf16* wdtb  = (__bf16*)(ws + OFF_WDTB);
  float*  Gws   = ws + OFF_G;
  float*  Minv  = ws + OFF_MINV;
  float*  misc  = ws + OFF_MISC;
  float*  gpart = ws + OFF_GPART;
  float*  multw = ws + OFF_MULT;
  float*  lpw   = ws + OFF_LP;

  prep_kernel<<<104, 256, 0, stream>>>(Psi, Wenc, Wdec, a_ws, c_ws, weffb, wdtb, gpart);
  neumann_kernel<<<1, 256, 0, stream>>>(gpart, vlv, lss, Gws, Minv, misc);
  mega_kernel<<<512, 512, 0, stream>>>(x, eta, (const short*)weffb, (const short*)wdtb,
                                       a_ws, c_ws, Gws, Minv, misc, lss, multw, lpw);
  reduce_kernel<<<1, 256, 0, stream>>>(multw, lpw, (float*)d_out);
}

// Round 9
// 127.434 us; speedup vs baseline: 1.3302x; 1.0177x over previous
//
#include <hip/hip_runtime.h>
#include <math.h>

// LinearCatVAE loss on MI355X.
// Psi = Helmert basis => Psi products are diag + prefix scans.
// R4-R6: barrier-free fused mega (bf16 MFMA z,t + fp32 scan/LSE + quad).
// R7 (no change): 512-thr chunk-split block; waves not co-scheduled (occ 20%).
// R8: column-split across BLOCKS: 1024 x 256thr (split=bid&1 -> chunks 0-15 /
// 16-31), 4 blocks/CU x 4 waves = 16 waves/CU through the normal small-block
// scheduler path. Per-split z/t partials + scan scalars to ws; new fixup
// kernel merges halves (R7 carry algebra) + Woodbury quad.

#define LOG2PI_F 1.8378770664093453f

typedef short  v8s    __attribute__((ext_vector_type(8)));
typedef float  f32x4v __attribute__((ext_vector_type(4)));
typedef __bf16 bf8v   __attribute__((ext_vector_type(8)));

// ---- workspace offsets (floats) ----
#define OFF_A     0          // 2048
#define OFF_C     2048       // 2048
#define OFF_WEFFB 4096       // 65536
#define OFF_WDTB  69632     // 65536
#define OFF_G     135168    // 4096
#define OFF_MINV  139264    // 4096
#define OFF_MISC  143360    // 64
#define OFF_GPART 143424    // 131072 -> ends 274496
#define OFF_ZPART 274496    // 2*8192*64 = 1048576
#define OFF_TPART 1323072   // 1048576
#define OFF_SCAN  2371648   // 2*8192*8 = 131072
#define OFF_MULT  2502720   // 8192
#define OFF_LP    2510912   // 8192

__device__ inline float red16(float v){
#pragma unroll
  for (int m = 1; m < 16; m <<= 1) v += __shfl_xor(v, m, 16);
  return v;
}

// ------- PREP (fused): blocks 0-7 coef, 8-71 wenceff, 72-103 wdtgram -------
__global__ __launch_bounds__(256) void prep_kernel(const float* __restrict__ Psi,
    const float* __restrict__ Wenc, const float* __restrict__ Wdec,
    float* __restrict__ a_ws, float* __restrict__ c_ws,
    __bf16* __restrict__ weffb, __bf16* __restrict__ wdtb,
    float* __restrict__ gparts){
  __shared__ __align__(16) float shm[4160];
  const int tid = threadIdx.x;
  const int blk = blockIdx.x;
  if (blk < 8){
    int e = blk * 256 + tid;
    float a = 0.f, c = 0.f;
    if (e < 1999){
      a = Psi[(size_t)e * 2001];
      c = -Psi[(size_t)e * 2001 + 1];
    }
    a_ws[e] = a;
    c_ws[e] = c;
    return;
  }
  if (blk < 72){
    float* scan = shm;
    int k = blk - 8;
    const float* wrow = Wenc + (size_t)k * 1999;
    int base = tid * 8;
    float w[8], sloc[8], av[8];
    float run = 0.f;
#pragma unroll
    for (int u = 0; u < 8; ++u){
      int e = base + u;
      bool v = (e < 1999);
      float wv = v ? wrow[e] : 0.f;
      av[u] = v ? Psi[(size_t)e * 2001] : 0.f;
      float cv = v ? -Psi[(size_t)e * 2001 + 1] : 0.f;
      w[u] = wv;
      sloc[u] = run;
      run += cv * wv;
    }
    scan[tid] = run;
    __syncthreads();
    for (int off = 1; off < 256; off <<= 1){
      float y = (tid >= off) ? scan[tid - off] : 0.f;
      __syncthreads();
      scan[tid] += y;
      __syncthreads();
    }
    float excl = scan[tid] - run;
#pragma unroll
    for (int u = 0; u < 8; ++u){
      int e = base + u;
      float val = (e < 2000) ? (av[u] * w[u] - (excl + sloc[u])) : 0.f;
      weffb[(size_t)k * 2048 + e] = (__bf16)val;
    }
    return;
  }
  auto Ws = (float(*)[64])shm;
  int j0 = (blk - 72) * 64;
#pragma unroll
  for (int i = 0; i < 16; ++i){
    int e = tid + i * 256;
    int j = e >> 6, kk = e & 63;
    Ws[j][kk] = (j0 + j < 1999) ? Wdec[(size_t)(j0 + j) * 64 + kk] : 0.f;
  }
  __syncthreads();
#pragma unroll
  for (int i = 0; i < 16; ++i){
    int e = tid + i * 256; int kk = e >> 6, j = e & 63;
    wdtb[(size_t)kk * 2048 + j0 + j] = (__bf16)Ws[j][kk];
  }
  int p = tid & 63;
  int qb = (tid >> 6) * 16;
  float acc[16] = {};
  for (int jj = 0; jj < 64; ++jj){
    float wp = Ws[jj][p];
    const float4 q0 = *(const float4*)&Ws[jj][qb];
    const float4 q1 = *(const float4*)&Ws[jj][qb + 4];
    const float4 q2 = *(const float4*)&Ws[jj][qb + 8];
    const float4 q3 = *(const float4*)&Ws[jj][qb + 12];
    acc[0]  = fmaf(wp, q0.x, acc[0]);  acc[1]  = fmaf(wp, q0.y, acc[1]);
    acc[2]  = fmaf(wp, q0.z, acc[2]);  acc[3]  = fmaf(wp, q0.w, acc[3]);
    acc[4]  = fmaf(wp, q1.x, acc[4]);  acc[5]  = fmaf(wp, q1.y, acc[5]);
    acc[6]  = fmaf(wp, q1.z, acc[6]);  acc[7]  = fmaf(wp, q1.w, acc[7]);
    acc[8]  = fmaf(wp, q2.x, acc[8]);  acc[9]  = fmaf(wp, q2.y, acc[9]);
    acc[10] = fmaf(wp, q2.z, acc[10]); acc[11] = fmaf(wp, q2.w, acc[11]);
    acc[12] = fmaf(wp, q3.x, acc[12]); acc[13] = fmaf(wp, q3.y, acc[13]);
    acc[14] = fmaf(wp, q3.z, acc[14]); acc[15] = fmaf(wp, q3.w, acc[15]);
  }
  float* gp = gparts + (size_t)(blk - 72) * 4096 + (size_t)p * 64 + qb;
#pragma unroll
  for (int u = 0; u < 4; ++u){
    float4 o; o.x = acc[4*u]; o.y = acc[4*u+1]; o.z = acc[4*u+2]; o.w = acc[4*u+3];
    *(float4*)&gp[4*u] = o;
  }
}

// ---- P3: gram reduce + Minv + logdet (Neumann truncated at A^2) ----
__global__ __launch_bounds__(256) void neumann_kernel(const float* __restrict__ gparts,
    const float* __restrict__ vlv, const float* __restrict__ lss,
    float* __restrict__ Gws, float* __restrict__ Minv, float* __restrict__ misc){
  __shared__ float As[64][65];
  __shared__ float A2s[64][65];
  __shared__ double dred[4][3];
  int tid = threadIdx.x;
  float var = expf(lss[0]);
  for (int e = tid; e < 4096; e += 256){
    int i = e >> 6;
    float s = 0.f;
#pragma unroll
    for (int p = 0; p < 32; ++p) s += gparts[(size_t)p * 4096 + e];
    Gws[e] = s;
    As[i][e & 63] = expf(vlv[i]) * s / var;
  }
  __syncthreads();
  for (int e = tid; e < 4096; e += 256){
    int i = e >> 6, j = e & 63;
    float s = 0.f;
    for (int q = 0; q < 64; ++q) s = fmaf(As[i][q], As[q][j], s);
    A2s[i][j] = s;
  }
  __syncthreads();
  double t1 = 0, t2 = 0, t3 = 0;
  for (int e = tid; e < 4096; e += 256){
    int i = e >> 6, j = e & 63;
    if (i == j){ t1 += (double)As[i][i]; t2 += (double)A2s[i][i]; }
    t3 += (double)A2s[i][j] * (double)As[j][i];
  }
#pragma unroll
  for (int m = 1; m < 64; m <<= 1){
    t1 += __shfl_xor(t1, m, 64); t2 += __shfl_xor(t2, m, 64); t3 += __shfl_xor(t3, m, 64);
  }
  int wid = tid >> 6;
  if ((tid & 63) == 0){ dred[wid][0] = t1; dred[wid][1] = t2; dred[wid][2] = t3; }
  __syncthreads();
  for (int e = tid; e < 4096; e += 256){
    int i = e >> 6, j = e & 63;
    float v = ((i == j) ? 1.f : 0.f) - As[i][j] + A2s[i][j];
    Minv[e] = v * expf(vlv[j]);
  }
  if (tid == 0){
    double tr1 = 0, tr2 = 0, tr3 = 0;
    for (int w2 = 0; w2 < 4; ++w2){
      tr1 += dred[w2][0]; tr2 += dred[w2][1]; tr3 += dred[w2][2];
    }
    misc[0] = (float)(1999.0 * (double)lss[0] + tr1 - tr2 / 2.0 + tr3 / 3.0);
  }
}

// ---------------- MEGA: column-split fused pass over x,eta ----------------
// 1024 blocks x 256 threads; split = bid&1 (chunks 0-15 / 16-31);
// rowblk = bid>>1 -> 16 rows. Partials to ws; merge in fixup_kernel.
struct ChunkBuf {
  float sx4[4];
  float se4[4];
  float ax[16];
  float ae[16];
  v8s bf0, bf1;
  v8s bd0, bd1;
};

__global__ __launch_bounds__(256) void mega_kernel(
    const float* __restrict__ x, const float* __restrict__ eta,
    const short* __restrict__ wfB, const short* __restrict__ wdB,
    const float* __restrict__ a_ws, const float* __restrict__ c_ws,
    float* __restrict__ zpart, float* __restrict__ tpart,
    float* __restrict__ scanw)
{
  __shared__ unsigned short lutlog[128];
  __shared__ float lutlg[128];
  __shared__ __align__(16) float a_lds[1024];
  __shared__ __align__(16) float c_lds[1024];
  __shared__ __align__(16) float z_l[16][68];
  __shared__ __align__(16) float t_l[16][68];

  const int tid = threadIdx.x;
  const int split = blockIdx.x & 1;
  const int rowblk = blockIdx.x >> 1;
  const int b0 = rowblk * 16;
  const int ch0 = split * 16;
  const int cb0 = split * 1024;          // column base
  if (tid < 128){
    union { __bf16 b; unsigned short u; } cv;
    cv.b = (__bf16)logf((float)(tid + 1));
    lutlog[tid] = cv.u;
    lutlg[tid] = lgammaf((float)(tid + 1));
  }
  for (int i = tid; i < 1024; i += 256){ a_lds[i] = a_ws[cb0 + i]; c_lds[i] = c_ws[cb0 + i]; }

  const int lrow = tid >> 4;
  const int sl   = tid & 15;
  const int lq4  = sl * 4;
  const int wid  = tid >> 6, lan = tid & 63;
  const int arow = lan & 15;
  const int bcol = wid * 16 + (lan & 15);
  const int kgrp = (lan >> 4) * 8;

  __syncthreads();

  f32x4v accz = {0.f, 0.f, 0.f, 0.f}, acct = {0.f, 0.f, 0.f, 0.f};
  float carry = 0.f, mOn = -3.0e38f, sOn = 0.f;
  float xdot = 0.f, sx = 0.f, sgl = 0.f, e2 = 0.f;

  const float* xs_base = x   + (size_t)(b0 + lrow) * 2000 + lq4;
  const float* es_base = eta + (size_t)(b0 + lrow) * 1999 + lq4;
  const float* xa_base = x   + (size_t)(b0 + arow) * 2000 + kgrp;
  const float* ea_base = eta + (size_t)(b0 + arow) * 1999 + kgrp;
  const short* wf_base = wfB + (size_t)bcol * 2048 + kgrp;
  const short* wd_base = wdB + (size_t)bcol * 2048 + kgrp;

  auto loadChunk = [&](ChunkBuf& B, int ch, bool guard){
    const int j0 = ch * 64;
    const float* xp = xs_base + j0;
    const float* ep = es_base + j0;
    if (!guard){
      f32x4v v = *(const f32x4v*)xp;
      B.sx4[0] = v[0]; B.sx4[1] = v[1]; B.sx4[2] = v[2]; B.sx4[3] = v[3];
#pragma unroll
      for (int u = 0; u < 4; ++u) B.se4[u] = ep[u];
    } else {
#pragma unroll
      for (int u = 0; u < 4; ++u){
        int c = j0 + lq4 + u;
        B.sx4[u] = (c < 2000) ? xp[u] : 0.f;
        B.se4[u] = (c < 1999) ? ep[u] : 0.f;
      }
    }
    const float* axp = xa_base + j0;
    const float* aep = ea_base + j0;
    if (!guard){
      f32x4v a0 = *(const f32x4v*)axp;
      f32x4v a1 = *(const f32x4v*)(axp + 4);
      f32x4v a2 = *(const f32x4v*)(axp + 32);
      f32x4v a3 = *(const f32x4v*)(axp + 36);
#pragma unroll
      for (int u = 0; u < 4; ++u){
        B.ax[u] = a0[u]; B.ax[4+u] = a1[u]; B.ax[8+u] = a2[u]; B.ax[12+u] = a3[u];
      }
#pragma unroll
      for (int u = 0; u < 8; ++u){ B.ae[u] = aep[u]; B.ae[8+u] = aep[32 + u]; }
    } else {
#pragma unroll
      for (int u = 0; u < 8; ++u){
        int c0 = j0 + kgrp + u, c1 = c0 + 32;
        B.ax[u]   = (c0 < 2000) ? axp[u]      : 0.f;
        B.ax[8+u] = (c1 < 2000) ? axp[32 + u] : 0.f;
        B.ae[u]   = (c0 < 1999) ? aep[u]      : 0.f;
        B.ae[8+u] = (c1 < 1999) ? aep[32 + u] : 0.f;
      }
    }
    B.bf0 = *(const v8s*)(wf_base + j0);
    B.bf1 = *(const v8s*)(wf_base + j0 + 32);
    B.bd0 = *(const v8s*)(wd_base + j0);
    B.bd1 = *(const v8s*)(wd_base + j0 + 32);
  };

  auto computeChunk = [&](ChunkBuf& B, int ch, bool guard){
    const int j0g = ch * 64;
    const int jl  = (ch - ch0) * 64;
    union U16 { v8s s; unsigned short u[8]; } ax0, ax1;
    union BU  { bf8v b; v8s s; } ae0, ae1;
#pragma unroll
    for (int u = 0; u < 8; ++u){
      ax0.u[u] = lutlog[(int)B.ax[u]];
      ax1.u[u] = lutlog[(int)B.ax[8+u]];
      ae0.b[u] = (__bf16)B.ae[u];
      ae1.b[u] = (__bf16)B.ae[8+u];
    }
    accz = __builtin_amdgcn_mfma_f32_16x16x32_bf16(ax0.s, B.bf0, accz, 0, 0, 0);
    accz = __builtin_amdgcn_mfma_f32_16x16x32_bf16(ax1.s, B.bf1, accz, 0, 0, 0);
    acct = __builtin_amdgcn_mfma_f32_16x16x32_bf16(ae0.s, B.bd0, acct, 0, 0, 0);
    acct = __builtin_amdgcn_mfma_f32_16x16x32_bf16(ae1.s, B.bd1, acct, 0, 0, 0);
    f32x4v cz = *(const f32x4v*)&c_lds[jl + lq4];
    f32x4v az = *(const f32x4v*)&a_lds[jl + lq4];
    float s0 = cz[0] * B.se4[0], s1 = cz[1] * B.se4[1];
    float s2 = cz[2] * B.se4[2], s3 = cz[3] * B.se4[3];
    float run = s0 + s1 + s2 + s3;
    float p1 = s0, p2 = s0 + s1, p3 = s0 + s1 + s2;
    float tot = run;
#pragma unroll
    for (int d = 1; d < 16; d <<= 1){
      float o = __shfl_up(tot, d, 16);
      if (sl >= d) tot += o;
    }
    float excl = tot - run;
    float base = carry + excl;
    carry += __shfl(tot, 15, 16);
    float lg0 = az[0] * B.se4[0] - base;
    float lg1 = az[1] * B.se4[1] - (base + p1);
    float lg2 = az[2] * B.se4[2] - (base + p2);
    float lg3 = az[3] * B.se4[3] - (base + p3);
    if (!guard){
      float cm = fmaxf(fmaxf(lg0, lg1), fmaxf(lg2, lg3));
      if (cm > mOn){ sOn *= __expf(mOn - cm); mOn = cm; }
      sOn += __expf(lg0 - mOn) + __expf(lg1 - mOn) + __expf(lg2 - mOn) + __expf(lg3 - mOn);
      xdot = fmaf(B.sx4[0], lg0, xdot);
      xdot = fmaf(B.sx4[1], lg1, xdot);
      xdot = fmaf(B.sx4[2], lg2, xdot);
      xdot = fmaf(B.sx4[3], lg3, xdot);
    } else {
      int nvalid = 2000 - (j0g + lq4);
      float cm = -3.0e38f;
      if (0 < nvalid) cm = fmaxf(cm, lg0);
      if (1 < nvalid) cm = fmaxf(cm, lg1);
      if (2 < nvalid) cm = fmaxf(cm, lg2);
      if (3 < nvalid) cm = fmaxf(cm, lg3);
      if (cm > mOn){ sOn *= __expf(mOn - cm); mOn = cm; }
      if (0 < nvalid){ sOn += __expf(lg0 - mOn); xdot = fmaf(B.sx4[0], lg0, xdot); }
      if (1 < nvalid){ sOn += __expf(lg1 - mOn); xdot = fmaf(B.sx4[1], lg1, xdot); }
      if (2 < nvalid){ sOn += __expf(lg2 - mOn); xdot = fmaf(B.sx4[2], lg2, xdot); }
      if (3 < nvalid){ sOn += __expf(lg3 - mOn); xdot = fmaf(B.sx4[3], lg3, xdot); }
    }
#pragma unroll
    for (int u = 0; u < 4; ++u){
      sx += B.sx4[u];
      sgl += lutlg[(int)B.sx4[u]];
      e2 = fmaf(B.se4[u], B.se4[u], e2);
    }
  };

  const bool lastGuard = (split == 1);
  ChunkBuf bufA, bufB;
  loadChunk(bufA, ch0, false);
#pragma unroll 1
  for (int i = 0; i < 14; i += 2){
    loadChunk(bufB, ch0 + i + 1, false);
    computeChunk(bufA, ch0 + i, false);
    loadChunk(bufA, ch0 + i + 2, false);
    computeChunk(bufB, ch0 + i + 1, false);
  }
  loadChunk(bufB, ch0 + 15, lastGuard);
  computeChunk(bufA, ch0 + 14, false);
  computeChunk(bufB, ch0 + 15, lastGuard);

  // ---- per-split reductions + partial writes ----
  xdot = red16(xdot); sx = red16(sx); sgl = red16(sgl); e2 = red16(e2);
#pragma unroll
  for (int d = 1; d < 16; d <<= 1){
    float om = __shfl_xor(mOn, d, 16);
    float os = __shfl_xor(sOn, d, 16);
    float nm = fmaxf(mOn, om);
    sOn = sOn * __expf(mOn - nm) + os * __expf(om - nm);
    mOn = nm;
  }
  {
    int r0 = (lan >> 4) * 4;
#pragma unroll
    for (int r = 0; r < 4; ++r){
      z_l[r0 + r][bcol] = accz[r];
      t_l[r0 + r][bcol] = acct[r];
    }
  }
  __syncthreads();
  {
    size_t rb = (size_t)(split * 8192 + b0 + lrow) * 64 + lq4;
    f32x4v zv = *(const f32x4v*)&z_l[lrow][lq4];
    f32x4v tv = *(const f32x4v*)&t_l[lrow][lq4];
    *(f32x4v*)&zpart[rb] = zv;
    *(f32x4v*)&tpart[rb] = tv;
  }
  if (sl == 0){
    float* so = &scanw[(size_t)(split * 8192 + b0 + lrow) * 8];
    so[0] = carry; so[1] = mOn; so[2] = sOn; so[3] = xdot;
    so[4] = sx; so[5] = sgl; so[6] = e2;
  }
}

// ---------------- FIXUP: merge splits + Woodbury quad ----------------
__global__ __launch_bounds__(256) void fixup_kernel(const float* __restrict__ zpart,
    const float* __restrict__ tpart, const float* __restrict__ scanw,
    const float* __restrict__ Gws, const float* __restrict__ Minv,
    const float* __restrict__ misc, const float* __restrict__ lss,
    float* __restrict__ mult_out, float* __restrict__ lp_out)
{
  __shared__ __align__(16) float z_l[16][68];
  __shared__ __align__(16) float t_l[16][68];
  const int tid = threadIdx.x;
  const int lrow = tid >> 4, sl = tid & 15, lq4 = sl * 4;
  const int b = blockIdx.x * 16 + lrow;

  f32x4v z0 = *(const f32x4v*)&zpart[(size_t)b * 64 + lq4];
  f32x4v z1 = *(const f32x4v*)&zpart[(size_t)(8192 + b) * 64 + lq4];
  f32x4v t0 = *(const f32x4v*)&tpart[(size_t)b * 64 + lq4];
  f32x4v t1 = *(const f32x4v*)&tpart[(size_t)(8192 + b) * 64 + lq4];
  float z4[4], t4[4];
#pragma unroll
  for (int u = 0; u < 4; ++u){
    z4[u] = z0[u] + z1[u];
    t4[u] = t0[u] + t1[u];
    z_l[lrow][lq4 + u] = z4[u];
  }
  float zz = 0.f, tz = 0.f;
#pragma unroll
  for (int u = 0; u < 4; ++u){ zz = fmaf(z4[u], z4[u], zz); tz = fmaf(t4[u], z4[u], tz); }
  float gz[4] = {0.f, 0.f, 0.f, 0.f};
#pragma unroll 8
  for (int q = 0; q < 64; ++q){
    float zq = z_l[lrow][q];
    f32x4v g = *(const f32x4v*)&Gws[q * 64 + lq4];   // G symmetric; L1/L2-hot
#pragma unroll
    for (int u = 0; u < 4; ++u) gz[u] = fmaf(g[u], zq, gz[u]);
  }
  float zGz = 0.f;
#pragma unroll
  for (int u = 0; u < 4; ++u) zGz = fmaf(z4[u], gz[u], zGz);
  float tk[4];
#pragma unroll
  for (int u = 0; u < 4; ++u){ tk[u] = t4[u] - gz[u]; t_l[lrow][lq4 + u] = tk[u]; }
  float sol[4] = {0.f, 0.f, 0.f, 0.f};
#pragma unroll 8
  for (int q = 0; q < 64; ++q){
    float tq = t_l[lrow][q];
    f32x4v g = *(const f32x4v*)&Minv[q * 64 + lq4];  // Minv symmetric
#pragma unroll
    for (int u = 0; u < 4; ++u) sol[u] = fmaf(g[u], tq, sol[u]);
  }
  float ts = 0.f;
#pragma unroll
  for (int u = 0; u < 4; ++u) ts = fmaf(tk[u], sol[u], ts);

  zz = red16(zz); tz = red16(tz); zGz = red16(zGz); ts = red16(ts);
  if (sl == 0){
    const float* s0 = &scanw[(size_t)b * 8];
    const float* s1 = &scanw[(size_t)(8192 + b) * 8];
    float carry1 = s0[0];
    float m0 = s0[1], S0 = s0[2];
    float m1 = s1[1] - carry1, S1 = s1[2];
    float M = fmaxf(m0, m1);
    float S = S0 * __expf(m0 - M) + S1 * __expf(m1 - M);
    float lse = M + logf(S);
    float xdT = s0[3] + s1[3] - carry1 * s1[4];
    float sxT = s0[4] + s1[4];
    float sglT = s0[5] + s1[5];
    float e2T = s0[6] + s1[6];
    mult_out[b] = lgammaf(sxT + 1.f) - sglT + xdT - sxT * lse;
    float var = expf(lss[0]);
    float logdet = misc[0];
    float diff2 = e2T - 2.f * tz + zGz;
    float quad = diff2 / var - ts / (var * var);
    lp_out[b] = -0.5f * (1999.f * LOG2PI_F + logdet + quad) - 0.5f * zz;
  }
}

// ---------------- Z: final mean + constants ----------------
__global__ __launch_bounds__(256) void reduce_kernel(const float* __restrict__ mult,
    const float* __restrict__ lp, float* __restrict__ out){
  __shared__ double red[4];
  int tid = threadIdx.x;
  double acc = 0.0;
  for (int b = tid; b < 8192; b += 256)
    acc += (double)mult[b] + (double)lp[b];
#pragma unroll
  for (int m = 1; m < 64; m <<= 1) acc += __shfl_xor(acc, m, 64);
  if ((tid & 63) == 0) red[tid >> 6] = acc;
  __syncthreads();
  if (tid == 0){
    double tot = red[0] + red[1] + red[2] + red[3];
    double mean = tot / 8192.0;
    double loss = -(mean - 0.5 * 64.0 * 1.8378770664093453);
    out[0] = (float)loss;
  }
}

extern "C" void kernel_launch(void* const* d_in, const int* in_sizes, int n_in,
                              void* d_out, int out_size, void* d_ws, size_t ws_size,
                              hipStream_t stream){
  const float* x    = (const float*)d_in[0];
  const float* Psi  = (const float*)d_in[1];
  const float* Wenc = (const float*)d_in[2];
  const float* Wdec = (const float*)d_in[3];
  const float* vlv  = (const float*)d_in[4];
  const float* lss  = (const float*)d_in[5];
  const float* eta  = (const float*)d_in[6];
  float* ws = (float*)d_ws;
  float*  a_ws  = ws + OFF_A;
  float*  c_ws  = ws + OFF_C;
  __bf16* weffb = (__bf16*)(ws + OFF_WEFFB);
  __bf16* wdtb  = (__bf16*)(ws + OFF_WDTB);
  float*  Gws   = ws + OFF_G;
  float*  Minv  = ws + OFF_MINV;
  float*  misc  = ws + OFF_MISC;
  float*  gpart = ws + OFF_GPART;
  float*  zpart = ws + OFF_ZPART;
  float*  tpart = ws + OFF_TPART;
  float*  scanw = ws + OFF_SCAN;
  float*  multw = ws + OFF_MULT;
  float*  lpw   = ws + OFF_LP;

  prep_kernel<<<104, 256, 0, stream>>>(Psi, Wenc, Wdec, a_ws, c_ws, weffb, wdtb, gpart);
  neumann_kernel<<<1, 256, 0, stream>>>(gpart, vlv, lss, Gws, Minv, misc);
  mega_kernel<<<1024, 256, 0, stream>>>(x, eta, (const short*)weffb, (const short*)wdtb,
                                        a_ws, c_ws, zpart, tpart, scanw);
  fixup_kernel<<<512, 256, 0, stream>>>(zpart, tpart, scanw, Gws, Minv, misc, lss,
                                        multw, lpw);
  reduce_kernel<<<1, 256, 0, stream>>>(multw, lpw, (float*)d_out);
}

// Round 10
// 107.588 us; speedup vs baseline: 1.5756x; 1.1845x over previous
//
#include <hip/hip_runtime.h>
#include <math.h>

// LinearCatVAE loss on MI355X.
// Psi = Helmert basis => Psi products are diag + prefix scans.
// R8: column-split mega (1024x256), barrier-free, 14 glb loads/chunk, x/eta
// read 5x (A-frags identical across the 4 waves + scan role) -> load-issue
// bound (VALU 21%, HBM 10%).
// R9: LDS-staged A-frags: scan threads load x/eta ONCE, convert (logf+bf16),
// ds_write At/Ae[2][16][72]; MFMA waves ds_read_b128 frags. 6 loads/chunk,
// 1 barrier/chunk, loads issued AFTER the barrier (drain-safe), consumed at
// the late ds_write. LDS ~34KB steers 4-block/CU cap -> VGPR budget 128.

#define LOG2PI_F 1.8378770664093453f

typedef short  v8s    __attribute__((ext_vector_type(8)));
typedef float  f32x4v __attribute__((ext_vector_type(4)));

// ---- workspace offsets (floats) ----
#define OFF_A     0          // 2048
#define OFF_C     2048       // 2048
#define OFF_WEFFB 4096       // 65536
#define OFF_WDTB  69632     // 65536
#define OFF_G     135168    // 4096
#define OFF_MINV  139264    // 4096
#define OFF_MISC  143360    // 64
#define OFF_GPART 143424    // 131072 -> ends 274496
#define OFF_ZPART 274496    // 2*8192*64 = 1048576
#define OFF_TPART 1323072   // 1048576
#define OFF_SCAN  2371648   // 2*8192*8 = 131072
#define OFF_MULT  2502720   // 8192
#define OFF_LP    2510912   // 8192

__device__ inline float red16(float v){
#pragma unroll
  for (int m = 1; m < 16; m <<= 1) v += __shfl_xor(v, m, 16);
  return v;
}

// ------- PREP (fused): blocks 0-7 coef, 8-71 wenceff, 72-103 wdtgram -------
__global__ __launch_bounds__(256) void prep_kernel(const float* __restrict__ Psi,
    const float* __restrict__ Wenc, const float* __restrict__ Wdec,
    float* __restrict__ a_ws, float* __restrict__ c_ws,
    __bf16* __restrict__ weffb, __bf16* __restrict__ wdtb,
    float* __restrict__ gparts){
  __shared__ __align__(16) float shm[4160];
  const int tid = threadIdx.x;
  const int blk = blockIdx.x;
  if (blk < 8){
    int e = blk * 256 + tid;
    float a = 0.f, c = 0.f;
    if (e < 1999){
      a = Psi[(size_t)e * 2001];
      c = -Psi[(size_t)e * 2001 + 1];
    }
    a_ws[e] = a;
    c_ws[e] = c;
    return;
  }
  if (blk < 72){
    float* scan = shm;
    int k = blk - 8;
    const float* wrow = Wenc + (size_t)k * 1999;
    int base = tid * 8;
    float w[8], sloc[8], av[8];
    float run = 0.f;
#pragma unroll
    for (int u = 0; u < 8; ++u){
      int e = base + u;
      bool v = (e < 1999);
      float wv = v ? wrow[e] : 0.f;
      av[u] = v ? Psi[(size_t)e * 2001] : 0.f;
      float cv = v ? -Psi[(size_t)e * 2001 + 1] : 0.f;
      w[u] = wv;
      sloc[u] = run;
      run += cv * wv;
    }
    scan[tid] = run;
    __syncthreads();
    for (int off = 1; off < 256; off <<= 1){
      float y = (tid >= off) ? scan[tid - off] : 0.f;
      __syncthreads();
      scan[tid] += y;
      __syncthreads();
    }
    float excl = scan[tid] - run;
#pragma unroll
    for (int u = 0; u < 8; ++u){
      int e = base + u;
      float val = (e < 2000) ? (av[u] * w[u] - (excl + sloc[u])) : 0.f;
      weffb[(size_t)k * 2048 + e] = (__bf16)val;
    }
    return;
  }
  auto Ws = (float(*)[64])shm;
  int j0 = (blk - 72) * 64;
#pragma unroll
  for (int i = 0; i < 16; ++i){
    int e = tid + i * 256;
    int j = e >> 6, kk = e & 63;
    Ws[j][kk] = (j0 + j < 1999) ? Wdec[(size_t)(j0 + j) * 64 + kk] : 0.f;
  }
  __syncthreads();
#pragma unroll
  for (int i = 0; i < 16; ++i){
    int e = tid + i * 256; int kk = e >> 6, j = e & 63;
    wdtb[(size_t)kk * 2048 + j0 + j] = (__bf16)Ws[j][kk];
  }
  int p = tid & 63;
  int qb = (tid >> 6) * 16;
  float acc[16] = {};
  for (int jj = 0; jj < 64; ++jj){
    float wp = Ws[jj][p];
    const float4 q0 = *(const float4*)&Ws[jj][qb];
    const float4 q1 = *(const float4*)&Ws[jj][qb + 4];
    const float4 q2 = *(const float4*)&Ws[jj][qb + 8];
    const float4 q3 = *(const float4*)&Ws[jj][qb + 12];
    acc[0]  = fmaf(wp, q0.x, acc[0]);  acc[1]  = fmaf(wp, q0.y, acc[1]);
    acc[2]  = fmaf(wp, q0.z, acc[2]);  acc[3]  = fmaf(wp, q0.w, acc[3]);
    acc[4]  = fmaf(wp, q1.x, acc[4]);  acc[5]  = fmaf(wp, q1.y, acc[5]);
    acc[6]  = fmaf(wp, q1.z, acc[6]);  acc[7]  = fmaf(wp, q1.w, acc[7]);
    acc[8]  = fmaf(wp, q2.x, acc[8]);  acc[9]  = fmaf(wp, q2.y, acc[9]);
    acc[10] = fmaf(wp, q2.z, acc[10]); acc[11] = fmaf(wp, q2.w, acc[11]);
    acc[12] = fmaf(wp, q3.x, acc[12]); acc[13] = fmaf(wp, q3.y, acc[13]);
    acc[14] = fmaf(wp, q3.z, acc[14]); acc[15] = fmaf(wp, q3.w, acc[15]);
  }
  float* gp = gparts + (size_t)(blk - 72) * 4096 + (size_t)p * 64 + qb;
#pragma unroll
  for (int u = 0; u < 4; ++u){
    float4 o; o.x = acc[4*u]; o.y = acc[4*u+1]; o.z = acc[4*u+2]; o.w = acc[4*u+3];
    *(float4*)&gp[4*u] = o;
  }
}

// ---- P3: gram reduce + Minv + logdet (Neumann truncated at A^2) ----
__global__ __launch_bounds__(256) void neumann_kernel(const float* __restrict__ gparts,
    const float* __restrict__ vlv, const float* __restrict__ lss,
    float* __restrict__ Gws, float* __restrict__ Minv, float* __restrict__ misc){
  __shared__ float As[64][65];
  __shared__ float A2s[64][65];
  __shared__ double dred[4][3];
  int tid = threadIdx.x;
  float var = expf(lss[0]);
  for (int e = tid; e < 4096; e += 256){
    int i = e >> 6;
    float s = 0.f;
#pragma unroll
    for (int p = 0; p < 32; ++p) s += gparts[(size_t)p * 4096 + e];
    Gws[e] = s;
    As[i][e & 63] = expf(vlv[i]) * s / var;
  }
  __syncthreads();
  for (int e = tid; e < 4096; e += 256){
    int i = e >> 6, j = e & 63;
    float s = 0.f;
    for (int q = 0; q < 64; ++q) s = fmaf(As[i][q], As[q][j], s);
    A2s[i][j] = s;
  }
  __syncthreads();
  double t1 = 0, t2 = 0, t3 = 0;
  for (int e = tid; e < 4096; e += 256){
    int i = e >> 6, j = e & 63;
    if (i == j){ t1 += (double)As[i][i]; t2 += (double)A2s[i][i]; }
    t3 += (double)A2s[i][j] * (double)As[j][i];
  }
#pragma unroll
  for (int m = 1; m < 64; m <<= 1){
    t1 += __shfl_xor(t1, m, 64); t2 += __shfl_xor(t2, m, 64); t3 += __shfl_xor(t3, m, 64);
  }
  int wid = tid >> 6;
  if ((tid & 63) == 0){ dred[wid][0] = t1; dred[wid][1] = t2; dred[wid][2] = t3; }
  __syncthreads();
  for (int e = tid; e < 4096; e += 256){
    int i = e >> 6, j = e & 63;
    float v = ((i == j) ? 1.f : 0.f) - As[i][j] + A2s[i][j];
    Minv[e] = v * expf(vlv[j]);
  }
  if (tid == 0){
    double tr1 = 0, tr2 = 0, tr3 = 0;
    for (int w2 = 0; w2 < 4; ++w2){
      tr1 += dred[w2][0]; tr2 += dred[w2][1]; tr3 += dred[w2][2];
    }
    misc[0] = (float)(1999.0 * (double)lss[0] + tr1 - tr2 / 2.0 + tr3 / 3.0);
  }
}

// ---------------- MEGA: LDS-staged column-split fused pass ----------------
// 1024 blocks x 256 threads; split = bid&1 (chunks 0-15 / 16-31);
// rowblk = bid>>1 -> 16 rows. One barrier/chunk; A-frags via LDS.
__global__ __launch_bounds__(256) void mega_kernel(
    const float* __restrict__ x, const float* __restrict__ eta,
    const short* __restrict__ wfB, const short* __restrict__ wdB,
    const float* __restrict__ a_ws, const float* __restrict__ c_ws,
    float* __restrict__ zpart, float* __restrict__ tpart,
    float* __restrict__ scanw)
{
  __shared__ float lutlg[128];
  __shared__ __align__(16) float a_lds[2048];   // only 1024 used (occ steer)
  __shared__ __align__(16) float c_lds[2048];   // only 1024 used
  __shared__ __align__(16) __bf16 At[2][16][72];
  __shared__ __align__(16) __bf16 Ae[2][16][72];
  __shared__ __align__(16) float z_l[16][68];
  __shared__ __align__(16) float t_l[16][68];

  const int tid = threadIdx.x;
  const int split = blockIdx.x & 1;
  const int rowblk = blockIdx.x >> 1;
  const int b0 = rowblk * 16;
  const int ch0 = split * 16;
  const int cb0 = split * 1024;
  if (tid < 128) lutlg[tid] = lgammaf((float)(tid + 1));
  for (int i = tid; i < 1024; i += 256){ a_lds[i] = a_ws[cb0 + i]; c_lds[i] = c_ws[cb0 + i]; }

  const int lrow = tid >> 4;
  const int sl   = tid & 15;
  const int lq4  = sl * 4;
  const int wid  = tid >> 6, lan = tid & 63;
  const int arow = lan & 15;
  const int bcol = wid * 16 + (lan & 15);
  const int kgrp = (lan >> 4) * 8;

  f32x4v accz = {0.f, 0.f, 0.f, 0.f}, acct = {0.f, 0.f, 0.f, 0.f};
  float carry = 0.f, mOn = -3.0e38f, sOn = 0.f;
  float xdot = 0.f, sx = 0.f, sgl = 0.f, e2 = 0.f;

  const float* xs_base = x   + (size_t)(b0 + lrow) * 2000 + lq4;
  const float* es_base = eta + (size_t)(b0 + lrow) * 1999 + lq4;
  const short* wf_base = wfB + (size_t)bcol * 2048 + kgrp;
  const short* wd_base = wdB + (size_t)bcol * 2048 + kgrp;

  float xA[4], eA[4], xB[4], eB[4];
  v8s bfA0, bfA1, bdA0, bdA1, bfB0, bfB1, bdB0, bdB1;

  auto loadScan = [&](float (&x4)[4], float (&e4)[4], int ch, bool guard){
    const int j0 = ch * 64;
    const float* xp = xs_base + j0;
    const float* ep = es_base + j0;
    if (!guard){
      f32x4v v = *(const f32x4v*)xp;
      x4[0] = v[0]; x4[1] = v[1]; x4[2] = v[2]; x4[3] = v[3];
#pragma unroll
      for (int u = 0; u < 4; ++u) e4[u] = ep[u];
    } else {
#pragma unroll
      for (int u = 0; u < 4; ++u){
        int c = j0 + lq4 + u;
        x4[u] = (c < 2000) ? xp[u] : 0.f;
        e4[u] = (c < 1999) ? ep[u] : 0.f;
      }
    }
  };
  auto loadB = [&](v8s& f0, v8s& f1, v8s& d0, v8s& d1, int ch){
    const int j0 = ch * 64;
    f0 = *(const v8s*)(wf_base + j0);
    f1 = *(const v8s*)(wf_base + j0 + 32);
    d0 = *(const v8s*)(wd_base + j0);
    d1 = *(const v8s*)(wd_base + j0 + 32);
  };
  auto stage = [&](const float (&x4)[4], const float (&e4)[4], int buf){
    union { __bf16 b[4]; unsigned long long q; } cx, ce;
#pragma unroll
    for (int u = 0; u < 4; ++u){
      cx.b[u] = (__bf16)__logf(x4[u] + 1.f);
      ce.b[u] = (__bf16)e4[u];
    }
    *(unsigned long long*)&At[buf][lrow][lq4] = cx.q;
    *(unsigned long long*)&Ae[buf][lrow][lq4] = ce.q;
  };
  auto mfmaStep = [&](int buf, v8s f0, v8s f1, v8s d0, v8s d1){
    v8s ax0 = *(const v8s*)&At[buf][arow][kgrp];
    v8s ax1 = *(const v8s*)&At[buf][arow][32 + kgrp];
    v8s ae0 = *(const v8s*)&Ae[buf][arow][kgrp];
    v8s ae1 = *(const v8s*)&Ae[buf][arow][32 + kgrp];
    accz = __builtin_amdgcn_mfma_f32_16x16x32_bf16(ax0, f0, accz, 0, 0, 0);
    accz = __builtin_amdgcn_mfma_f32_16x16x32_bf16(ax1, f1, accz, 0, 0, 0);
    acct = __builtin_amdgcn_mfma_f32_16x16x32_bf16(ae0, d0, acct, 0, 0, 0);
    acct = __builtin_amdgcn_mfma_f32_16x16x32_bf16(ae1, d1, acct, 0, 0, 0);
  };
  auto scanStep = [&](const float (&x4)[4], const float (&e4)[4], int ch, bool guard){
    const int j0g = ch * 64;
    const int jl  = (ch - ch0) * 64;
    f32x4v cz = *(const f32x4v*)&c_lds[jl + lq4];
    f32x4v az = *(const f32x4v*)&a_lds[jl + lq4];
    float s0 = cz[0] * e4[0], s1 = cz[1] * e4[1];
    float s2 = cz[2] * e4[2], s3 = cz[3] * e4[3];
    float run = s0 + s1 + s2 + s3;
    float p1 = s0, p2 = s0 + s1, p3 = s0 + s1 + s2;
    float tot = run;
#pragma unroll
    for (int d = 1; d < 16; d <<= 1){
      float o = __shfl_up(tot, d, 16);
      if (sl >= d) tot += o;
    }
    float excl = tot - run;
    float base = carry + excl;
    carry += __shfl(tot, 15, 16);
    float lg0 = az[0] * e4[0] - base;
    float lg1 = az[1] * e4[1] - (base + p1);
    float lg2 = az[2] * e4[2] - (base + p2);
    float lg3 = az[3] * e4[3] - (base + p3);
    if (!guard){
      float cm = fmaxf(fmaxf(lg0, lg1), fmaxf(lg2, lg3));
      if (cm > mOn){ sOn *= __expf(mOn - cm); mOn = cm; }
      sOn += __expf(lg0 - mOn) + __expf(lg1 - mOn) + __expf(lg2 - mOn) + __expf(lg3 - mOn);
      xdot = fmaf(x4[0], lg0, xdot);
      xdot = fmaf(x4[1], lg1, xdot);
      xdot = fmaf(x4[2], lg2, xdot);
      xdot = fmaf(x4[3], lg3, xdot);
    } else {
      int nvalid = 2000 - (j0g + lq4);
      float cm = -3.0e38f;
      if (0 < nvalid) cm = fmaxf(cm, lg0);
      if (1 < nvalid) cm = fmaxf(cm, lg1);
      if (2 < nvalid) cm = fmaxf(cm, lg2);
      if (3 < nvalid) cm = fmaxf(cm, lg3);
      if (cm > mOn){ sOn *= __expf(mOn - cm); mOn = cm; }
      if (0 < nvalid){ sOn += __expf(lg0 - mOn); xdot = fmaf(x4[0], lg0, xdot); }
      if (1 < nvalid){ sOn += __expf(lg1 - mOn); xdot = fmaf(x4[1], lg1, xdot); }
      if (2 < nvalid){ sOn += __expf(lg2 - mOn); xdot = fmaf(x4[2], lg2, xdot); }
      if (3 < nvalid){ sOn += __expf(lg3 - mOn); xdot = fmaf(x4[3], lg3, xdot); }
    }
#pragma unroll
    for (int u = 0; u < 4; ++u){
      sx += x4[u];
      sgl += lutlg[(int)x4[u]];
      e2 = fmaf(e4[u], e4[u], e2);
    }
  };

  const bool lastGuard = (split == 1);
  // prologue: chunk 0 into regs A + staged to buf0; B-frags for chunk 0
  loadScan(xA, eA, ch0, false);
  loadB(bfA0, bfA1, bdA0, bdA1, ch0);
  stage(xA, eA, 0);            // LUT init (tid<128) done before; stage uses no LUT
#pragma unroll 1
  for (int c = 0; c < 16; ++c){
    __syncthreads();           // buf[c&1] staged & visible; LUT/a/c ready (c==0)
    bool g = lastGuard && (c + 1 == 15);
    if (c < 15){               // issue next-chunk loads AFTER barrier (no drain)
      loadScan(xB, eB, ch0 + c + 1, g);
      loadB(bfB0, bfB1, bdB0, bdB1, ch0 + c + 1);
    }
    mfmaStep(c & 1, bfA0, bfA1, bdA0, bdA1);
    scanStep(xA, eA, ch0 + c, lastGuard && (c == 15));
    if (c < 15){
      stage(xB, eB, (c + 1) & 1);   // waits on loads here (had mfma+scan time)
#pragma unroll
      for (int u = 0; u < 4; ++u){ xA[u] = xB[u]; eA[u] = eB[u]; }
      bfA0 = bfB0; bfA1 = bfB1; bdA0 = bdB0; bdA1 = bdB1;
    }
  }

  // ---- per-split reductions + partial writes ----
  xdot = red16(xdot); sx = red16(sx); sgl = red16(sgl); e2 = red16(e2);
#pragma unroll
  for (int d = 1; d < 16; d <<= 1){
    float om = __shfl_xor(mOn, d, 16);
    float os = __shfl_xor(sOn, d, 16);
    float nm = fmaxf(mOn, om);
    sOn = sOn * __expf(mOn - nm) + os * __expf(om - nm);
    mOn = nm;
  }
  __syncthreads();             // all LDS frag reads done before z_l reuse
  {
    int r0 = (lan >> 4) * 4;
#pragma unroll
    for (int r = 0; r < 4; ++r){
      z_l[r0 + r][bcol] = accz[r];
      t_l[r0 + r][bcol] = acct[r];
    }
  }
  __syncthreads();
  {
    size_t rb = (size_t)(split * 8192 + b0 + lrow) * 64 + lq4;
    f32x4v zv = *(const f32x4v*)&z_l[lrow][lq4];
    f32x4v tv = *(const f32x4v*)&t_l[lrow][lq4];
    *(f32x4v*)&zpart[rb] = zv;
    *(f32x4v*)&tpart[rb] = tv;
  }
  if (sl == 0){
    float* so = &scanw[(size_t)(split * 8192 + b0 + lrow) * 8];
    so[0] = carry; so[1] = mOn; so[2] = sOn; so[3] = xdot;
    so[4] = sx; so[5] = sgl; so[6] = e2;
  }
}

// ---------------- FIXUP: merge splits + Woodbury quad ----------------
__global__ __launch_bounds__(256) void fixup_kernel(const float* __restrict__ zpart,
    const float* __restrict__ tpart, const float* __restrict__ scanw,
    const float* __restrict__ Gws, const float* __restrict__ Minv,
    const float* __restrict__ misc, const float* __restrict__ lss,
    float* __restrict__ mult_out, float* __restrict__ lp_out)
{
  __shared__ __align__(16) float z_l[16][68];
  __shared__ __align__(16) float t_l[16][68];
  const int tid = threadIdx.x;
  const int lrow = tid >> 4, sl = tid & 15, lq4 = sl * 4;
  const int b = blockIdx.x * 16 + lrow;

  f32x4v z0 = *(const f32x4v*)&zpart[(size_t)b * 64 + lq4];
  f32x4v z1 = *(const f32x4v*)&zpart[(size_t)(8192 + b) * 64 + lq4];
  f32x4v t0 = *(const f32x4v*)&tpart[(size_t)b * 64 + lq4];
  f32x4v t1 = *(const f32x4v*)&tpart[(size_t)(8192 + b) * 64 + lq4];
  float z4[4], t4[4];
#pragma unroll
  for (int u = 0; u < 4; ++u){
    z4[u] = z0[u] + z1[u];
    t4[u] = t0[u] + t1[u];
    z_l[lrow][lq4 + u] = z4[u];
  }
  float zz = 0.f, tz = 0.f;
#pragma unroll
  for (int u = 0; u < 4; ++u){ zz = fmaf(z4[u], z4[u], zz); tz = fmaf(t4[u], z4[u], tz); }
  float gz[4] = {0.f, 0.f, 0.f, 0.f};
#pragma unroll 8
  for (int q = 0; q < 64; ++q){
    float zq = z_l[lrow][q];
    f32x4v g = *(const f32x4v*)&Gws[q * 64 + lq4];   // G symmetric; L2-hot
#pragma unroll
    for (int u = 0; u < 4; ++u) gz[u] = fmaf(g[u], zq, gz[u]);
  }
  float zGz = 0.f;
#pragma unroll
  for (int u = 0; u < 4; ++u) zGz = fmaf(z4[u], gz[u], zGz);
  float tk[4];
#pragma unroll
  for (int u = 0; u < 4; ++u){ tk[u] = t4[u] - gz[u]; t_l[lrow][lq4 + u] = tk[u]; }
  float sol[4] = {0.f, 0.f, 0.f, 0.f};
#pragma unroll 8
  for (int q = 0; q < 64; ++q){
    float tq = t_l[lrow][q];
    f32x4v g = *(const f32x4v*)&Minv[q * 64 + lq4];  // Minv symmetric
#pragma unroll
    for (int u = 0; u < 4; ++u) sol[u] = fmaf(g[u], tq, sol[u]);
  }
  float ts = 0.f;
#pragma unroll
  for (int u = 0; u < 4; ++u) ts = fmaf(tk[u], sol[u], ts);

  zz = red16(zz); tz = red16(tz); zGz = red16(zGz); ts = red16(ts);
  if (sl == 0){
    const float* s0 = &scanw[(size_t)b * 8];
    const float* s1 = &scanw[(size_t)(8192 + b) * 8];
    float carry1 = s0[0];
    float m0 = s0[1], S0 = s0[2];
    float m1 = s1[1] - carry1, S1 = s1[2];
    float M = fmaxf(m0, m1);
    float S = S0 * __expf(m0 - M) + S1 * __expf(m1 - M);
    float lse = M + logf(S);
    float xdT = s0[3] + s1[3] - carry1 * s1[4];
    float sxT = s0[4] + s1[4];
    float sglT = s0[5] + s1[5];
    float e2T = s0[6] + s1[6];
    mult_out[b] = lgammaf(sxT + 1.f) - sglT + xdT - sxT * lse;
    float var = expf(lss[0]);
    float logdet = misc[0];
    float diff2 = e2T - 2.f * tz + zGz;
    float quad = diff2 / var - ts / (var * var);
    lp_out[b] = -0.5f * (1999.f * LOG2PI_F + logdet + quad) - 0.5f * zz;
  }
}

// ---------------- Z: final mean + constants ----------------
__global__ __launch_bounds__(256) void reduce_kernel(const float* __restrict__ mult,
    const float* __restrict__ lp, float* __restrict__ out){
  __shared__ double red[4];
  int tid = threadIdx.x;
  double acc = 0.0;
  for (int b = tid; b < 8192; b += 256)
    acc += (double)mult[b] + (double)lp[b];
#pragma unroll
  for (int m = 1; m < 64; m <<= 1) acc += __shfl_xor(acc, m, 64);
  if ((tid & 63) == 0) red[tid >> 6] = acc;
  __syncthreads();
  if (tid == 0){
    double tot = red[0] + red[1] + red[2] + red[3];
    double mean = tot / 8192.0;
    double loss = -(mean - 0.5 * 64.0 * 1.8378770664093453);
    out[0] = (float)loss;
  }
}

extern "C" void kernel_launch(void* const* d_in, const int* in_sizes, int n_in,
                              void* d_out, int out_size, void* d_ws, size_t ws_size,
                              hipStream_t stream){
  const float* x    = (const float*)d_in[0];
  const float* Psi  = (const float*)d_in[1];
  const float* Wenc = (const float*)d_in[2];
  const float* Wdec = (const float*)d_in[3];
  const float* vlv  = (const float*)d_in[4];
  const float* lss  = (const float*)d_in[5];
  const float* eta  = (const float*)d_in[6];
  float* ws = (float*)d_ws;
  float*  a_ws  = ws + OFF_A;
  float*  c_ws  = ws + OFF_C;
  __bf16* weffb = (__bf16*)(ws + OFF_WEFFB);
  __bf16* wdtb  = (__bf16*)(ws + OFF_WDTB);
  float*  Gws   = ws + OFF_G;
  float*  Minv  = ws + OFF_MINV;
  float*  misc  = ws + OFF_MISC;
  float*  gpart = ws + OFF_GPART;
  float*  zpart = ws + OFF_ZPART;
  float*  tpart = ws + OFF_TPART;
  float*  scanw = ws + OFF_SCAN;
  float*  multw = ws + OFF_MULT;
  float*  lpw   = ws + OFF_LP;

  prep_kernel<<<104, 256, 0, stream>>>(Psi, Wenc, Wdec, a_ws, c_ws, weffb, wdtb, gpart);
  neumann_kernel<<<1, 256, 0, stream>>>(gpart, vlv, lss, Gws, Minv, misc);
  mega_kernel<<<1024, 256, 0, stream>>>(x, eta, (const short*)weffb, (const short*)wdtb,
                                        a_ws, c_ws, zpart, tpart, scanw);
  fixup_kernel<<<512, 256, 0, stream>>>(zpart, tpart, scanw, Gws, Minv, misc, lss,
                                        multw, lpw);
  reduce_kernel<<<1, 256, 0, stream>>>(multw, lpw, (float*)d_out);
}

// Round 11
// 106.924 us; speedup vs baseline: 1.5854x; 1.0062x over previous
//
#include <hip/hip_runtime.h>
#include <math.h>

// LinearCatVAE loss on MI355X.
// Psi = Helmert basis => Psi products are diag + prefix scans.
// R9: LDS-staged A-frags (6 loads/chunk, 1 barrier/chunk) -> VGPR 60, occ 32%.
// R10: split-4 mega (grid 2048, 8 chunks/block) + LDS cut to ~13.9KB
// (a/c sliced, z_l/t_l overlaid on At/Ae) -> 8 blocks/CU x 4 waves = 32
// waves/CU; VGPR 60 fits the 64-budget tier. Fixup merges 4 splits with
// prefix-carry algebra. Aux: coef separate (Psi diag read once), wenceff
// reads a/c coalesced, gram_reduce parallel, neumann reads G directly.

#define LOG2PI_F 1.8378770664093453f

typedef short  v8s    __attribute__((ext_vector_type(8)));
typedef float  f32x4v __attribute__((ext_vector_type(4)));

// ---- workspace offsets (floats) ----
#define OFF_A     0          // 2048
#define OFF_C     2048       // 2048
#define OFF_WEFFB 4096       // 65536
#define OFF_WDTB  69632     // 65536
#define OFF_G     135168    // 4096
#define OFF_MINV  139264    // 4096
#define OFF_MISC  143360    // 64
#define OFF_ZPART 143424    // 4*8192*64 = 2097152 -> end 2240576
#define OFF_GPART OFF_ZPART // alias: gpart (131072) dead before mega writes
#define OFF_TPART 2240576   // 2097152 -> end 4337728
#define OFF_SCAN  4337728   // 4*8192*8 = 262144 -> end 4599872
#define OFF_MULT  4599872   // 8192
#define OFF_LP    4608064   // 8192 -> end 4616256 (~17.6 MB)

__device__ inline float red16(float v){
#pragma unroll
  for (int m = 1; m < 16; m <<= 1) v += __shfl_xor(v, m, 16);
  return v;
}

// ---------------- P0: Helmert coefficients (Psi diag read ONCE) -------------
__global__ __launch_bounds__(256) void coef_kernel(const float* __restrict__ Psi,
                                                   float* __restrict__ a_ws,
                                                   float* __restrict__ c_ws){
  int e = blockIdx.x * 256 + threadIdx.x;   // 0..2047
  float a = 0.f, c = 0.f;
  if (e < 1999){
    a = Psi[(size_t)e * 2001];
    c = -Psi[(size_t)e * 2001 + 1];
  }
  a_ws[e] = a;
  c_ws[e] = c;
}

// ------- P1 (fused): blocks 0-63 wenceff (a/c coalesced), 64-95 wdtgram -----
__global__ __launch_bounds__(256) void prep2_kernel(const float* __restrict__ Wenc,
    const float* __restrict__ Wdec, const float* __restrict__ a_ws,
    const float* __restrict__ c_ws, __bf16* __restrict__ weffb,
    __bf16* __restrict__ wdtb, float* __restrict__ gparts){
  __shared__ __align__(16) float shm[4160];
  const int tid = threadIdx.x;
  const int blk = blockIdx.x;
  if (blk < 64){
    float* scan = shm;
    int k = blk;
    const float* wrow = Wenc + (size_t)k * 1999;
    int base = tid * 8;
    float w[8], sloc[8];
    float run = 0.f;
#pragma unroll
    for (int u = 0; u < 8; ++u){
      int e = base + u;
      float wv = (e < 1999) ? wrow[e] : 0.f;
      w[u] = wv;
      sloc[u] = run;
      run += c_ws[e] * wv;
    }
    scan[tid] = run;
    __syncthreads();
    for (int off = 1; off < 256; off <<= 1){
      float y = (tid >= off) ? scan[tid - off] : 0.f;
      __syncthreads();
      scan[tid] += y;
      __syncthreads();
    }
    float excl = scan[tid] - run;
#pragma unroll
    for (int u = 0; u < 8; ++u){
      int e = base + u;
      float val = (e < 2000) ? (a_ws[e] * w[u] - (excl + sloc[u])) : 0.f;
      weffb[(size_t)k * 2048 + e] = (__bf16)val;
    }
    return;
  }
  // wdtgram
  auto Ws = (float(*)[64])shm;
  int j0 = (blk - 64) * 64;
#pragma unroll
  for (int i = 0; i < 16; ++i){
    int e = tid + i * 256;
    int j = e >> 6, kk = e & 63;
    Ws[j][kk] = (j0 + j < 1999) ? Wdec[(size_t)(j0 + j) * 64 + kk] : 0.f;
  }
  __syncthreads();
#pragma unroll
  for (int i = 0; i < 16; ++i){
    int e = tid + i * 256; int kk = e >> 6, j = e & 63;
    wdtb[(size_t)kk * 2048 + j0 + j] = (__bf16)Ws[j][kk];
  }
  int p = tid & 63;
  int qb = (tid >> 6) * 16;
  float acc[16] = {};
  for (int jj = 0; jj < 64; ++jj){
    float wp = Ws[jj][p];
    const float4 q0 = *(const float4*)&Ws[jj][qb];
    const float4 q1 = *(const float4*)&Ws[jj][qb + 4];
    const float4 q2 = *(const float4*)&Ws[jj][qb + 8];
    const float4 q3 = *(const float4*)&Ws[jj][qb + 12];
    acc[0]  = fmaf(wp, q0.x, acc[0]);  acc[1]  = fmaf(wp, q0.y, acc[1]);
    acc[2]  = fmaf(wp, q0.z, acc[2]);  acc[3]  = fmaf(wp, q0.w, acc[3]);
    acc[4]  = fmaf(wp, q1.x, acc[4]);  acc[5]  = fmaf(wp, q1.y, acc[5]);
    acc[6]  = fmaf(wp, q1.z, acc[6]);  acc[7]  = fmaf(wp, q1.w, acc[7]);
    acc[8]  = fmaf(wp, q2.x, acc[8]);  acc[9]  = fmaf(wp, q2.y, acc[9]);
    acc[10] = fmaf(wp, q2.z, acc[10]); acc[11] = fmaf(wp, q2.w, acc[11]);
    acc[12] = fmaf(wp, q3.x, acc[12]); acc[13] = fmaf(wp, q3.y, acc[13]);
    acc[14] = fmaf(wp, q3.z, acc[14]); acc[15] = fmaf(wp, q3.w, acc[15]);
  }
  float* gp = gparts + (size_t)(blk - 64) * 4096 + (size_t)p * 64 + qb;
#pragma unroll
  for (int u = 0; u < 4; ++u){
    float4 o; o.x = acc[4*u]; o.y = acc[4*u+1]; o.z = acc[4*u+2]; o.w = acc[4*u+3];
    *(float4*)&gp[4*u] = o;
  }
}

// ---------------- P2b: reduce 32 partial grams -> G ----------------
__global__ __launch_bounds__(256) void gram_reduce_kernel(const float* __restrict__ gparts,
                                                          float* __restrict__ G){
  int e = blockIdx.x * 256 + threadIdx.x;   // 16 blocks
  float s = 0.f;
#pragma unroll
  for (int p = 0; p < 32; ++p) s += gparts[(size_t)p * 4096 + e];
  G[e] = s;
}

// ---- P3: Minv + logdet (Neumann truncated at A^2); G read coalesced ----
__global__ __launch_bounds__(256) void neumann_kernel(const float* __restrict__ Gws,
    const float* __restrict__ vlv, const float* __restrict__ lss,
    float* __restrict__ Minv, float* __restrict__ misc){
  __shared__ float As[64][65];
  __shared__ float A2s[64][65];
  __shared__ double dred[4][3];
  int tid = threadIdx.x;
  float var = expf(lss[0]);
  for (int e = tid; e < 4096; e += 256){
    int i = e >> 6;
    As[i][e & 63] = expf(vlv[i]) * Gws[e] / var;
  }
  __syncthreads();
  for (int e = tid; e < 4096; e += 256){
    int i = e >> 6, j = e & 63;
    float s = 0.f;
    for (int q = 0; q < 64; ++q) s = fmaf(As[i][q], As[q][j], s);
    A2s[i][j] = s;
  }
  __syncthreads();
  double t1 = 0, t2 = 0, t3 = 0;
  for (int e = tid; e < 4096; e += 256){
    int i = e >> 6, j = e & 63;
    if (i == j){ t1 += (double)As[i][i]; t2 += (double)A2s[i][i]; }
    t3 += (double)A2s[i][j] * (double)As[j][i];
  }
#pragma unroll
  for (int m = 1; m < 64; m <<= 1){
    t1 += __shfl_xor(t1, m, 64); t2 += __shfl_xor(t2, m, 64); t3 += __shfl_xor(t3, m, 64);
  }
  int wid = tid >> 6;
  if ((tid & 63) == 0){ dred[wid][0] = t1; dred[wid][1] = t2; dred[wid][2] = t3; }
  __syncthreads();
  for (int e = tid; e < 4096; e += 256){
    int i = e >> 6, j = e & 63;
    float v = ((i == j) ? 1.f : 0.f) - As[i][j] + A2s[i][j];
    Minv[e] = v * expf(vlv[j]);
  }
  if (tid == 0){
    double tr1 = 0, tr2 = 0, tr3 = 0;
    for (int w2 = 0; w2 < 4; ++w2){
      tr1 += dred[w2][0]; tr2 += dred[w2][1]; tr3 += dred[w2][2];
    }
    misc[0] = (float)(1999.0 * (double)lss[0] + tr1 - tr2 / 2.0 + tr3 / 3.0);
  }
}

// ---------------- MEGA: split-4 LDS-staged fused pass ----------------
// 2048 blocks x 256 threads; split = bid&3 (8 chunks of 64 cols each);
// rowblk = bid>>2 -> 16 rows. LDS ~13.9KB -> 8 blocks/CU.
__global__ __launch_bounds__(256) void mega_kernel(
    const float* __restrict__ x, const float* __restrict__ eta,
    const short* __restrict__ wfB, const short* __restrict__ wdB,
    const float* __restrict__ a_ws, const float* __restrict__ c_ws,
    float* __restrict__ zpart, float* __restrict__ tpart,
    float* __restrict__ scanw)
{
  __shared__ float lutlg[128];
  __shared__ __align__(16) float a_lds[512];
  __shared__ __align__(16) float c_lds[512];
  __shared__ __align__(16) unsigned char fragbuf[9216];   // At/Ae; later z_l/t_l
  auto At = (__bf16(*)[16][72])(fragbuf);                 // [2][16][72]
  auto Ae = (__bf16(*)[16][72])(fragbuf + 4608);
  auto z_l = (float(*)[68])(fragbuf);                     // epilogue overlay
  auto t_l = (float(*)[68])(fragbuf + 4352);

  const int tid = threadIdx.x;
  const int split = blockIdx.x & 3;
  const int rowblk = blockIdx.x >> 2;
  const int b0 = rowblk * 16;
  const int ch0 = split * 8;
  const int cb0 = split * 512;
  if (tid < 128) lutlg[tid] = lgammaf((float)(tid + 1));
  for (int i = tid; i < 512; i += 256){ a_lds[i] = a_ws[cb0 + i]; c_lds[i] = c_ws[cb0 + i]; }

  const int lrow = tid >> 4;
  const int sl   = tid & 15;
  const int lq4  = sl * 4;
  const int wid  = tid >> 6, lan = tid & 63;
  const int arow = lan & 15;
  const int bcol = wid * 16 + (lan & 15);
  const int kgrp = (lan >> 4) * 8;

  f32x4v accz = {0.f, 0.f, 0.f, 0.f}, acct = {0.f, 0.f, 0.f, 0.f};
  float carry = 0.f, mOn = -3.0e38f, sOn = 0.f;
  float xdot = 0.f, sx = 0.f, sgl = 0.f, e2 = 0.f;

  const float* xs_base = x   + (size_t)(b0 + lrow) * 2000 + lq4;
  const float* es_base = eta + (size_t)(b0 + lrow) * 1999 + lq4;
  const short* wf_base = wfB + (size_t)bcol * 2048 + kgrp;
  const short* wd_base = wdB + (size_t)bcol * 2048 + kgrp;

  float xA[4], eA[4], xB[4], eB[4];
  v8s bfA0, bfA1, bdA0, bdA1, bfB0, bfB1, bdB0, bdB1;

  auto loadScan = [&](float (&x4)[4], float (&e4)[4], int ch, bool guard){
    const int j0 = ch * 64;
    const float* xp = xs_base + j0;
    const float* ep = es_base + j0;
    if (!guard){
      f32x4v v = *(const f32x4v*)xp;
      x4[0] = v[0]; x4[1] = v[1]; x4[2] = v[2]; x4[3] = v[3];
#pragma unroll
      for (int u = 0; u < 4; ++u) e4[u] = ep[u];
    } else {
#pragma unroll
      for (int u = 0; u < 4; ++u){
        int c = j0 + lq4 + u;
        x4[u] = (c < 2000) ? xp[u] : 0.f;
        e4[u] = (c < 1999) ? ep[u] : 0.f;
      }
    }
  };
  auto loadB = [&](v8s& f0, v8s& f1, v8s& d0, v8s& d1, int ch){
    const int j0 = ch * 64;
    f0 = *(const v8s*)(wf_base + j0);
    f1 = *(const v8s*)(wf_base + j0 + 32);
    d0 = *(const v8s*)(wd_base + j0);
    d1 = *(const v8s*)(wd_base + j0 + 32);
  };
  auto stage = [&](const float (&x4)[4], const float (&e4)[4], int buf){
    union { __bf16 b[4]; unsigned long long q; } cx, ce;
#pragma unroll
    for (int u = 0; u < 4; ++u){
      cx.b[u] = (__bf16)__logf(x4[u] + 1.f);
      ce.b[u] = (__bf16)e4[u];
    }
    *(unsigned long long*)&At[buf][lrow][lq4] = cx.q;
    *(unsigned long long*)&Ae[buf][lrow][lq4] = ce.q;
  };
  auto mfmaStep = [&](int buf, v8s f0, v8s f1, v8s d0, v8s d1){
    v8s ax0 = *(const v8s*)&At[buf][arow][kgrp];
    v8s ax1 = *(const v8s*)&At[buf][arow][32 + kgrp];
    v8s ae0 = *(const v8s*)&Ae[buf][arow][kgrp];
    v8s ae1 = *(const v8s*)&Ae[buf][arow][32 + kgrp];
    accz = __builtin_amdgcn_mfma_f32_16x16x32_bf16(ax0, f0, accz, 0, 0, 0);
    accz = __builtin_amdgcn_mfma_f32_16x16x32_bf16(ax1, f1, accz, 0, 0, 0);
    acct = __builtin_amdgcn_mfma_f32_16x16x32_bf16(ae0, d0, acct, 0, 0, 0);
    acct = __builtin_amdgcn_mfma_f32_16x16x32_bf16(ae1, d1, acct, 0, 0, 0);
  };
  auto scanStep = [&](const float (&x4)[4], const float (&e4)[4], int ch, bool guard){
    const int j0g = ch * 64;
    const int jl  = (ch - ch0) * 64;
    f32x4v cz = *(const f32x4v*)&c_lds[jl + lq4];
    f32x4v az = *(const f32x4v*)&a_lds[jl + lq4];
    float s0 = cz[0] * e4[0], s1 = cz[1] * e4[1];
    float s2 = cz[2] * e4[2], s3 = cz[3] * e4[3];
    float run = s0 + s1 + s2 + s3;
    float p1 = s0, p2 = s0 + s1, p3 = s0 + s1 + s2;
    float tot = run;
#pragma unroll
    for (int d = 1; d < 16; d <<= 1){
      float o = __shfl_up(tot, d, 16);
      if (sl >= d) tot += o;
    }
    float excl = tot - run;
    float base = carry + excl;
    carry += __shfl(tot, 15, 16);
    float lg0 = az[0] * e4[0] - base;
    float lg1 = az[1] * e4[1] - (base + p1);
    float lg2 = az[2] * e4[2] - (base + p2);
    float lg3 = az[3] * e4[3] - (base + p3);
    if (!guard){
      float cm = fmaxf(fmaxf(lg0, lg1), fmaxf(lg2, lg3));
      if (cm > mOn){ sOn *= __expf(mOn - cm); mOn = cm; }
      sOn += __expf(lg0 - mOn) + __expf(lg1 - mOn) + __expf(lg2 - mOn) + __expf(lg3 - mOn);
      xdot = fmaf(x4[0], lg0, xdot);
      xdot = fmaf(x4[1], lg1, xdot);
      xdot = fmaf(x4[2], lg2, xdot);
      xdot = fmaf(x4[3], lg3, xdot);
    } else {
      int nvalid = 2000 - (j0g + lq4);
      float cm = -3.0e38f;
      if (0 < nvalid) cm = fmaxf(cm, lg0);
      if (1 < nvalid) cm = fmaxf(cm, lg1);
      if (2 < nvalid) cm = fmaxf(cm, lg2);
      if (3 < nvalid) cm = fmaxf(cm, lg3);
      if (cm > mOn){ sOn *= __expf(mOn - cm); mOn = cm; }
      if (0 < nvalid){ sOn += __expf(lg0 - mOn); xdot = fmaf(x4[0], lg0, xdot); }
      if (1 < nvalid){ sOn += __expf(lg1 - mOn); xdot = fmaf(x4[1], lg1, xdot); }
      if (2 < nvalid){ sOn += __expf(lg2 - mOn); xdot = fmaf(x4[2], lg2, xdot); }
      if (3 < nvalid){ sOn += __expf(lg3 - mOn); xdot = fmaf(x4[3], lg3, xdot); }
    }
#pragma unroll
    for (int u = 0; u < 4; ++u){
      sx += x4[u];
      sgl += lutlg[(int)x4[u]];
      e2 = fmaf(e4[u], e4[u], e2);
    }
  };

  const bool lastSplit = (split == 3);
  loadScan(xA, eA, ch0, false);
  loadB(bfA0, bfA1, bdA0, bdA1, ch0);
  stage(xA, eA, 0);
#pragma unroll 1
  for (int c = 0; c < 8; ++c){
    __syncthreads();           // buf[c&1] staged; luts/a/c ready (c==0)
    if (c < 7){                // issue next-chunk loads AFTER barrier
      loadScan(xB, eB, ch0 + c + 1, lastSplit && (c + 1 == 7));
      loadB(bfB0, bfB1, bdB0, bdB1, ch0 + c + 1);
    }
    mfmaStep(c & 1, bfA0, bfA1, bdA0, bdA1);
    scanStep(xA, eA, ch0 + c, lastSplit && (c == 7));
    if (c < 7){
      stage(xB, eB, (c + 1) & 1);   // waits on loads here (had compute time)
#pragma unroll
      for (int u = 0; u < 4; ++u){ xA[u] = xB[u]; eA[u] = eB[u]; }
      bfA0 = bfB0; bfA1 = bfB1; bdA0 = bdB0; bdA1 = bdB1;
    }
  }

  // ---- per-split reductions + partial writes ----
  xdot = red16(xdot); sx = red16(sx); sgl = red16(sgl); e2 = red16(e2);
#pragma unroll
  for (int d = 1; d < 16; d <<= 1){
    float om = __shfl_xor(mOn, d, 16);
    float os = __shfl_xor(sOn, d, 16);
    float nm = fmaxf(mOn, om);
    sOn = sOn * __expf(mOn - nm) + os * __expf(om - nm);
    mOn = nm;
  }
  __syncthreads();             // all frag reads done before z_l/t_l overlay
  {
    int r0 = (lan >> 4) * 4;
#pragma unroll
    for (int r = 0; r < 4; ++r){
      z_l[r0 + r][bcol] = accz[r];
      t_l[r0 + r][bcol] = acct[r];
    }
  }
  __syncthreads();
  {
    size_t rb = (size_t)(split * 8192 + b0 + lrow) * 64 + lq4;
    f32x4v zv = *(const f32x4v*)&z_l[lrow][lq4];
    f32x4v tv = *(const f32x4v*)&t_l[lrow][lq4];
    *(f32x4v*)&zpart[rb] = zv;
    *(f32x4v*)&tpart[rb] = tv;
  }
  if (sl == 0){
    float* so = &scanw[(size_t)(split * 8192 + b0 + lrow) * 8];
    so[0] = carry; so[1] = mOn; so[2] = sOn; so[3] = xdot;
    so[4] = sx; so[5] = sgl; so[6] = e2;
  }
}

// ---------------- FIXUP: merge 4 splits + Woodbury quad ----------------
__global__ __launch_bounds__(256) void fixup_kernel(const float* __restrict__ zpart,
    const float* __restrict__ tpart, const float* __restrict__ scanw,
    const float* __restrict__ Gws, const float* __restrict__ Minv,
    const float* __restrict__ misc, const float* __restrict__ lss,
    float* __restrict__ mult_out, float* __restrict__ lp_out)
{
  __shared__ __align__(16) float z_l[16][68];
  __shared__ __align__(16) float t_l[16][68];
  const int tid = threadIdx.x;
  const int lrow = tid >> 4, sl = tid & 15, lq4 = sl * 4;
  const int b = blockIdx.x * 16 + lrow;

  float z4[4] = {0.f,0.f,0.f,0.f}, t4[4] = {0.f,0.f,0.f,0.f};
#pragma unroll
  for (int s = 0; s < 4; ++s){
    f32x4v zv = *(const f32x4v*)&zpart[(size_t)(s * 8192 + b) * 64 + lq4];
    f32x4v tv = *(const f32x4v*)&tpart[(size_t)(s * 8192 + b) * 64 + lq4];
#pragma unroll
    for (int u = 0; u < 4; ++u){ z4[u] += zv[u]; t4[u] += tv[u]; }
  }
#pragma unroll
  for (int u = 0; u < 4; ++u) z_l[lrow][lq4 + u] = z4[u];
  float zz = 0.f, tz = 0.f;
#pragma unroll
  for (int u = 0; u < 4; ++u){ zz = fmaf(z4[u], z4[u], zz); tz = fmaf(t4[u], z4[u], tz); }
  float gz[4] = {0.f, 0.f, 0.f, 0.f};
#pragma unroll 8
  for (int q = 0; q < 64; ++q){
    float zq = z_l[lrow][q];
    f32x4v g = *(const f32x4v*)&Gws[q * 64 + lq4];   // G symmetric; L2-hot
#pragma unroll
    for (int u = 0; u < 4; ++u) gz[u] = fmaf(g[u], zq, gz[u]);
  }
  float zGz = 0.f;
#pragma unroll
  for (int u = 0; u < 4; ++u) zGz = fmaf(z4[u], gz[u], zGz);
  float tk[4];
#pragma unroll
  for (int u = 0; u < 4; ++u){ tk[u] = t4[u] - gz[u]; t_l[lrow][lq4 + u] = tk[u]; }
  float sol[4] = {0.f, 0.f, 0.f, 0.f};
#pragma unroll 8
  for (int q = 0; q < 64; ++q){
    float tq = t_l[lrow][q];
    f32x4v g = *(const f32x4v*)&Minv[q * 64 + lq4];  // Minv symmetric
#pragma unroll
    for (int u = 0; u < 4; ++u) sol[u] = fmaf(g[u], tq, sol[u]);
  }
  float ts = 0.f;
#pragma unroll
  for (int u = 0; u < 4; ++u) ts = fmaf(tk[u], sol[u], ts);

  zz = red16(zz); tz = red16(tz); zGz = red16(zGz); ts = red16(ts);
  if (sl == 0){
    // merge 4 splits with prefix carries
    float C = 0.f, M = -3.0e38f, S = 0.f;
    float xdT = 0.f, sxT = 0.f, sglT = 0.f, e2T = 0.f;
#pragma unroll
    for (int s = 0; s < 4; ++s){
      const float* p = &scanw[(size_t)(s * 8192 + b) * 8];
      float mp = p[1] - C;
      float Ss = p[2];
      float mm = fmaxf(M, mp);
      S = S * __expf(M - mm) + Ss * __expf(mp - mm);
      M = mm;
      xdT += p[3] - C * p[4];
      sxT += p[4]; sglT += p[5]; e2T += p[6];
      C += p[0];
    }
    float lse = M + logf(S);
    mult_out[b] = lgammaf(sxT + 1.f) - sglT + xdT - sxT * lse;
    float var = expf(lss[0]);
    float logdet = misc[0];
    float diff2 = e2T - 2.f * tz + zGz;
    float quad = diff2 / var - ts / (var * var);
    lp_out[b] = -0.5f * (1999.f * LOG2PI_F + logdet + quad) - 0.5f * zz;
  }
}

// ---------------- Z: final mean + constants ----------------
__global__ __launch_bounds__(256) void reduce_kernel(const float* __restrict__ mult,
    const float* __restrict__ lp, float* __restrict__ out){
  __shared__ double red[4];
  int tid = threadIdx.x;
  double acc = 0.0;
  for (int b = tid; b < 8192; b += 256)
    acc += (double)mult[b] + (double)lp[b];
#pragma unroll
  for (int m = 1; m < 64; m <<= 1) acc += __shfl_xor(acc, m, 64);
  if ((tid & 63) == 0) red[tid >> 6] = acc;
  __syncthreads();
  if (tid == 0){
    double tot = red[0] + red[1] + red[2] + red[3];
    double mean = tot / 8192.0;
    double loss = -(mean - 0.5 * 64.0 * 1.8378770664093453);
    out[0] = (float)loss;
  }
}

extern "C" void kernel_launch(void* const* d_in, const int* in_sizes, int n_in,
                              void* d_out, int out_size, void* d_ws, size_t ws_size,
                              hipStream_t stream){
  const float* x    = (const float*)d_in[0];
  const float* Psi  = (const float*)d_in[1];
  const float* Wenc = (const float*)d_in[2];
  const float* Wdec = (const float*)d_in[3];
  const float* vlv  = (const float*)d_in[4];
  const float* lss  = (const float*)d_in[5];
  const float* eta  = (const float*)d_in[6];
  float* ws = (float*)d_ws;
  float*  a_ws  = ws + OFF_A;
  float*  c_ws  = ws + OFF_C;
  __bf16* weffb = (__bf16*)(ws + OFF_WEFFB);
  __bf16* wdtb  = (__bf16*)(ws + OFF_WDTB);
  float*  Gws   = ws + OFF_G;
  float*  Minv  = ws + OFF_MINV;
  float*  misc  = ws + OFF_MISC;
  float*  gpart = ws + OFF_GPART;   // aliases zpart region (dead until mega)
  float*  zpart = ws + OFF_ZPART;
  float*  tpart = ws + OFF_TPART;
  float*  scanw = ws + OFF_SCAN;
  float*  multw = ws + OFF_MULT;
  float*  lpw   = ws + OFF_LP;

  coef_kernel<<<8, 256, 0, stream>>>(Psi, a_ws, c_ws);
  prep2_kernel<<<96, 256, 0, stream>>>(Wenc, Wdec, a_ws, c_ws, weffb, wdtb, gpart);
  gram_reduce_kernel<<<16, 256, 0, stream>>>(gpart, Gws);
  neumann_kernel<<<1, 256, 0, stream>>>(Gws, vlv, lss, Minv, misc);
  mega_kernel<<<2048, 256, 0, stream>>>(x, eta, (const short*)weffb, (const short*)wdtb,
                                        a_ws, c_ws, zpart, tpart, scanw);
  fixup_kernel<<<512, 256, 0, stream>>>(zpart, tpart, scanw, Gws, Minv, misc, lss,
                                        multw, lpw);
  reduce_kernel<<<1, 256, 0, stream>>>(multw, lpw, (float*)d_out);
}

// Round 12
// 98.468 us; speedup vs baseline: 1.7215x; 1.0859x over previous
//
#include <hip/hip_runtime.h>
#include <math.h>

// LinearCatVAE loss on MI355X.
// Psi = Helmert basis => Psi products are diag + prefix scans.
// R10: split-4 LDS-staged mega; static wave caps no longer bind (~11 waves/CU
// at 32 allowed) -> per-wave memory pipeline depth is the limiter (Little's
// law: 6 x 16B in flight x 11 waves ~= measured 1 TB/s).
// R11: depth-2 register prefetch, 3 rotating sets, FULLY UNROLLED chunk loop
// (static indices; runtime-indexed vector arrays would spill). Stage(c+1)
// waits loads issued 1.5 chunks earlier; ~12 loads in flight/wave. VGPR ~110
// -> LDS padded to ~36KB to pin the 4-block/128-VGPR tier (R6-proven).
// fixup block-sums into 512 doubles; reduce shrinks.

#define LOG2PI_F 1.8378770664093453f

typedef short  v8s    __attribute__((ext_vector_type(8)));
typedef float  f32x4v __attribute__((ext_vector_type(4)));

// ---- workspace offsets (floats) ----
#define OFF_A     0          // 2048
#define OFF_C     2048       // 2048
#define OFF_WEFFB 4096       // 65536
#define OFF_WDTB  69632     // 65536
#define OFF_G     135168    // 4096
#define OFF_MINV  139264    // 4096
#define OFF_MISC  143360    // 64
#define OFF_ZPART 143424    // 4*8192*64 = 2097152 -> end 2240576
#define OFF_GPART OFF_ZPART // alias: gpart (131072) dead before mega writes
#define OFF_TPART 2240576   // 2097152 -> end 4337728
#define OFF_SCAN  4337728   // 4*8192*8 = 262144 -> end 4599872
#define OFF_PART  4599872   // 512 doubles = 1024 floats
#define OFF_END   4600896

__device__ inline float red16(float v){
#pragma unroll
  for (int m = 1; m < 16; m <<= 1) v += __shfl_xor(v, m, 16);
  return v;
}

// ---------------- P0: Helmert coefficients (Psi diag read ONCE) -------------
__global__ __launch_bounds__(256) void coef_kernel(const float* __restrict__ Psi,
                                                   float* __restrict__ a_ws,
                                                   float* __restrict__ c_ws){
  int e = blockIdx.x * 256 + threadIdx.x;   // 0..2047
  float a = 0.f, c = 0.f;
  if (e < 1999){
    a = Psi[(size_t)e * 2001];
    c = -Psi[(size_t)e * 2001 + 1];
  }
  a_ws[e] = a;
  c_ws[e] = c;
}

// ------- P1 (fused): blocks 0-63 wenceff (a/c coalesced), 64-95 wdtgram -----
__global__ __launch_bounds__(256) void prep2_kernel(const float* __restrict__ Wenc,
    const float* __restrict__ Wdec, const float* __restrict__ a_ws,
    const float* __restrict__ c_ws, __bf16* __restrict__ weffb,
    __bf16* __restrict__ wdtb, float* __restrict__ gparts){
  __shared__ __align__(16) float shm[4160];
  const int tid = threadIdx.x;
  const int blk = blockIdx.x;
  if (blk < 64){
    float* scan = shm;
    int k = blk;
    const float* wrow = Wenc + (size_t)k * 1999;
    int base = tid * 8;
    float w[8], sloc[8];
    float run = 0.f;
#pragma unroll
    for (int u = 0; u < 8; ++u){
      int e = base + u;
      float wv = (e < 1999) ? wrow[e] : 0.f;
      w[u] = wv;
      sloc[u] = run;
      run += c_ws[e] * wv;
    }
    scan[tid] = run;
    __syncthreads();
    for (int off = 1; off < 256; off <<= 1){
      float y = (tid >= off) ? scan[tid - off] : 0.f;
      __syncthreads();
      scan[tid] += y;
      __syncthreads();
    }
    float excl = scan[tid] - run;
#pragma unroll
    for (int u = 0; u < 8; ++u){
      int e = base + u;
      float val = (e < 2000) ? (a_ws[e] * w[u] - (excl + sloc[u])) : 0.f;
      weffb[(size_t)k * 2048 + e] = (__bf16)val;
    }
    return;
  }
  // wdtgram
  auto Ws = (float(*)[64])shm;
  int j0 = (blk - 64) * 64;
#pragma unroll
  for (int i = 0; i < 16; ++i){
    int e = tid + i * 256;
    int j = e >> 6, kk = e & 63;
    Ws[j][kk] = (j0 + j < 1999) ? Wdec[(size_t)(j0 + j) * 64 + kk] : 0.f;
  }
  __syncthreads();
#pragma unroll
  for (int i = 0; i < 16; ++i){
    int e = tid + i * 256; int kk = e >> 6, j = e & 63;
    wdtb[(size_t)kk * 2048 + j0 + j] = (__bf16)Ws[j][kk];
  }
  int p = tid & 63;
  int qb = (tid >> 6) * 16;
  float acc[16] = {};
  for (int jj = 0; jj < 64; ++jj){
    float wp = Ws[jj][p];
    const float4 q0 = *(const float4*)&Ws[jj][qb];
    const float4 q1 = *(const float4*)&Ws[jj][qb + 4];
    const float4 q2 = *(const float4*)&Ws[jj][qb + 8];
    const float4 q3 = *(const float4*)&Ws[jj][qb + 12];
    acc[0]  = fmaf(wp, q0.x, acc[0]);  acc[1]  = fmaf(wp, q0.y, acc[1]);
    acc[2]  = fmaf(wp, q0.z, acc[2]);  acc[3]  = fmaf(wp, q0.w, acc[3]);
    acc[4]  = fmaf(wp, q1.x, acc[4]);  acc[5]  = fmaf(wp, q1.y, acc[5]);
    acc[6]  = fmaf(wp, q1.z, acc[6]);  acc[7]  = fmaf(wp, q1.w, acc[7]);
    acc[8]  = fmaf(wp, q2.x, acc[8]);  acc[9]  = fmaf(wp, q2.y, acc[9]);
    acc[10] = fmaf(wp, q2.z, acc[10]); acc[11] = fmaf(wp, q2.w, acc[11]);
    acc[12] = fmaf(wp, q3.x, acc[12]); acc[13] = fmaf(wp, q3.y, acc[13]);
    acc[14] = fmaf(wp, q3.z, acc[14]); acc[15] = fmaf(wp, q3.w, acc[15]);
  }
  float* gp = gparts + (size_t)(blk - 64) * 4096 + (size_t)p * 64 + qb;
#pragma unroll
  for (int u = 0; u < 4; ++u){
    float4 o; o.x = acc[4*u]; o.y = acc[4*u+1]; o.z = acc[4*u+2]; o.w = acc[4*u+3];
    *(float4*)&gp[4*u] = o;
  }
}

// ---------------- P2b: reduce 32 partial grams -> G ----------------
__global__ __launch_bounds__(256) void gram_reduce_kernel(const float* __restrict__ gparts,
                                                          float* __restrict__ G){
  int e = blockIdx.x * 256 + threadIdx.x;   // 16 blocks
  float s = 0.f;
#pragma unroll
  for (int p = 0; p < 32; ++p) s += gparts[(size_t)p * 4096 + e];
  G[e] = s;
}

// ---- P3: Minv + logdet (Neumann truncated at A^2) ----
__global__ __launch_bounds__(256) void neumann_kernel(const float* __restrict__ Gws,
    const float* __restrict__ vlv, const float* __restrict__ lss,
    float* __restrict__ Minv, float* __restrict__ misc){
  __shared__ float As[64][65];
  __shared__ float A2s[64][65];
  __shared__ double dred[4][3];
  int tid = threadIdx.x;
  float var = expf(lss[0]);
  for (int e = tid; e < 4096; e += 256){
    int i = e >> 6;
    As[i][e & 63] = expf(vlv[i]) * Gws[e] / var;
  }
  __syncthreads();
  for (int e = tid; e < 4096; e += 256){
    int i = e >> 6, j = e & 63;
    float s = 0.f;
    for (int q = 0; q < 64; ++q) s = fmaf(As[i][q], As[q][j], s);
    A2s[i][j] = s;
  }
  __syncthreads();
  double t1 = 0, t2 = 0, t3 = 0;
  for (int e = tid; e < 4096; e += 256){
    int i = e >> 6, j = e & 63;
    if (i == j){ t1 += (double)As[i][i]; t2 += (double)A2s[i][i]; }
    t3 += (double)A2s[i][j] * (double)As[j][i];
  }
#pragma unroll
  for (int m = 1; m < 64; m <<= 1){
    t1 += __shfl_xor(t1, m, 64); t2 += __shfl_xor(t2, m, 64); t3 += __shfl_xor(t3, m, 64);
  }
  int wid = tid >> 6;
  if ((tid & 63) == 0){ dred[wid][0] = t1; dred[wid][1] = t2; dred[wid][2] = t3; }
  __syncthreads();
  for (int e = tid; e < 4096; e += 256){
    int i = e >> 6, j = e & 63;
    float v = ((i == j) ? 1.f : 0.f) - As[i][j] + A2s[i][j];
    Minv[e] = v * expf(vlv[j]);
  }
  if (tid == 0){
    double tr1 = 0, tr2 = 0, tr3 = 0;
    for (int w2 = 0; w2 < 4; ++w2){
      tr1 += dred[w2][0]; tr2 += dred[w2][1]; tr3 += dred[w2][2];
    }
    misc[0] = (float)(1999.0 * (double)lss[0] + tr1 - tr2 / 2.0 + tr3 / 3.0);
  }
}

// ---------------- MEGA: split-4, depth-2 prefetch, fully unrolled ----------
// 2048 blocks x 256 threads; split = bid&3 (8 chunks of 64 cols);
// rowblk = bid>>2 -> 16 rows.
struct PSet {
  float x4[4];
  float e4[4];
  v8s bf0, bf1, bd0, bd1;
};

__global__ __launch_bounds__(256) void mega_kernel(
    const float* __restrict__ x, const float* __restrict__ eta,
    const short* __restrict__ wfB, const short* __restrict__ wdB,
    const float* __restrict__ a_ws, const float* __restrict__ c_ws,
    float* __restrict__ zpart, float* __restrict__ tpart,
    float* __restrict__ scanw)
{
  __shared__ float lutlg[128];
  __shared__ __align__(16) float a_lds[512];
  __shared__ __align__(16) float c_lds[512];
  __shared__ __align__(16) unsigned char fragbuf[9216];   // At/Ae; later z_l/t_l
  __shared__ __align__(16) unsigned char steer[22528];    // occupancy steer: 4 blk/CU -> VGPR budget 128
  auto At = (__bf16(*)[16][72])(fragbuf);                 // [2][16][72]
  auto Ae = (__bf16(*)[16][72])(fragbuf + 4608);
  auto z_l = (float(*)[68])(fragbuf);                     // epilogue overlay
  auto t_l = (float(*)[68])(fragbuf + 4352);

  const int tid = threadIdx.x;
  if (tid == 0) ((volatile unsigned char*)steer)[0] = 1;  // keep allocation
  const int split = blockIdx.x & 3;
  const int rowblk = blockIdx.x >> 2;
  const int b0 = rowblk * 16;
  const int ch0 = split * 8;
  const int cb0 = split * 512;
  if (tid < 128) lutlg[tid] = lgammaf((float)(tid + 1));
  for (int i = tid; i < 512; i += 256){ a_lds[i] = a_ws[cb0 + i]; c_lds[i] = c_ws[cb0 + i]; }

  const int lrow = tid >> 4;
  const int sl   = tid & 15;
  const int lq4  = sl * 4;
  const int wid  = tid >> 6, lan = tid & 63;
  const int arow = lan & 15;
  const int bcol = wid * 16 + (lan & 15);
  const int kgrp = (lan >> 4) * 8;

  f32x4v accz = {0.f, 0.f, 0.f, 0.f}, acct = {0.f, 0.f, 0.f, 0.f};
  float carry = 0.f, mOn = -3.0e38f, sOn = 0.f;
  float xdot = 0.f, sx = 0.f, sgl = 0.f, e2 = 0.f;

  const float* xs_base = x   + (size_t)(b0 + lrow) * 2000 + lq4;
  const float* es_base = eta + (size_t)(b0 + lrow) * 1999 + lq4;
  const short* wf_base = wfB + (size_t)bcol * 2048 + kgrp;
  const short* wd_base = wdB + (size_t)bcol * 2048 + kgrp;

  const bool lastSplit = (split == 3);

  auto loadSet = [&](PSet& S, int ch, bool guard){
    const int j0 = ch * 64;
    const float* xp = xs_base + j0;
    const float* ep = es_base + j0;
    if (!guard){
      f32x4v v = *(const f32x4v*)xp;
      S.x4[0] = v[0]; S.x4[1] = v[1]; S.x4[2] = v[2]; S.x4[3] = v[3];
#pragma unroll
      for (int u = 0; u < 4; ++u) S.e4[u] = ep[u];
    } else {
#pragma unroll
      for (int u = 0; u < 4; ++u){
        int c = j0 + lq4 + u;
        S.x4[u] = (c < 2000) ? xp[u] : 0.f;
        S.e4[u] = (c < 1999) ? ep[u] : 0.f;
      }
    }
    S.bf0 = *(const v8s*)(wf_base + j0);
    S.bf1 = *(const v8s*)(wf_base + j0 + 32);
    S.bd0 = *(const v8s*)(wd_base + j0);
    S.bd1 = *(const v8s*)(wd_base + j0 + 32);
  };
  auto stage = [&](const PSet& S, int buf){
    union { __bf16 b[4]; unsigned long long q; } cx, ce;
#pragma unroll
    for (int u = 0; u < 4; ++u){
      cx.b[u] = (__bf16)__logf(S.x4[u] + 1.f);
      ce.b[u] = (__bf16)S.e4[u];
    }
    *(unsigned long long*)&At[buf][lrow][lq4] = cx.q;
    *(unsigned long long*)&Ae[buf][lrow][lq4] = ce.q;
  };
  auto mfmaStep = [&](int buf, const PSet& S){
    v8s ax0 = *(const v8s*)&At[buf][arow][kgrp];
    v8s ax1 = *(const v8s*)&At[buf][arow][32 + kgrp];
    v8s ae0 = *(const v8s*)&Ae[buf][arow][kgrp];
    v8s ae1 = *(const v8s*)&Ae[buf][arow][32 + kgrp];
    accz = __builtin_amdgcn_mfma_f32_16x16x32_bf16(ax0, S.bf0, accz, 0, 0, 0);
    accz = __builtin_amdgcn_mfma_f32_16x16x32_bf16(ax1, S.bf1, accz, 0, 0, 0);
    acct = __builtin_amdgcn_mfma_f32_16x16x32_bf16(ae0, S.bd0, acct, 0, 0, 0);
    acct = __builtin_amdgcn_mfma_f32_16x16x32_bf16(ae1, S.bd1, acct, 0, 0, 0);
  };
  auto scanStep = [&](const PSet& S, int c, bool guard){
    const int j0g = (ch0 + c) * 64;
    const int jl  = c * 64;
    f32x4v cz = *(const f32x4v*)&c_lds[jl + lq4];
    f32x4v az = *(const f32x4v*)&a_lds[jl + lq4];
    float s0 = cz[0] * S.e4[0], s1 = cz[1] * S.e4[1];
    float s2 = cz[2] * S.e4[2], s3 = cz[3] * S.e4[3];
    float run = s0 + s1 + s2 + s3;
    float p1 = s0, p2 = s0 + s1, p3 = s0 + s1 + s2;
    float tot = run;
#pragma unroll
    for (int d = 1; d < 16; d <<= 1){
      float o = __shfl_up(tot, d, 16);
      if (sl >= d) tot += o;
    }
    float excl = tot - run;
    float base = carry + excl;
    carry += __shfl(tot, 15, 16);
    float lg0 = az[0] * S.e4[0] - base;
    float lg1 = az[1] * S.e4[1] - (base + p1);
    float lg2 = az[2] * S.e4[2] - (base + p2);
    float lg3 = az[3] * S.e4[3] - (base + p3);
    if (!guard){
      float cm = fmaxf(fmaxf(lg0, lg1), fmaxf(lg2, lg3));
      if (cm > mOn){ sOn *= __expf(mOn - cm); mOn = cm; }
      sOn += __expf(lg0 - mOn) + __expf(lg1 - mOn) + __expf(lg2 - mOn) + __expf(lg3 - mOn);
      xdot = fmaf(S.x4[0], lg0, xdot);
      xdot = fmaf(S.x4[1], lg1, xdot);
      xdot = fmaf(S.x4[2], lg2, xdot);
      xdot = fmaf(S.x4[3], lg3, xdot);
    } else {
      int nvalid = 2000 - (j0g + lq4);
      float cm = -3.0e38f;
      if (0 < nvalid) cm = fmaxf(cm, lg0);
      if (1 < nvalid) cm = fmaxf(cm, lg1);
      if (2 < nvalid) cm = fmaxf(cm, lg2);
      if (3 < nvalid) cm = fmaxf(cm, lg3);
      if (cm > mOn){ sOn *= __expf(mOn - cm); mOn = cm; }
      if (0 < nvalid){ sOn += __expf(lg0 - mOn); xdot = fmaf(S.x4[0], lg0, xdot); }
      if (1 < nvalid){ sOn += __expf(lg1 - mOn); xdot = fmaf(S.x4[1], lg1, xdot); }
      if (2 < nvalid){ sOn += __expf(lg2 - mOn); xdot = fmaf(S.x4[2], lg2, xdot); }
      if (3 < nvalid){ sOn += __expf(lg3 - mOn); xdot = fmaf(S.x4[3], lg3, xdot); }
    }
#pragma unroll
    for (int u = 0; u < 4; ++u){
      sx += S.x4[u];
      sgl += lutlg[(int)S.x4[u]];
      e2 = fmaf(S.e4[u], S.e4[u], e2);
    }
  };

  PSet S[3];
  loadSet(S[0], ch0 + 0, false);
  loadSet(S[1], ch0 + 1, false);
  stage(S[0], 0);
  // depth-2 pipeline, FULLY UNROLLED so all S[] indices are compile-time
#pragma unroll
  for (int c = 0; c < 8; ++c){
    __syncthreads();                     // buf[c&1] staged & visible
    if (c + 2 < 8)
      loadSet(S[(c + 2) % 3], ch0 + c + 2, lastSplit && (c + 2 == 7));
    mfmaStep(c & 1, S[c % 3]);
    scanStep(S[c % 3], c, lastSplit && (c == 7));
    if (c < 7)
      stage(S[(c + 1) % 3], (c + 1) & 1);   // waits loads issued 1.5 chunks ago
  }

  // ---- per-split reductions + partial writes ----
  xdot = red16(xdot); sx = red16(sx); sgl = red16(sgl); e2 = red16(e2);
#pragma unroll
  for (int d = 1; d < 16; d <<= 1){
    float om = __shfl_xor(mOn, d, 16);
    float os = __shfl_xor(sOn, d, 16);
    float nm = fmaxf(mOn, om);
    sOn = sOn * __expf(mOn - nm) + os * __expf(om - nm);
    mOn = nm;
  }
  __syncthreads();             // all frag reads done before z_l/t_l overlay
  {
    int r0 = (lan >> 4) * 4;
#pragma unroll
    for (int r = 0; r < 4; ++r){
      z_l[r0 + r][bcol] = accz[r];
      t_l[r0 + r][bcol] = acct[r];
    }
  }
  __syncthreads();
  {
    size_t rb = (size_t)(split * 8192 + b0 + lrow) * 64 + lq4;
    f32x4v zv = *(const f32x4v*)&z_l[lrow][lq4];
    f32x4v tv = *(const f32x4v*)&t_l[lrow][lq4];
    *(f32x4v*)&zpart[rb] = zv;
    *(f32x4v*)&tpart[rb] = tv;
  }
  if (sl == 0){
    float* so = &scanw[(size_t)(split * 8192 + b0 + lrow) * 8];
    so[0] = carry; so[1] = mOn; so[2] = sOn; so[3] = xdot;
    so[4] = sx; so[5] = sgl; so[6] = e2;
  }
}

// ---------------- FIXUP: merge 4 splits + quad; block-sum to double --------
__global__ __launch_bounds__(256) void fixup_kernel(const float* __restrict__ zpart,
    const float* __restrict__ tpart, const float* __restrict__ scanw,
    const float* __restrict__ Gws, const float* __restrict__ Minv,
    const float* __restrict__ misc, const float* __restrict__ lss,
    double* __restrict__ part_out)
{
  __shared__ __align__(16) float z_l[16][68];
  __shared__ __align__(16) float t_l[16][68];
  __shared__ double rsum[16];
  const int tid = threadIdx.x;
  const int lrow = tid >> 4, sl = tid & 15, lq4 = sl * 4;
  const int b = blockIdx.x * 16 + lrow;

  float z4[4] = {0.f,0.f,0.f,0.f}, t4[4] = {0.f,0.f,0.f,0.f};
#pragma unroll
  for (int s = 0; s < 4; ++s){
    f32x4v zv = *(const f32x4v*)&zpart[(size_t)(s * 8192 + b) * 64 + lq4];
    f32x4v tv = *(const f32x4v*)&tpart[(size_t)(s * 8192 + b) * 64 + lq4];
#pragma unroll
    for (int u = 0; u < 4; ++u){ z4[u] += zv[u]; t4[u] += tv[u]; }
  }
#pragma unroll
  for (int u = 0; u < 4; ++u) z_l[lrow][lq4 + u] = z4[u];
  float zz = 0.f, tz = 0.f;
#pragma unroll
  for (int u = 0; u < 4; ++u){ zz = fmaf(z4[u], z4[u], zz); tz = fmaf(t4[u], z4[u], tz); }
  float gz[4] = {0.f, 0.f, 0.f, 0.f};
#pragma unroll 8
  for (int q = 0; q < 64; ++q){
    float zq = z_l[lrow][q];
    f32x4v g = *(const f32x4v*)&Gws[q * 64 + lq4];   // G symmetric; L2-hot
#pragma unroll
    for (int u = 0; u < 4; ++u) gz[u] = fmaf(g[u], zq, gz[u]);
  }
  float zGz = 0.f;
#pragma unroll
  for (int u = 0; u < 4; ++u) zGz = fmaf(z4[u], gz[u], zGz);
  float tk[4];
#pragma unroll
  for (int u = 0; u < 4; ++u){ tk[u] = t4[u] - gz[u]; t_l[lrow][lq4 + u] = tk[u]; }
  float sol[4] = {0.f, 0.f, 0.f, 0.f};
#pragma unroll 8
  for (int q = 0; q < 64; ++q){
    float tq = t_l[lrow][q];
    f32x4v g = *(const f32x4v*)&Minv[q * 64 + lq4];  // Minv symmetric
#pragma unroll
    for (int u = 0; u < 4; ++u) sol[u] = fmaf(g[u], tq, sol[u]);
  }
  float ts = 0.f;
#pragma unroll
  for (int u = 0; u < 4; ++u) ts = fmaf(tk[u], sol[u], ts);

  zz = red16(zz); tz = red16(tz); zGz = red16(zGz); ts = red16(ts);
  if (sl == 0){
    // merge 4 splits with prefix carries
    float C = 0.f, M = -3.0e38f, S = 0.f;
    float xdT = 0.f, sxT = 0.f, sglT = 0.f, e2T = 0.f;
#pragma unroll
    for (int s = 0; s < 4; ++s){
      const float* p = &scanw[(size_t)(s * 8192 + b) * 8];
      float mp = p[1] - C;
      float Ss = p[2];
      float mm = fmaxf(M, mp);
      S = S * __expf(M - mm) + Ss * __expf(mp - mm);
      M = mm;
      xdT += p[3] - C * p[4];
      sxT += p[4]; sglT += p[5]; e2T += p[6];
      C += p[0];
    }
    float lse = M + logf(S);
    float mult = lgammaf(sxT + 1.f) - sglT + xdT - sxT * lse;
    float var = expf(lss[0]);
    float logdet = misc[0];
    float diff2 = e2T - 2.f * tz + zGz;
    float quad = diff2 / var - ts / (var * var);
    float lp = -0.5f * (1999.f * LOG2PI_F + logdet + quad) - 0.5f * zz;
    rsum[lrow] = (double)mult + (double)lp;
  }
  __syncthreads();
  if (tid == 0){
    double s = 0.0;
#pragma unroll
    for (int r = 0; r < 16; ++r) s += rsum[r];
    part_out[blockIdx.x] = s;
  }
}

// ---------------- Z: final mean + constants ----------------
__global__ __launch_bounds__(256) void reduce_kernel(const double* __restrict__ part,
                                                     float* __restrict__ out){
  __shared__ double red[4];
  int tid = threadIdx.x;
  double acc = part[tid] + part[tid + 256];
#pragma unroll
  for (int m = 1; m < 64; m <<= 1) acc += __shfl_xor(acc, m, 64);
  if ((tid & 63) == 0) red[tid >> 6] = acc;
  __syncthreads();
  if (tid == 0){
    double tot = red[0] + red[1] + red[2] + red[3];
    double mean = tot / 8192.0;
    double loss = -(mean - 0.5 * 64.0 * 1.8378770664093453);
    out[0] = (float)loss;
  }
}

extern "C" void kernel_launch(void* const* d_in, const int* in_sizes, int n_in,
                              void* d_out, int out_size, void* d_ws, size_t ws_size,
                              hipStream_t stream){
  const float* x    = (const float*)d_in[0];
  const float* Psi  = (const float*)d_in[1];
  const float* Wenc = (const float*)d_in[2];
  const float* Wdec = (const float*)d_in[3];
  const float* vlv  = (const float*)d_in[4];
  const float* lss  = (const float*)d_in[5];
  const float* eta  = (const float*)d_in[6];
  float* ws = (float*)d_ws;
  float*  a_ws  = ws + OFF_A;
  float*  c_ws  = ws + OFF_C;
  __bf16* weffb = (__bf16*)(ws + OFF_WEFFB);
  __bf16* wdtb  = (__bf16*)(ws + OFF_WDTB);
  float*  Gws   = ws + OFF_G;
  float*  Minv  = ws + OFF_MINV;
  float*  misc  = ws + OFF_MISC;
  float*  gpart = ws + OFF_GPART;   // aliases zpart region (dead until mega)
  float*  zpart = ws + OFF_ZPART;
  float*  tpart = ws + OFF_TPART;
  float*  scanw = ws + OFF_SCAN;
  double* partw = (double*)(ws + OFF_PART);

  coef_kernel<<<8, 256, 0, stream>>>(Psi, a_ws, c_ws);
  prep2_kernel<<<96, 256, 0, stream>>>(Wenc, Wdec, a_ws, c_ws, weffb, wdtb, gpart);
  gram_reduce_kernel<<<16, 256, 0, stream>>>(gpart, Gws);
  neumann_kernel<<<1, 256, 0, stream>>>(Gws, vlv, lss, Minv, misc);
  mega_kernel<<<2048, 256, 0, stream>>>(x, eta, (const short*)weffb, (const short*)wdtb,
                                        a_ws, c_ws, zpart, tpart, scanw);
  fixup_kernel<<<512, 256, 0, stream>>>(zpart, tpart, scanw, Gws, Minv, misc, lss, partw);
  reduce_kernel<<<1, 256, 0, stream>>>(partw, (float*)d_out);
}

// Round 13
// 93.191 us; speedup vs baseline: 1.8190x; 1.0566x over previous
//
#include <hip/hip_runtime.h>
#include <math.h>

// LinearCatVAE loss on MI355X.
// Psi = Helmert basis => Psi products are diag + prefix scans.
// R11 (neutral): depth-2 prefetch offset by occupancy drop; bound by
// outstanding-bytes (Little's law ~1TB/s). 64/72 transactions per wave-chunk
// were scattered W B-frag loads (lane stride 4KB -> 16 segments/instr).
// R12: (1) pre-swizzled W-frag stream wfrag[split][chunk][frag][tid][8bf16],
// plane-separated -> every W load is a 1KB coalesced burst (16x fewer
// transactions); (2) LDS steered to ~29.7KB -> 5 blocks/CU x 4 waves = 20
// waves/CU with VGPR budget 102 >= 88 (no spill).

#define LOG2PI_F 1.8378770664093453f

typedef short  v8s    __attribute__((ext_vector_type(8)));
typedef float  f32x4v __attribute__((ext_vector_type(4)));

// ---- workspace offsets (floats) ----
#define OFF_A     0          // 2048
#define OFF_C     2048       // 2048
#define OFF_WEFFB 4096       // 65536
#define OFF_WDTB  69632     // 65536
#define OFF_G     135168    // 4096
#define OFF_MINV  139264    // 4096
#define OFF_MISC  143360    // 64
#define OFF_WFRAG 143424    // 131072 (512KB: 32 sc x 4 planes x 256 tid x 8 bf16)
#define OFF_ZPART 274496    // 4*8192*64 = 2097152 -> end 2371648
#define OFF_GPART OFF_ZPART // alias: gpart (131072) dead before mega writes
#define OFF_TPART 2371648   // 2097152 -> end 4468800
#define OFF_SCAN  4468800   // 4*8192*8 = 262144 -> end 4730944
#define OFF_PART  4730944   // 512 doubles = 1024 floats
#define OFF_END   4731968   // ~18.9 MB

__device__ inline float red16(float v){
#pragma unroll
  for (int m = 1; m < 16; m <<= 1) v += __shfl_xor(v, m, 16);
  return v;
}

// ---------------- P0: Helmert coefficients (Psi diag read ONCE) -------------
__global__ __launch_bounds__(256) void coef_kernel(const float* __restrict__ Psi,
                                                   float* __restrict__ a_ws,
                                                   float* __restrict__ c_ws){
  int e = blockIdx.x * 256 + threadIdx.x;   // 0..2047
  float a = 0.f, c = 0.f;
  if (e < 1999){
    a = Psi[(size_t)e * 2001];
    c = -Psi[(size_t)e * 2001 + 1];
  }
  a_ws[e] = a;
  c_ws[e] = c;
}

// ------- P1 (fused): blocks 0-63 wenceff (a/c coalesced), 64-95 wdtgram -----
__global__ __launch_bounds__(256) void prep2_kernel(const float* __restrict__ Wenc,
    const float* __restrict__ Wdec, const float* __restrict__ a_ws,
    const float* __restrict__ c_ws, __bf16* __restrict__ weffb,
    __bf16* __restrict__ wdtb, float* __restrict__ gparts){
  __shared__ __align__(16) float shm[4160];
  const int tid = threadIdx.x;
  const int blk = blockIdx.x;
  if (blk < 64){
    float* scan = shm;
    int k = blk;
    const float* wrow = Wenc + (size_t)k * 1999;
    int base = tid * 8;
    float w[8], sloc[8];
    float run = 0.f;
#pragma unroll
    for (int u = 0; u < 8; ++u){
      int e = base + u;
      float wv = (e < 1999) ? wrow[e] : 0.f;
      w[u] = wv;
      sloc[u] = run;
      run += c_ws[e] * wv;
    }
    scan[tid] = run;
    __syncthreads();
    for (int off = 1; off < 256; off <<= 1){
      float y = (tid >= off) ? scan[tid - off] : 0.f;
      __syncthreads();
      scan[tid] += y;
      __syncthreads();
    }
    float excl = scan[tid] - run;
#pragma unroll
    for (int u = 0; u < 8; ++u){
      int e = base + u;
      float val = (e < 2000) ? (a_ws[e] * w[u] - (excl + sloc[u])) : 0.f;
      weffb[(size_t)k * 2048 + e] = (__bf16)val;
    }
    return;
  }
  // wdtgram
  auto Ws = (float(*)[64])shm;
  int j0 = (blk - 64) * 64;
#pragma unroll
  for (int i = 0; i < 16; ++i){
    int e = tid + i * 256;
    int j = e >> 6, kk = e & 63;
    Ws[j][kk] = (j0 + j < 1999) ? Wdec[(size_t)(j0 + j) * 64 + kk] : 0.f;
  }
  __syncthreads();
#pragma unroll
  for (int i = 0; i < 16; ++i){
    int e = tid + i * 256; int kk = e >> 6, j = e & 63;
    wdtb[(size_t)kk * 2048 + j0 + j] = (__bf16)Ws[j][kk];
  }
  int p = tid & 63;
  int qb = (tid >> 6) * 16;
  float acc[16] = {};
  for (int jj = 0; jj < 64; ++jj){
    float wp = Ws[jj][p];
    const float4 q0 = *(const float4*)&Ws[jj][qb];
    const float4 q1 = *(const float4*)&Ws[jj][qb + 4];
    const float4 q2 = *(const float4*)&Ws[jj][qb + 8];
    const float4 q3 = *(const float4*)&Ws[jj][qb + 12];
    acc[0]  = fmaf(wp, q0.x, acc[0]);  acc[1]  = fmaf(wp, q0.y, acc[1]);
    acc[2]  = fmaf(wp, q0.z, acc[2]);  acc[3]  = fmaf(wp, q0.w, acc[3]);
    acc[4]  = fmaf(wp, q1.x, acc[4]);  acc[5]  = fmaf(wp, q1.y, acc[5]);
    acc[6]  = fmaf(wp, q1.z, acc[6]);  acc[7]  = fmaf(wp, q1.w, acc[7]);
    acc[8]  = fmaf(wp, q2.x, acc[8]);  acc[9]  = fmaf(wp, q2.y, acc[9]);
    acc[10] = fmaf(wp, q2.z, acc[10]); acc[11] = fmaf(wp, q2.w, acc[11]);
    acc[12] = fmaf(wp, q3.x, acc[12]); acc[13] = fmaf(wp, q3.y, acc[13]);
    acc[14] = fmaf(wp, q3.z, acc[14]); acc[15] = fmaf(wp, q3.w, acc[15]);
  }
  float* gp = gparts + (size_t)(blk - 64) * 4096 + (size_t)p * 64 + qb;
#pragma unroll
  for (int u = 0; u < 4; ++u){
    float4 o; o.x = acc[4*u]; o.y = acc[4*u+1]; o.z = acc[4*u+2]; o.w = acc[4*u+3];
    *(float4*)&gp[4*u] = o;
  }
}

// ---- P1c: pre-swizzled W-fragment stream --------------------------------
// wfrag[sc=split*8+ch][frag 0..3][tid][8 bf16]; frag0/1 = weffb khalf0/1,
// frag2/3 = wdtb khalf0/1, per-tid (bcol,kgrp) matching mega's MFMA mapping.
__global__ __launch_bounds__(256) void wfrag_kernel(const short* __restrict__ wf,
    const short* __restrict__ wd, short* __restrict__ fr){
  const int tid = threadIdx.x;
  const int sc = blockIdx.x;            // 0..31
  const int j0 = sc * 64;
  const int bcol = ((tid >> 6) << 4) + (tid & 15);
  const int kg = ((tid >> 4) & 3) * 8;
  const short* pf = wf + (size_t)bcol * 2048 + j0 + kg;
  const short* pd = wd + (size_t)bcol * 2048 + j0 + kg;
  short* o = fr + (size_t)sc * 8192 + tid * 8;
  *(v8s*)(o)        = *(const v8s*)(pf);
  *(v8s*)(o + 2048) = *(const v8s*)(pf + 32);
  *(v8s*)(o + 4096) = *(const v8s*)(pd);
  *(v8s*)(o + 6144) = *(const v8s*)(pd + 32);
}

// ---------------- P2b: reduce 32 partial grams -> G ----------------
__global__ __launch_bounds__(256) void gram_reduce_kernel(const float* __restrict__ gparts,
                                                          float* __restrict__ G){
  int e = blockIdx.x * 256 + threadIdx.x;   // 16 blocks
  float s = 0.f;
#pragma unroll
  for (int p = 0; p < 32; ++p) s += gparts[(size_t)p * 4096 + e];
  G[e] = s;
}

// ---- P3: Minv + logdet (Neumann truncated at A^2) ----
__global__ __launch_bounds__(256) void neumann_kernel(const float* __restrict__ Gws,
    const float* __restrict__ vlv, const float* __restrict__ lss,
    float* __restrict__ Minv, float* __restrict__ misc){
  __shared__ float As[64][65];
  __shared__ float A2s[64][65];
  __shared__ double dred[4][3];
  int tid = threadIdx.x;
  float var = expf(lss[0]);
  for (int e = tid; e < 4096; e += 256){
    int i = e >> 6;
    As[i][e & 63] = expf(vlv[i]) * Gws[e] / var;
  }
  __syncthreads();
  for (int e = tid; e < 4096; e += 256){
    int i = e >> 6, j = e & 63;
    float s = 0.f;
    for (int q = 0; q < 64; ++q) s = fmaf(As[i][q], As[q][j], s);
    A2s[i][j] = s;
  }
  __syncthreads();
  double t1 = 0, t2 = 0, t3 = 0;
  for (int e = tid; e < 4096; e += 256){
    int i = e >> 6, j = e & 63;
    if (i == j){ t1 += (double)As[i][i]; t2 += (double)A2s[i][i]; }
    t3 += (double)A2s[i][j] * (double)As[j][i];
  }
#pragma unroll
  for (int m = 1; m < 64; m <<= 1){
    t1 += __shfl_xor(t1, m, 64); t2 += __shfl_xor(t2, m, 64); t3 += __shfl_xor(t3, m, 64);
  }
  int wid = tid >> 6;
  if ((tid & 63) == 0){ dred[wid][0] = t1; dred[wid][1] = t2; dred[wid][2] = t3; }
  __syncthreads();
  for (int e = tid; e < 4096; e += 256){
    int i = e >> 6, j = e & 63;
    float v = ((i == j) ? 1.f : 0.f) - As[i][j] + A2s[i][j];
    Minv[e] = v * expf(vlv[j]);
  }
  if (tid == 0){
    double tr1 = 0, tr2 = 0, tr3 = 0;
    for (int w2 = 0; w2 < 4; ++w2){
      tr1 += dred[w2][0]; tr2 += dred[w2][1]; tr3 += dred[w2][2];
    }
    misc[0] = (float)(1999.0 * (double)lss[0] + tr1 - tr2 / 2.0 + tr3 / 3.0);
  }
}

// ---------------- MEGA: split-4, depth-2 prefetch, coalesced W-frags -------
// 2048 blocks x 256 threads; split = bid&3 (8 chunks of 64 cols);
// rowblk = bid>>2 -> 16 rows. LDS ~29.7KB -> 5 blocks/CU (VGPR budget 102).
struct PSet {
  float x4[4];
  float e4[4];
  v8s bf0, bf1, bd0, bd1;
};

__global__ __launch_bounds__(256) void mega_kernel(
    const float* __restrict__ x, const float* __restrict__ eta,
    const short* __restrict__ wfrag,
    const float* __restrict__ a_ws, const float* __restrict__ c_ws,
    float* __restrict__ zpart, float* __restrict__ tpart,
    float* __restrict__ scanw)
{
  __shared__ float lutlg[128];
  __shared__ __align__(16) float a_lds[512];
  __shared__ __align__(16) float c_lds[512];
  __shared__ __align__(16) unsigned char fragbuf[9216];   // At/Ae; later z_l/t_l
  __shared__ __align__(16) unsigned char steer[15872];    // occupancy steer: 5 blk/CU
  auto At = (__bf16(*)[16][72])(fragbuf);                 // [2][16][72]
  auto Ae = (__bf16(*)[16][72])(fragbuf + 4608);
  auto z_l = (float(*)[68])(fragbuf);                     // epilogue overlay
  auto t_l = (float(*)[68])(fragbuf + 4352);

  const int tid = threadIdx.x;
  if (tid == 0) ((volatile unsigned char*)steer)[0] = 1;  // keep allocation
  const int split = blockIdx.x & 3;
  const int rowblk = blockIdx.x >> 2;
  const int b0 = rowblk * 16;
  const int ch0 = split * 8;
  const int cb0 = split * 512;
  if (tid < 128) lutlg[tid] = lgammaf((float)(tid + 1));
  for (int i = tid; i < 512; i += 256){ a_lds[i] = a_ws[cb0 + i]; c_lds[i] = c_ws[cb0 + i]; }

  const int lrow = tid >> 4;
  const int sl   = tid & 15;
  const int lq4  = sl * 4;
  const int wid  = tid >> 6, lan = tid & 63;
  const int arow = lan & 15;
  const int bcol = wid * 16 + (lan & 15);
  const int kgrp = (lan >> 4) * 8;

  f32x4v accz = {0.f, 0.f, 0.f, 0.f}, acct = {0.f, 0.f, 0.f, 0.f};
  float carry = 0.f, mOn = -3.0e38f, sOn = 0.f;
  float xdot = 0.f, sx = 0.f, sgl = 0.f, e2 = 0.f;

  const float* xs_base = x   + (size_t)(b0 + lrow) * 2000 + lq4;
  const float* es_base = eta + (size_t)(b0 + lrow) * 1999 + lq4;
  const short* fr_base = wfrag + (size_t)ch0 * 8192 + (size_t)tid * 8;

  const bool lastSplit = (split == 3);

  auto loadSet = [&](PSet& S, int c, bool guard){
    const int j0 = (ch0 + c) * 64;
    const float* xp = xs_base + j0;
    const float* ep = es_base + j0;
    if (!guard){
      f32x4v v = *(const f32x4v*)xp;
      S.x4[0] = v[0]; S.x4[1] = v[1]; S.x4[2] = v[2]; S.x4[3] = v[3];
#pragma unroll
      for (int u = 0; u < 4; ++u) S.e4[u] = ep[u];
    } else {
#pragma unroll
      for (int u = 0; u < 4; ++u){
        int cc = j0 + lq4 + u;
        S.x4[u] = (cc < 2000) ? xp[u] : 0.f;
        S.e4[u] = (cc < 1999) ? ep[u] : 0.f;
      }
    }
    const short* fb = fr_base + (size_t)c * 8192;
    S.bf0 = *(const v8s*)(fb);
    S.bf1 = *(const v8s*)(fb + 2048);
    S.bd0 = *(const v8s*)(fb + 4096);
    S.bd1 = *(const v8s*)(fb + 6144);
  };
  auto stage = [&](const PSet& S, int buf){
    union { __bf16 b[4]; unsigned long long q; } cx, ce;
#pragma unroll
    for (int u = 0; u < 4; ++u){
      cx.b[u] = (__bf16)__logf(S.x4[u] + 1.f);
      ce.b[u] = (__bf16)S.e4[u];
    }
    *(unsigned long long*)&At[buf][lrow][lq4] = cx.q;
    *(unsigned long long*)&Ae[buf][lrow][lq4] = ce.q;
  };
  auto mfmaStep = [&](int buf, const PSet& S){
    v8s ax0 = *(const v8s*)&At[buf][arow][kgrp];
    v8s ax1 = *(const v8s*)&At[buf][arow][32 + kgrp];
    v8s ae0 = *(const v8s*)&Ae[buf][arow][kgrp];
    v8s ae1 = *(const v8s*)&Ae[buf][arow][32 + kgrp];
    accz = __builtin_amdgcn_mfma_f32_16x16x32_bf16(ax0, S.bf0, accz, 0, 0, 0);
    accz = __builtin_amdgcn_mfma_f32_16x16x32_bf16(ax1, S.bf1, accz, 0, 0, 0);
    acct = __builtin_amdgcn_mfma_f32_16x16x32_bf16(ae0, S.bd0, acct, 0, 0, 0);
    acct = __builtin_amdgcn_mfma_f32_16x16x32_bf16(ae1, S.bd1, acct, 0, 0, 0);
  };
  auto scanStep = [&](const PSet& S, int c, bool guard){
    const int j0g = (ch0 + c) * 64;
    const int jl  = c * 64;
    f32x4v cz = *(const f32x4v*)&c_lds[jl + lq4];
    f32x4v az = *(const f32x4v*)&a_lds[jl + lq4];
    float s0 = cz[0] * S.e4[0], s1 = cz[1] * S.e4[1];
    float s2 = cz[2] * S.e4[2], s3 = cz[3] * S.e4[3];
    float run = s0 + s1 + s2 + s3;
    float p1 = s0, p2 = s0 + s1, p3 = s0 + s1 + s2;
    float tot = run;
#pragma unroll
    for (int d = 1; d < 16; d <<= 1){
      float o = __shfl_up(tot, d, 16);
      if (sl >= d) tot += o;
    }
    float excl = tot - run;
    float base = carry + excl;
    carry += __shfl(tot, 15, 16);
    float lg0 = az[0] * S.e4[0] - base;
    float lg1 = az[1] * S.e4[1] - (base + p1);
    float lg2 = az[2] * S.e4[2] - (base + p2);
    float lg3 = az[3] * S.e4[3] - (base + p3);
    if (!guard){
      float cm = fmaxf(fmaxf(lg0, lg1), fmaxf(lg2, lg3));
      if (cm > mOn){ sOn *= __expf(mOn - cm); mOn = cm; }
      sOn += __expf(lg0 - mOn) + __expf(lg1 - mOn) + __expf(lg2 - mOn) + __expf(lg3 - mOn);
      xdot = fmaf(S.x4[0], lg0, xdot);
      xdot = fmaf(S.x4[1], lg1, xdot);
      xdot = fmaf(S.x4[2], lg2, xdot);
      xdot = fmaf(S.x4[3], lg3, xdot);
    } else {
      int nvalid = 2000 - (j0g + lq4);
      float cm = -3.0e38f;
      if (0 < nvalid) cm = fmaxf(cm, lg0);
      if (1 < nvalid) cm = fmaxf(cm, lg1);
      if (2 < nvalid) cm = fmaxf(cm, lg2);
      if (3 < nvalid) cm = fmaxf(cm, lg3);
      if (cm > mOn){ sOn *= __expf(mOn - cm); mOn = cm; }
      if (0 < nvalid){ sOn += __expf(lg0 - mOn); xdot = fmaf(S.x4[0], lg0, xdot); }
      if (1 < nvalid){ sOn += __expf(lg1 - mOn); xdot = fmaf(S.x4[1], lg1, xdot); }
      if (2 < nvalid){ sOn += __expf(lg2 - mOn); xdot = fmaf(S.x4[2], lg2, xdot); }
      if (3 < nvalid){ sOn += __expf(lg3 - mOn); xdot = fmaf(S.x4[3], lg3, xdot); }
    }
#pragma unroll
    for (int u = 0; u < 4; ++u){
      sx += S.x4[u];
      sgl += lutlg[(int)S.x4[u]];
      e2 = fmaf(S.e4[u], S.e4[u], e2);
    }
  };

  PSet S[3];
  loadSet(S[0], 0, false);
  loadSet(S[1], 1, false);
  stage(S[0], 0);
  // depth-2 pipeline, FULLY UNROLLED so all S[] indices are compile-time
#pragma unroll
  for (int c = 0; c < 8; ++c){
    __syncthreads();                     // buf[c&1] staged & visible
    if (c + 2 < 8)
      loadSet(S[(c + 2) % 3], c + 2, lastSplit && (c + 2 == 7));
    mfmaStep(c & 1, S[c % 3]);
    scanStep(S[c % 3], c, lastSplit && (c == 7));
    if (c < 7)
      stage(S[(c + 1) % 3], (c + 1) & 1);   // waits loads issued 1.5 chunks ago
  }

  // ---- per-split reductions + partial writes ----
  xdot = red16(xdot); sx = red16(sx); sgl = red16(sgl); e2 = red16(e2);
#pragma unroll
  for (int d = 1; d < 16; d <<= 1){
    float om = __shfl_xor(mOn, d, 16);
    float os = __shfl_xor(sOn, d, 16);
    float nm = fmaxf(mOn, om);
    sOn = sOn * __expf(mOn - nm) + os * __expf(om - nm);
    mOn = nm;
  }
  __syncthreads();             // all frag reads done before z_l/t_l overlay
  {
    int r0 = (lan >> 4) * 4;
#pragma unroll
    for (int r = 0; r < 4; ++r){
      z_l[r0 + r][bcol] = accz[r];
      t_l[r0 + r][bcol] = acct[r];
    }
  }
  __syncthreads();
  {
    size_t rb = (size_t)(split * 8192 + b0 + lrow) * 64 + lq4;
    f32x4v zv = *(const f32x4v*)&z_l[lrow][lq4];
    f32x4v tv = *(const f32x4v*)&t_l[lrow][lq4];
    *(f32x4v*)&zpart[rb] = zv;
    *(f32x4v*)&tpart[rb] = tv;
  }
  if (sl == 0){
    float* so = &scanw[(size_t)(split * 8192 + b0 + lrow) * 8];
    so[0] = carry; so[1] = mOn; so[2] = sOn; so[3] = xdot;
    so[4] = sx; so[5] = sgl; so[6] = e2;
  }
}

// ---------------- FIXUP: merge 4 splits + quad; block-sum to double --------
__global__ __launch_bounds__(256) void fixup_kernel(const float* __restrict__ zpart,
    const float* __restrict__ tpart, const float* __restrict__ scanw,
    const float* __restrict__ Gws, const float* __restrict__ Minv,
    const float* __restrict__ misc, const float* __restrict__ lss,
    double* __restrict__ part_out)
{
  __shared__ __align__(16) float z_l[16][68];
  __shared__ __align__(16) float t_l[16][68];
  __shared__ double rsum[16];
  const int tid = threadIdx.x;
  const int lrow = tid >> 4, sl = tid & 15, lq4 = sl * 4;
  const int b = blockIdx.x * 16 + lrow;

  float z4[4] = {0.f,0.f,0.f,0.f}, t4[4] = {0.f,0.f,0.f,0.f};
#pragma unroll
  for (int s = 0; s < 4; ++s){
    f32x4v zv = *(const f32x4v*)&zpart[(size_t)(s * 8192 + b) * 64 + lq4];
    f32x4v tv = *(const f32x4v*)&tpart[(size_t)(s * 8192 + b) * 64 + lq4];
#pragma unroll
    for (int u = 0; u < 4; ++u){ z4[u] += zv[u]; t4[u] += tv[u]; }
  }
#pragma unroll
  for (int u = 0; u < 4; ++u) z_l[lrow][lq4 + u] = z4[u];
  float zz = 0.f, tz = 0.f;
#pragma unroll
  for (int u = 0; u < 4; ++u){ zz = fmaf(z4[u], z4[u], zz); tz = fmaf(t4[u], z4[u], tz); }
  float gz[4] = {0.f, 0.f, 0.f, 0.f};
#pragma unroll 8
  for (int q = 0; q < 64; ++q){
    float zq = z_l[lrow][q];
    f32x4v g = *(const f32x4v*)&Gws[q * 64 + lq4];   // G symmetric; L2-hot
#pragma unroll
    for (int u = 0; u < 4; ++u) gz[u] = fmaf(g[u], zq, gz[u]);
  }
  float zGz = 0.f;
#pragma unroll
  for (int u = 0; u < 4; ++u) zGz = fmaf(z4[u], gz[u], zGz);
  float tk[4];
#pragma unroll
  for (int u = 0; u < 4; ++u){ tk[u] = t4[u] - gz[u]; t_l[lrow][lq4 + u] = tk[u]; }
  float sol[4] = {0.f, 0.f, 0.f, 0.f};
#pragma unroll 8
  for (int q = 0; q < 64; ++q){
    float tq = t_l[lrow][q];
    f32x4v g = *(const f32x4v*)&Minv[q * 64 + lq4];  // Minv symmetric
#pragma unroll
    for (int u = 0; u < 4; ++u) sol[u] = fmaf(g[u], tq, sol[u]);
  }
  float ts = 0.f;
#pragma unroll
  for (int u = 0; u < 4; ++u) ts = fmaf(tk[u], sol[u], ts);

  zz = red16(zz); tz = red16(tz); zGz = red16(zGz); ts = red16(ts);
  if (sl == 0){
    // merge 4 splits with prefix carries
    float C = 0.f, M = -3.0e38f, S = 0.f;
    float xdT = 0.f, sxT = 0.f, sglT = 0.f, e2T = 0.f;
#pragma unroll
    for (int s = 0; s < 4; ++s){
      const float* p = &scanw[(size_t)(s * 8192 + b) * 8];
      float mp = p[1] - C;
      float Ss = p[2];
      float mm = fmaxf(M, mp);
      S = S * __expf(M - mm) + Ss * __expf(mp - mm);
      M = mm;
      xdT += p[3] - C * p[4];
      sxT += p[4]; sglT += p[5]; e2T += p[6];
      C += p[0];
    }
    float lse = M + logf(S);
    float mult = lgammaf(sxT + 1.f) - sglT + xdT - sxT * lse;
    float var = expf(lss[0]);
    float logdet = misc[0];
    float diff2 = e2T - 2.f * tz + zGz;
    float quad = diff2 / var - ts / (var * var);
    float lp = -0.5f * (1999.f * LOG2PI_F + logdet + quad) - 0.5f * zz;
    rsum[lrow] = (double)mult + (double)lp;
  }
  __syncthreads();
  if (tid == 0){
    double s = 0.0;
#pragma unroll
    for (int r = 0; r < 16; ++r) s += rsum[r];
    part_out[blockIdx.x] = s;
  }
}

// ---------------- Z: final mean + constants ----------------
__global__ __launch_bounds__(256) void reduce_kernel(const double* __restrict__ part,
                                                     float* __restrict__ out){
  __shared__ double red[4];
  int tid = threadIdx.x;
  double acc = part[tid] + part[tid + 256];
#pragma unroll
  for (int m = 1; m < 64; m <<= 1) acc += __shfl_xor(acc, m, 64);
  if ((tid & 63) == 0) red[tid >> 6] = acc;
  __syncthreads();
  if (tid == 0){
    double tot = red[0] + red[1] + red[2] + red[3];
    double mean = tot / 8192.0;
    double loss = -(mean - 0.5 * 64.0 * 1.8378770664093453);
    out[0] = (float)loss;
  }
}

extern "C" void kernel_launch(void* const* d_in, const int* in_sizes, int n_in,
                              void* d_out, int out_size, void* d_ws, size_t ws_size,
                              hipStream_t stream){
  const float* x    = (const float*)d_in[0];
  const float* Psi  = (const float*)d_in[1];
  const float* Wenc = (const float*)d_in[2];
  const float* Wdec = (const float*)d_in[3];
  const float* vlv  = (const float*)d_in[4];
  const float* lss  = (const float*)d_in[5];
  const float* eta  = (const float*)d_in[6];
  float* ws = (float*)d_ws;
  float*  a_ws  = ws + OFF_A;
  float*  c_ws  = ws + OFF_C;
  __bf16* weffb = (__bf16*)(ws + OFF_WEFFB);
  __bf16* wdtb  = (__bf16*)(ws + OFF_WDTB);
  float*  Gws   = ws + OFF_G;
  float*  Minv  = ws + OFF_MINV;
  float*  misc  = ws + OFF_MISC;
  short*  wfrag = (short*)(ws + OFF_WFRAG);
  float*  gpart = ws + OFF_GPART;   // aliases zpart region (dead until mega)
  float*  zpart = ws + OFF_ZPART;
  float*  tpart = ws + OFF_TPART;
  float*  scanw = ws + OFF_SCAN;
  double* partw = (double*)(ws + OFF_PART);

  coef_kernel<<<8, 256, 0, stream>>>(Psi, a_ws, c_ws);
  prep2_kernel<<<96, 256, 0, stream>>>(Wenc, Wdec, a_ws, c_ws, weffb, wdtb, gpart);
  wfrag_kernel<<<32, 256, 0, stream>>>((const short*)weffb, (const short*)wdtb, wfrag);
  gram_reduce_kernel<<<16, 256, 0, stream>>>(gpart, Gws);
  neumann_kernel<<<1, 256, 0, stream>>>(Gws, vlv, lss, Minv, misc);
  mega_kernel<<<2048, 256, 0, stream>>>(x, eta, wfrag, a_ws, c_ws, zpart, tpart, scanw);
  fixup_kernel<<<512, 256, 0, stream>>>(zpart, tpart, scanw, Gws, Minv, misc, lss, partw);
  reduce_kernel<<<1, 256, 0, stream>>>(partw, (float*)d_out);
}